// Round 3
// baseline (633.855 us; speedup 1.0000x reference)
//
#include <hip/hip_runtime.h>
#include <hip/hip_bf16.h>
#include <math.h>

#define B_ 4
#define N_ 1024
#define C_ 768
#define H_ 12
#define D_ 64
#define TOPK_ 32
#define EPS_ 1e-9f

struct TopkRec { unsigned int cnt; unsigned short c[62]; };  // 128 B

// ---------------------------------------------------------------------------
// Generic NN GEMM: C[M,Nc] = A[M,K] @ B[K,Nc] + bias[Nc]
// 64x64 block tile, 16 K-chunk, 256 threads, 4x4 micro-tile per thread.
// ---------------------------------------------------------------------------
__global__ __launch_bounds__(256) void gemm_nn_bias(
    const float* __restrict__ A, const float* __restrict__ Bm,
    const float* __restrict__ bias, float* __restrict__ Cm,
    int M, int Ncols, int Kdim, int lda, int ldb, int ldc)
{
    __shared__ float As[16][68];   // transposed: As[kk][row]
    __shared__ float Bs[16][68];   // natural:    Bs[kk][col]
    const int t  = threadIdx.x;
    const int tx = t & 15, ty = t >> 4;
    const int m0 = blockIdx.y * 64, n0 = blockIdx.x * 64;
    const int arow = t >> 2, akk = (t & 3) * 4;
    const int bkk  = t >> 4, bcol = (t & 15) * 4;

    float acc[4][4] = {{0.f, 0.f, 0.f, 0.f}, {0.f, 0.f, 0.f, 0.f},
                       {0.f, 0.f, 0.f, 0.f}, {0.f, 0.f, 0.f, 0.f}};

    for (int k0 = 0; k0 < Kdim; k0 += 16) {
        float4 av = *(const float4*)&A[(size_t)(m0 + arow) * lda + k0 + akk];
        float4 bv = *(const float4*)&Bm[(size_t)(k0 + bkk) * ldb + n0 + bcol];
        __syncthreads();
        As[akk + 0][arow] = av.x;
        As[akk + 1][arow] = av.y;
        As[akk + 2][arow] = av.z;
        As[akk + 3][arow] = av.w;
        *(float4*)&Bs[bkk][bcol] = bv;
        __syncthreads();
        #pragma unroll
        for (int kk = 0; kk < 16; ++kk) {
            float4 a  = *(const float4*)&As[kk][ty * 4];
            float4 b4 = *(const float4*)&Bs[kk][tx * 4];
            float ar[4] = {a.x, a.y, a.z, a.w};
            float br[4] = {b4.x, b4.y, b4.z, b4.w};
            #pragma unroll
            for (int i = 0; i < 4; ++i)
                #pragma unroll
                for (int j = 0; j < 4; ++j)
                    acc[i][j] += ar[i] * br[j];
        }
    }
    #pragma unroll
    for (int i = 0; i < 4; ++i) {
        float4 o;
        o.x = acc[i][0] + bias[n0 + tx * 4 + 0];
        o.y = acc[i][1] + bias[n0 + tx * 4 + 1];
        o.z = acc[i][2] + bias[n0 + tx * 4 + 2];
        o.w = acc[i][3] + bias[n0 + tx * 4 + 3];
        *(float4*)&Cm[(size_t)(m0 + ty * 4 + i) * ldc + n0 + tx * 4] = o;
    }
}

// ---------------------------------------------------------------------------
// z[b,n,m] = (scale/H) * Qc[b,n,:].Kc[b,m,:] + gumbel(u[b,n,m])
// ---------------------------------------------------------------------------
__global__ __launch_bounds__(256) void zscore_kernel(
    const float* __restrict__ qkv, const float* __restrict__ u,
    float* __restrict__ z)
{
    __shared__ float As[16][68];   // As[kk][n]
    __shared__ float Bs[16][68];   // Bs[kk][m]
    const int t  = threadIdx.x;
    const int tx = t & 15, ty = t >> 4;
    const int b  = blockIdx.z;
    const int n0 = blockIdx.y * 64, m0 = blockIdx.x * 64;
    const int lrow = t >> 2, lkk = (t & 3) * 4;
    const float* qbase = qkv + (size_t)b * N_ * 2304;

    float acc[4][4] = {{0.f, 0.f, 0.f, 0.f}, {0.f, 0.f, 0.f, 0.f},
                       {0.f, 0.f, 0.f, 0.f}, {0.f, 0.f, 0.f, 0.f}};

    for (int k0 = 0; k0 < C_; k0 += 16) {
        float4 av = *(const float4*)&qbase[(size_t)(n0 + lrow) * 2304 + k0 + lkk];
        float4 bv = *(const float4*)&qbase[(size_t)(m0 + lrow) * 2304 + 768 + k0 + lkk];
        __syncthreads();
        As[lkk + 0][lrow] = av.x;
        As[lkk + 1][lrow] = av.y;
        As[lkk + 2][lrow] = av.z;
        As[lkk + 3][lrow] = av.w;
        Bs[lkk + 0][lrow] = bv.x;
        Bs[lkk + 1][lrow] = bv.y;
        Bs[lkk + 2][lrow] = bv.z;
        Bs[lkk + 3][lrow] = bv.w;
        __syncthreads();
        #pragma unroll
        for (int kk = 0; kk < 16; ++kk) {
            float4 a  = *(const float4*)&As[kk][ty * 4];
            float4 b4 = *(const float4*)&Bs[kk][tx * 4];
            float ar[4] = {a.x, a.y, a.z, a.w};
            float br[4] = {b4.x, b4.y, b4.z, b4.w};
            #pragma unroll
            for (int i = 0; i < 4; ++i)
                #pragma unroll
                for (int j = 0; j < 4; ++j)
                    acc[i][j] += ar[i] * br[j];
        }
    }
    const float sc = 0.125f / 12.0f;   // scale / H
    #pragma unroll
    for (int i = 0; i < 4; ++i) {
        const int n = n0 + ty * 4 + i;
        float4 o;
        float vals[4];
        #pragma unroll
        for (int j = 0; j < 4; ++j) {
            const int m = m0 + tx * 4 + j;
            float uv = u[((size_t)b * N_ + n) * N_ + m];
            float g  = -logf(-logf(uv + EPS_) + EPS_);
            vals[j]  = acc[i][j] * sc + g;
        }
        o.x = vals[0]; o.y = vals[1]; o.z = vals[2]; o.w = vals[3];
        *(float4*)&z[((size_t)b * N_ + n) * N_ + m0 + tx * 4] = o;
    }
}

// ---------------------------------------------------------------------------
// Per row: exact 32nd-largest of z[row,:]; emit ALL column indices with
// z >= thresh (count-exact, capped at 62 which requires a 31-way tie to hit).
// One wave per row, 16 elems/lane.
// ---------------------------------------------------------------------------
__global__ __launch_bounds__(64) void topk_cols_kernel(
    const float* __restrict__ z, TopkRec* __restrict__ recs)
{
    const int row  = blockIdx.x;
    const int lane = threadIdx.x;
    const float* zr = z + (size_t)row * N_;
    float zv[16], wk[16];
    #pragma unroll
    for (int j = 0; j < 16; ++j) { zv[j] = zr[lane + 64 * j]; wk[j] = zv[j]; }

    float thresh = -INFINITY;
    for (int it = 0; it < TOPK_; ++it) {
        float lm = wk[0]; int li = 0;
        #pragma unroll
        for (int j = 1; j < 16; ++j)
            if (wk[j] > lm) { lm = wk[j]; li = j; }
        float gm = lm;
        gm = fmaxf(gm, __shfl_xor(gm, 1));
        gm = fmaxf(gm, __shfl_xor(gm, 2));
        gm = fmaxf(gm, __shfl_xor(gm, 4));
        gm = fmaxf(gm, __shfl_xor(gm, 8));
        gm = fmaxf(gm, __shfl_xor(gm, 16));
        gm = fmaxf(gm, __shfl_xor(gm, 32));
        unsigned long long has = __ballot(lm == gm);
        int first = __ffsll((unsigned long long)has) - 1;
        if (lane == first) wk[li] = -INFINITY;
        thresh = gm;
    }

    const unsigned long long below = ((unsigned long long)1 << lane) - 1;
    unsigned int basec = 0;
    TopkRec* rec = recs + row;
    #pragma unroll
    for (int j = 0; j < 16; ++j) {
        unsigned long long w = __ballot(zv[j] >= thresh);
        if (zv[j] >= thresh) {
            unsigned int pos = basec + (unsigned int)__popcll(w & below);
            if (pos < 62u) rec->c[pos] = (unsigned short)(lane + 64 * j);
        }
        basec += (unsigned int)__popcll(w);
    }
    if (lane == 0) rec->cnt = basec > 62u ? 62u : basec;
}

// ---------------------------------------------------------------------------
// Pass A: per (b,h,row): softmax max m and denominator l over ALL 1024 cols.
// Flash structure minus PV: no P tile, no V staging, 2 syncs per tile.
// ---------------------------------------------------------------------------
__global__ __launch_bounds__(256) void attn_ml_kernel(
    const float* __restrict__ qkv, float2* __restrict__ ml)
{
    __shared__ float Qs[64][68];    // Qs[d][r]  (transposed)
    __shared__ float Ks[64][68];    // Ks[d][c]  (transposed)

    const int t  = threadIdx.x;
    const int tx = t & 15, ty = t >> 4;
    const int n0 = blockIdx.x * 64;
    const int h  = blockIdx.y;
    const int b  = blockIdx.z;
    const int lr = t >> 2;           // staged row/col 0..63
    const int dq = (t & 3) * 16;     // staged d-base: 0,16,32,48

    // Load Q tile (transposed): d = dq..dq+15 for row lr
    #pragma unroll
    for (int qq = 0; qq < 4; ++qq) {
        float4 qv = *(const float4*)
            &qkv[(size_t)(b * N_ + n0 + lr) * 2304 + h * 64 + dq + qq * 4];
        Qs[dq + qq * 4 + 0][lr] = qv.x;
        Qs[dq + qq * 4 + 1][lr] = qv.y;
        Qs[dq + qq * 4 + 2][lr] = qv.z;
        Qs[dq + qq * 4 + 3][lr] = qv.w;
    }

    float mrun[4], lsum[4];
    #pragma unroll
    for (int i = 0; i < 4; ++i) { mrun[i] = -INFINITY; lsum[i] = 0.f; }

    for (int m0 = 0; m0 < N_; m0 += 64) {
        float4 kv[4];
        #pragma unroll
        for (int qq = 0; qq < 4; ++qq)
            kv[qq] = *(const float4*)
                &qkv[(size_t)(b * N_ + m0 + lr) * 2304 + 768 + h * 64 + dq + qq * 4];

        __syncthreads();                 // prev tile's scores done reading Ks
        #pragma unroll
        for (int qq = 0; qq < 4; ++qq) { // K transposed [d][c]
            Ks[dq + qq * 4 + 0][lr] = kv[qq].x;
            Ks[dq + qq * 4 + 1][lr] = kv[qq].y;
            Ks[dq + qq * 4 + 2][lr] = kv[qq].z;
            Ks[dq + qq * 4 + 3][lr] = kv[qq].w;
        }
        __syncthreads();

        float s[4][4] = {{0.f, 0.f, 0.f, 0.f}, {0.f, 0.f, 0.f, 0.f},
                         {0.f, 0.f, 0.f, 0.f}, {0.f, 0.f, 0.f, 0.f}};
        #pragma unroll 8
        for (int d = 0; d < 64; ++d) {
            float4 a  = *(const float4*)&Qs[d][ty * 4];
            float4 b4 = *(const float4*)&Ks[d][tx * 4];
            float ar[4] = {a.x, a.y, a.z, a.w};
            float br[4] = {b4.x, b4.y, b4.z, b4.w};
            #pragma unroll
            for (int i = 0; i < 4; ++i)
                #pragma unroll
                for (int j = 0; j < 4; ++j)
                    s[i][j] += ar[i] * br[j];
        }

        #pragma unroll
        for (int i = 0; i < 4; ++i) {
            float tmax = fmaxf(fmaxf(s[i][0], s[i][1]), fmaxf(s[i][2], s[i][3]));
            tmax *= 0.125f;
            tmax = fmaxf(tmax, __shfl_xor(tmax, 1));
            tmax = fmaxf(tmax, __shfl_xor(tmax, 2));
            tmax = fmaxf(tmax, __shfl_xor(tmax, 4));
            tmax = fmaxf(tmax, __shfl_xor(tmax, 8));
            float mnew  = fmaxf(mrun[i], tmax);
            float alpha = expf(mrun[i] - mnew);
            float tsum = 0.f;
            #pragma unroll
            for (int j = 0; j < 4; ++j)
                tsum += expf(s[i][j] * 0.125f - mnew);
            tsum += __shfl_xor(tsum, 1);
            tsum += __shfl_xor(tsum, 2);
            tsum += __shfl_xor(tsum, 4);
            tsum += __shfl_xor(tsum, 8);
            lsum[i] = lsum[i] * alpha + tsum;
            mrun[i] = mnew;
        }
    }

    if (tx == 0) {
        #pragma unroll
        for (int i = 0; i < 4; ++i)
            ml[((size_t)(b * H_ + h)) * N_ + n0 + ty * 4 + i] =
                make_float2(mrun[i], lsum[i]);
    }
}

// ---------------------------------------------------------------------------
// Pass B: per (b,n): gather the selected columns (shared across heads),
// recompute their scores, accumulate exp(s-m)/l * v.  4 waves, head h
// handled by wave h%4; lane owns dimension d.
// ---------------------------------------------------------------------------
__global__ __launch_bounds__(256) void sparse_pv_kernel(
    const float* __restrict__ qkv, const TopkRec* __restrict__ recs,
    const float2* __restrict__ ml, const float* __restrict__ head_scores,
    float* __restrict__ out1)
{
    __shared__ int cols_s[62];
    __shared__ int cnt_s;

    const int t    = threadIdx.x;
    const int lane = t & 63, wv = t >> 6;
    const int row  = blockIdx.x;              // b*N + n
    const int b    = row >> 10, n = row & 1023;

    const TopkRec* rec = recs + row;
    if (t == 0) cnt_s = (int)min(rec->cnt, 62u);
    if (t < 62) cols_s[t] = rec->c[t];

    float hsum = 0.f;
    #pragma unroll
    for (int i = 0; i < H_; ++i) hsum += head_scores[i];
    const float hs_mean = hsum * (1.0f / 12.0f);
    __syncthreads();
    const int cnt = cnt_s;

    const float* qrow = qkv + (size_t)row * 2304;
    for (int h = wv; h < H_; h += 4) {
        const float q = qrow[h * 64 + lane];
        const float2 mlv = ml[((size_t)(b * H_ + h)) * N_ + n];
        float acc = 0.f;
        for (int j = 0; j < cnt; ++j) {
            const int c = cols_s[j];
            const float* crow = qkv + ((size_t)(b * N_ + c)) * 2304 + h * 64 + lane;
            float prod = q * crow[768];
            prod += __shfl_xor(prod, 1);
            prod += __shfl_xor(prod, 2);
            prod += __shfl_xor(prod, 4);
            prod += __shfl_xor(prod, 8);
            prod += __shfl_xor(prod, 16);
            prod += __shfl_xor(prod, 32);
            float p = expf(prod * 0.125f - mlv.x);
            acc += p * crow[1536];
        }
        out1[(size_t)row * C_ + h * 64 + lane] = acc * (hs_mean / mlv.y);
    }
}

// ---------------------------------------------------------------------------
extern "C" void kernel_launch(void* const* d_in, const int* in_sizes, int n_in,
                              void* d_out, int out_size, void* d_ws, size_t ws_size,
                              hipStream_t stream)
{
    (void)in_sizes; (void)n_in; (void)out_size; (void)ws_size;
    const float* x           = (const float*)d_in[0];
    const float* u           = (const float*)d_in[1];
    const float* qkv_w       = (const float*)d_in[2];
    const float* qkv_b       = (const float*)d_in[3];
    const float* proj_w      = (const float*)d_in[4];
    const float* proj_b      = (const float*)d_in[5];
    const float* head_scores = (const float*)d_in[6];
    float* out = (float*)d_out;

    // Workspace layout (within the proven 55,050,240-byte footprint):
    //   [0, 37748736)            qkv
    //   [37748736, 54525952)     z (16.78 MB); after topk, z is dead:
    //       out1 = first 12,582,912 B of z-slot
    //       ml   = z-slot + 12,582,912 (393,216 B)  [written by passA, after topk]
    //   [54525952, 55050240)     TopkRec[4096] (128 B each = 524,288 B)
    char* ws = (char*)d_ws;
    float*   ws_qkv  = (float*)ws;
    float*   ws_z    = (float*)(ws + 37748736);
    float*   ws_out1 = ws_z;
    float2*  ws_ml   = (float2*)(ws + 37748736 + 12582912);
    TopkRec* ws_rec  = (TopkRec*)(ws + 54525952);

    dim3 blk(256);

    // 1) qkv = x @ qkv_w + qkv_b   (4096 x 2304 x 768)
    gemm_nn_bias<<<dim3(2304 / 64, 4096 / 64), blk, 0, stream>>>(
        x, qkv_w, qkv_b, ws_qkv, 4096, 2304, 768, 768, 2304, 2304);

    // 2) z = (scale/H) Qc.Kc^T + gumbel(u)
    zscore_kernel<<<dim3(16, 16, B_), blk, 0, stream>>>(ws_qkv, u, ws_z);

    // 3) exact top-32 threshold per row -> selected column index records
    topk_cols_kernel<<<dim3(B_ * N_), dim3(64), 0, stream>>>(ws_z, ws_rec);

    // 4a) per-head softmax max + denominator over all columns
    attn_ml_kernel<<<dim3(16, H_, B_), blk, 0, stream>>>(ws_qkv, ws_ml);

    // 4b) sparse gather: numerator over selected columns only -> out1
    sparse_pv_kernel<<<dim3(B_ * N_), blk, 0, stream>>>(
        ws_qkv, ws_rec, ws_ml, head_scores, ws_out1);

    // 5) out = out1 @ proj_w + proj_b
    gemm_nn_bias<<<dim3(768 / 64, 4096 / 64), blk, 0, stream>>>(
        ws_out1, proj_w, proj_b, out, 4096, 768, 768, 768, 768, 768);
}

// Round 4
// 510.933 us; speedup vs baseline: 1.2406x; 1.2406x over previous
//
#include <hip/hip_runtime.h>
#include <hip/hip_bf16.h>
#include <math.h>

#define B_ 4
#define N_ 1024
#define C_ 768
#define H_ 12
#define D_ 64
#define TOPK_ 32
#define EPS_ 1e-9f

#define LDT 104   // padded LDS row stride (bf16 elems): 96 used + 8 pad -> 208B

typedef __attribute__((ext_vector_type(8))) short bf16x8;
typedef __attribute__((ext_vector_type(4))) short short4v;
typedef __attribute__((ext_vector_type(4))) float f32x4;

struct TopkRec { unsigned int cnt; unsigned short c[62]; };  // 128 B

__device__ __forceinline__ unsigned short f2bf(float f) {
    unsigned int u = __float_as_uint(f);
    u += 0x7fffu + ((u >> 16) & 1u);
    return (unsigned short)(u >> 16);
}
__device__ __forceinline__ float bf2f(unsigned short h) {
    return __uint_as_float(((unsigned int)h) << 16);
}

// ---------------------------------------------------------------------------
// Split-bf16 MFMA GEMM (NN): C[M,N] = A[M,K] @ B[K,N] + bias.
// fp32 emulation: per real k, LDS holds interleaved triples
//   A: {hi,hi,lo}   B: {hi,lo,hi}   =>  sum = Ah*Bh + Ah*Bl + Al*Bh.
// 128x128 tile, K-step 32 real (96 interleaved), 4 waves each 64x64 out.
// ---------------------------------------------------------------------------
__global__ __launch_bounds__(256) void gemm_mfma_nn(
    const float* __restrict__ A, const float* __restrict__ Bm,
    const float* __restrict__ bias, float* __restrict__ Cm,
    int Kdim, int lda, int ldb, int ldc)
{
    __shared__ unsigned short As[128 * LDT];
    __shared__ unsigned short Bs[128 * LDT];
    const int t    = threadIdx.x;
    const int m0   = blockIdx.y * 128, n0 = blockIdx.x * 128;
    const int lane = t & 63, w = t >> 6;
    const int wm   = (w >> 1) * 64, wn = (w & 1) * 64;
    const int fr   = lane & 15, kg8 = lane >> 4;

    const int arow = t >> 1, akq = t & 1;     // A-stage: row, which 16-k half
    const int bkq  = t >> 5, bnq = t & 31;    // B-stage: k-quad, n-quad

    f32x4 acc[4][4];
    #pragma unroll
    for (int i = 0; i < 4; ++i)
        #pragma unroll
        for (int j = 0; j < 4; ++j)
            acc[i][j] = (f32x4){0.f, 0.f, 0.f, 0.f};

    for (int k0 = 0; k0 < Kdim; k0 += 32) {
        float4 a4[4], b4[4];
        #pragma unroll
        for (int i = 0; i < 4; ++i)
            a4[i] = *(const float4*)&A[(size_t)(m0 + arow) * lda + k0 + akq * 16 + i * 4];
        #pragma unroll
        for (int i = 0; i < 4; ++i)
            b4[i] = *(const float4*)&Bm[(size_t)(k0 + bkq * 4 + i) * ldb + n0 + bnq * 4];

        __syncthreads();   // previous iteration's MFMA reads done

        // ---- A: 16 real k -> 48 bf16 {hi,hi,lo}, contiguous, 6x b128
        {
            unsigned short at[48];
            #pragma unroll
            for (int i = 0; i < 4; ++i) {
                float av[4] = {a4[i].x, a4[i].y, a4[i].z, a4[i].w};
                #pragma unroll
                for (int c = 0; c < 4; ++c) {
                    const int ki = i * 4 + c;
                    unsigned short hi = f2bf(av[c]);
                    unsigned short lo = f2bf(av[c] - bf2f(hi));
                    at[3 * ki + 0] = hi;
                    at[3 * ki + 1] = hi;
                    at[3 * ki + 2] = lo;
                }
            }
            const int base = arow * LDT + akq * 48;
            #pragma unroll
            for (int q = 0; q < 6; ++q)
                *(bf16x8*)&As[base + q * 8] = *(const bf16x8*)&at[q * 8];
        }
        // ---- B: 4 k x 4 n -> per n, 12 bf16 {hi,lo,hi}, 3x b64
        {
            unsigned short bt[4][12];
            #pragma unroll
            for (int i = 0; i < 4; ++i) {
                float bv[4] = {b4[i].x, b4[i].y, b4[i].z, b4[i].w};
                #pragma unroll
                for (int j = 0; j < 4; ++j) {
                    unsigned short hi = f2bf(bv[j]);
                    unsigned short lo = f2bf(bv[j] - bf2f(hi));
                    bt[j][3 * i + 0] = hi;
                    bt[j][3 * i + 1] = lo;
                    bt[j][3 * i + 2] = hi;
                }
            }
            #pragma unroll
            for (int j = 0; j < 4; ++j) {
                const int base = (bnq * 4 + j) * LDT + bkq * 12;
                #pragma unroll
                for (int q = 0; q < 3; ++q)
                    *(short4v*)&Bs[base + q * 4] = *(const short4v*)&bt[j][q * 4];
            }
        }
        __syncthreads();

        #pragma unroll
        for (int kg = 0; kg < 3; ++kg) {
            bf16x8 af[4], bfv[4];
            #pragma unroll
            for (int fm = 0; fm < 4; ++fm)
                af[fm] = *(const bf16x8*)&As[(wm + fm * 16 + fr) * LDT + kg * 32 + kg8 * 8];
            #pragma unroll
            for (int fn = 0; fn < 4; ++fn)
                bfv[fn] = *(const bf16x8*)&Bs[(wn + fn * 16 + fr) * LDT + kg * 32 + kg8 * 8];
            #pragma unroll
            for (int fm = 0; fm < 4; ++fm)
                #pragma unroll
                for (int fn = 0; fn < 4; ++fn)
                    acc[fm][fn] = __builtin_amdgcn_mfma_f32_16x16x32_bf16(
                        af[fm], bfv[fn], acc[fm][fn], 0, 0, 0);
        }
    }

    const int r4 = (lane >> 4) * 4;
    #pragma unroll
    for (int fn = 0; fn < 4; ++fn) {
        const int col = n0 + wn + fn * 16 + fr;
        const float bv = bias[col];
        #pragma unroll
        for (int fm = 0; fm < 4; ++fm) {
            #pragma unroll
            for (int i = 0; i < 4; ++i)
                Cm[(size_t)(m0 + wm + fm * 16 + r4 + i) * ldc + col] =
                    acc[fm][fn][i] + bv;
        }
    }
}

// ---------------------------------------------------------------------------
// Split-bf16 MFMA zscore (NT): z[b,n,m] = (scale/H)*Qc[n,:].Kc[m,:] + gumbel.
// Both operands are k-contiguous qkv rows -> both staged like "A".
// ---------------------------------------------------------------------------
__global__ __launch_bounds__(256) void zscore_mfma(
    const float* __restrict__ qkv, const float* __restrict__ u,
    float* __restrict__ z)
{
    __shared__ unsigned short As[128 * LDT];
    __shared__ unsigned short Bs[128 * LDT];
    const int t    = threadIdx.x;
    const int b    = blockIdx.z;
    const int n0   = blockIdx.y * 128;   // query rows
    const int m0   = blockIdx.x * 128;   // key rows (output cols)
    const int lane = t & 63, w = t >> 6;
    const int wm   = (w >> 1) * 64, wn = (w & 1) * 64;
    const int fr   = lane & 15, kg8 = lane >> 4;
    const int srow = t >> 1, skq = t & 1;

    const float* qbase = qkv + (size_t)b * N_ * 2304;

    f32x4 acc[4][4];
    #pragma unroll
    for (int i = 0; i < 4; ++i)
        #pragma unroll
        for (int j = 0; j < 4; ++j)
            acc[i][j] = (f32x4){0.f, 0.f, 0.f, 0.f};

    for (int k0 = 0; k0 < C_; k0 += 32) {
        float4 a4[4], b4[4];
        #pragma unroll
        for (int i = 0; i < 4; ++i) {
            a4[i] = *(const float4*)&qbase[(size_t)(n0 + srow) * 2304 + k0 + skq * 16 + i * 4];
            b4[i] = *(const float4*)&qbase[(size_t)(m0 + srow) * 2304 + 768 + k0 + skq * 16 + i * 4];
        }

        __syncthreads();
        {
            unsigned short at[48], bt[48];
            #pragma unroll
            for (int i = 0; i < 4; ++i) {
                float av[4] = {a4[i].x, a4[i].y, a4[i].z, a4[i].w};
                float bw[4] = {b4[i].x, b4[i].y, b4[i].z, b4[i].w};
                #pragma unroll
                for (int c = 0; c < 4; ++c) {
                    const int ki = i * 4 + c;
                    unsigned short hi = f2bf(av[c]);
                    unsigned short lo = f2bf(av[c] - bf2f(hi));
                    at[3 * ki + 0] = hi; at[3 * ki + 1] = hi; at[3 * ki + 2] = lo;
                    hi = f2bf(bw[c]);
                    lo = f2bf(bw[c] - bf2f(hi));
                    bt[3 * ki + 0] = hi; bt[3 * ki + 1] = lo; bt[3 * ki + 2] = hi;
                }
            }
            const int base = srow * LDT + skq * 48;
            #pragma unroll
            for (int q = 0; q < 6; ++q) {
                *(bf16x8*)&As[base + q * 8] = *(const bf16x8*)&at[q * 8];
                *(bf16x8*)&Bs[base + q * 8] = *(const bf16x8*)&bt[q * 8];
            }
        }
        __syncthreads();

        #pragma unroll
        for (int kg = 0; kg < 3; ++kg) {
            bf16x8 af[4], bfv[4];
            #pragma unroll
            for (int fm = 0; fm < 4; ++fm)
                af[fm] = *(const bf16x8*)&As[(wm + fm * 16 + fr) * LDT + kg * 32 + kg8 * 8];
            #pragma unroll
            for (int fn = 0; fn < 4; ++fn)
                bfv[fn] = *(const bf16x8*)&Bs[(wn + fn * 16 + fr) * LDT + kg * 32 + kg8 * 8];
            #pragma unroll
            for (int fm = 0; fm < 4; ++fm)
                #pragma unroll
                for (int fn = 0; fn < 4; ++fn)
                    acc[fm][fn] = __builtin_amdgcn_mfma_f32_16x16x32_bf16(
                        af[fm], bfv[fn], acc[fm][fn], 0, 0, 0);
        }
    }

    const float sc = 0.125f / 12.0f;
    const int r4 = (lane >> 4) * 4;
    #pragma unroll
    for (int fn = 0; fn < 4; ++fn) {
        const int m = m0 + wn + fn * 16 + fr;
        #pragma unroll
        for (int fm = 0; fm < 4; ++fm) {
            #pragma unroll
            for (int i = 0; i < 4; ++i) {
                const int n = n0 + wm + fm * 16 + r4 + i;
                const float uv = u[((size_t)(b * N_ + n)) * N_ + m];
                const float g  = -logf(-logf(uv + EPS_) + EPS_);
                z[((size_t)(b * N_ + n)) * N_ + m] = acc[fm][fn][i] * sc + g;
            }
        }
    }
}

// ---------------------------------------------------------------------------
// Per row: exact 32nd-largest of z[row,:]; emit ALL column indices with
// z >= thresh (count-exact, capped at 62). One wave per row, 16 elems/lane.
// ---------------------------------------------------------------------------
__global__ __launch_bounds__(64) void topk_cols_kernel(
    const float* __restrict__ z, TopkRec* __restrict__ recs)
{
    const int row  = blockIdx.x;
    const int lane = threadIdx.x;
    const float* zr = z + (size_t)row * N_;
    float zv[16], wk[16];
    #pragma unroll
    for (int j = 0; j < 16; ++j) { zv[j] = zr[lane + 64 * j]; wk[j] = zv[j]; }

    float thresh = -INFINITY;
    for (int it = 0; it < TOPK_; ++it) {
        float lm = wk[0]; int li = 0;
        #pragma unroll
        for (int j = 1; j < 16; ++j)
            if (wk[j] > lm) { lm = wk[j]; li = j; }
        float gm = lm;
        gm = fmaxf(gm, __shfl_xor(gm, 1));
        gm = fmaxf(gm, __shfl_xor(gm, 2));
        gm = fmaxf(gm, __shfl_xor(gm, 4));
        gm = fmaxf(gm, __shfl_xor(gm, 8));
        gm = fmaxf(gm, __shfl_xor(gm, 16));
        gm = fmaxf(gm, __shfl_xor(gm, 32));
        unsigned long long has = __ballot(lm == gm);
        int first = __ffsll((unsigned long long)has) - 1;
        if (lane == first) wk[li] = -INFINITY;
        thresh = gm;
    }

    const unsigned long long below = ((unsigned long long)1 << lane) - 1;
    unsigned int basec = 0;
    TopkRec* rec = recs + row;
    #pragma unroll
    for (int j = 0; j < 16; ++j) {
        unsigned long long wmask = __ballot(zv[j] >= thresh);
        if (zv[j] >= thresh) {
            unsigned int pos = basec + (unsigned int)__popcll(wmask & below);
            if (pos < 62u) rec->c[pos] = (unsigned short)(lane + 64 * j);
        }
        basec += (unsigned int)__popcll(wmask);
    }
    if (lane == 0) rec->cnt = basec > 62u ? 62u : basec;
}

// ---------------------------------------------------------------------------
// Pass A: per (b,h,row): softmax max m and denominator l over ALL 1024 cols.
// ---------------------------------------------------------------------------
__global__ __launch_bounds__(256) void attn_ml_kernel(
    const float* __restrict__ qkv, float2* __restrict__ ml)
{
    __shared__ float Qs[64][68];    // Qs[d][r]  (transposed)
    __shared__ float Ks[64][68];    // Ks[d][c]  (transposed)

    const int t  = threadIdx.x;
    const int tx = t & 15, ty = t >> 4;
    const int n0 = blockIdx.x * 64;
    const int h  = blockIdx.y;
    const int b  = blockIdx.z;
    const int lr = t >> 2;
    const int dq = (t & 3) * 16;

    #pragma unroll
    for (int qq = 0; qq < 4; ++qq) {
        float4 qv = *(const float4*)
            &qkv[(size_t)(b * N_ + n0 + lr) * 2304 + h * 64 + dq + qq * 4];
        Qs[dq + qq * 4 + 0][lr] = qv.x;
        Qs[dq + qq * 4 + 1][lr] = qv.y;
        Qs[dq + qq * 4 + 2][lr] = qv.z;
        Qs[dq + qq * 4 + 3][lr] = qv.w;
    }

    float mrun[4], lsum[4];
    #pragma unroll
    for (int i = 0; i < 4; ++i) { mrun[i] = -INFINITY; lsum[i] = 0.f; }

    for (int m0 = 0; m0 < N_; m0 += 64) {
        float4 kv[4];
        #pragma unroll
        for (int qq = 0; qq < 4; ++qq)
            kv[qq] = *(const float4*)
                &qkv[(size_t)(b * N_ + m0 + lr) * 2304 + 768 + h * 64 + dq + qq * 4];

        __syncthreads();
        #pragma unroll
        for (int qq = 0; qq < 4; ++qq) {
            Ks[dq + qq * 4 + 0][lr] = kv[qq].x;
            Ks[dq + qq * 4 + 1][lr] = kv[qq].y;
            Ks[dq + qq * 4 + 2][lr] = kv[qq].z;
            Ks[dq + qq * 4 + 3][lr] = kv[qq].w;
        }
        __syncthreads();

        float s[4][4] = {{0.f, 0.f, 0.f, 0.f}, {0.f, 0.f, 0.f, 0.f},
                         {0.f, 0.f, 0.f, 0.f}, {0.f, 0.f, 0.f, 0.f}};
        #pragma unroll 8
        for (int d = 0; d < 64; ++d) {
            float4 a  = *(const float4*)&Qs[d][ty * 4];
            float4 b4 = *(const float4*)&Ks[d][tx * 4];
            float ar[4] = {a.x, a.y, a.z, a.w};
            float br[4] = {b4.x, b4.y, b4.z, b4.w};
            #pragma unroll
            for (int i = 0; i < 4; ++i)
                #pragma unroll
                for (int j = 0; j < 4; ++j)
                    s[i][j] += ar[i] * br[j];
        }

        #pragma unroll
        for (int i = 0; i < 4; ++i) {
            float tmax = fmaxf(fmaxf(s[i][0], s[i][1]), fmaxf(s[i][2], s[i][3]));
            tmax *= 0.125f;
            tmax = fmaxf(tmax, __shfl_xor(tmax, 1));
            tmax = fmaxf(tmax, __shfl_xor(tmax, 2));
            tmax = fmaxf(tmax, __shfl_xor(tmax, 4));
            tmax = fmaxf(tmax, __shfl_xor(tmax, 8));
            float mnew  = fmaxf(mrun[i], tmax);
            float alpha = expf(mrun[i] - mnew);
            float tsum = 0.f;
            #pragma unroll
            for (int j = 0; j < 4; ++j)
                tsum += expf(s[i][j] * 0.125f - mnew);
            tsum += __shfl_xor(tsum, 1);
            tsum += __shfl_xor(tsum, 2);
            tsum += __shfl_xor(tsum, 4);
            tsum += __shfl_xor(tsum, 8);
            lsum[i] = lsum[i] * alpha + tsum;
            mrun[i] = mnew;
        }
    }

    if (tx == 0) {
        #pragma unroll
        for (int i = 0; i < 4; ++i)
            ml[((size_t)(b * H_ + h)) * N_ + n0 + ty * 4 + i] =
                make_float2(mrun[i], lsum[i]);
    }
}

// ---------------------------------------------------------------------------
// Pass B: per (b,n): gather selected columns (head-independent), recompute
// scores, accumulate exp(s-m)/l * v. 4-column batches for reduce-chain ILP.
// ---------------------------------------------------------------------------
__global__ __launch_bounds__(256) void sparse_pv_kernel(
    const float* __restrict__ qkv, const TopkRec* __restrict__ recs,
    const float2* __restrict__ ml, const float* __restrict__ head_scores,
    float* __restrict__ out1)
{
    __shared__ int cols_s[62];
    __shared__ int cnt_s;

    const int t    = threadIdx.x;
    const int lane = t & 63, wv = t >> 6;
    const int row  = blockIdx.x;              // b*N + n
    const int b    = row >> 10, n = row & 1023;

    const TopkRec* rec = recs + row;
    if (t == 0) cnt_s = (int)min(rec->cnt, 62u);
    if (t < 62) cols_s[t] = rec->c[t];

    float hsum = 0.f;
    #pragma unroll
    for (int i = 0; i < H_; ++i) hsum += head_scores[i];
    const float hs_mean = hsum * (1.0f / 12.0f);
    __syncthreads();
    const int cnt = cnt_s;

    const float* qrow   = qkv + (size_t)row * 2304;
    const float* kvbase = qkv + (size_t)b * N_ * 2304;
    for (int h = wv; h < H_; h += 4) {
        const float q = qrow[h * 64 + lane];
        const float2 mlv = ml[((size_t)(b * H_ + h)) * N_ + n];
        float acc = 0.f;
        for (int j0 = 0; j0 < cnt; j0 += 4) {
            int nj = cnt - j0; if (nj > 4) nj = 4;
            float pr[4], vvv[4];
            #pragma unroll
            for (int jj = 0; jj < 4; ++jj) {
                int idx = j0 + jj; if (idx >= cnt) idx = cnt - 1;
                const float* crow = kvbase + (size_t)cols_s[idx] * 2304 + h * 64 + lane;
                pr[jj]  = q * crow[768];
                vvv[jj] = crow[1536];
            }
            #pragma unroll
            for (int d = 1; d < 64; d <<= 1) {
                pr[0] += __shfl_xor(pr[0], d);
                pr[1] += __shfl_xor(pr[1], d);
                pr[2] += __shfl_xor(pr[2], d);
                pr[3] += __shfl_xor(pr[3], d);
            }
            #pragma unroll
            for (int jj = 0; jj < 4; ++jj)
                if (jj < nj) acc += expf(pr[jj] * 0.125f - mlv.x) * vvv[jj];
        }
        out1[(size_t)row * C_ + h * 64 + lane] = acc * (hs_mean / mlv.y);
    }
}

// ---------------------------------------------------------------------------
extern "C" void kernel_launch(void* const* d_in, const int* in_sizes, int n_in,
                              void* d_out, int out_size, void* d_ws, size_t ws_size,
                              hipStream_t stream)
{
    (void)in_sizes; (void)n_in; (void)out_size; (void)ws_size;
    const float* x           = (const float*)d_in[0];
    const float* u           = (const float*)d_in[1];
    const float* qkv_w       = (const float*)d_in[2];
    const float* qkv_b       = (const float*)d_in[3];
    const float* proj_w      = (const float*)d_in[4];
    const float* proj_b      = (const float*)d_in[5];
    const float* head_scores = (const float*)d_in[6];
    float* out = (float*)d_out;

    // Workspace layout (proven 55,050,240-byte footprint):
    //   [0, 37748736)            qkv (fp32)
    //   [37748736, 54525952)     z (16.78 MB); after topk:
    //       out1 = first 12,582,912 B
    //       ml   = +12,582,912 (393,216 B)
    //   [54525952, 55050240)     TopkRec[4096]
    char* ws = (char*)d_ws;
    float*   ws_qkv  = (float*)ws;
    float*   ws_z    = (float*)(ws + 37748736);
    float*   ws_out1 = ws_z;
    float2*  ws_ml   = (float2*)(ws + 37748736 + 12582912);
    TopkRec* ws_rec  = (TopkRec*)(ws + 54525952);

    // 1) qkv = x @ qkv_w + qkv_b   (4096 x 2304 x 768, split-bf16 MFMA)
    gemm_mfma_nn<<<dim3(2304 / 128, 4096 / 128), dim3(256), 0, stream>>>(
        x, qkv_w, qkv_b, ws_qkv, 768, 768, 2304, 2304);

    // 2) z = (scale/H) Qc.Kc^T + gumbel(u)   (split-bf16 MFMA, NT)
    zscore_mfma<<<dim3(8, 8, B_), dim3(256), 0, stream>>>(ws_qkv, u, ws_z);

    // 3) exact top-32 threshold per row -> selected column records
    topk_cols_kernel<<<dim3(B_ * N_), dim3(64), 0, stream>>>(ws_z, ws_rec);

    // 4a) per-head softmax max + denominator over all columns
    attn_ml_kernel<<<dim3(16, H_, B_), dim3(256), 0, stream>>>(ws_qkv, ws_ml);

    // 4b) sparse gather numerator -> out1
    sparse_pv_kernel<<<dim3(B_ * N_), dim3(256), 0, stream>>>(
        ws_qkv, ws_rec, ws_ml, head_scores, ws_out1);

    // 5) out = out1 @ proj_w + proj_b   (split-bf16 MFMA)
    gemm_mfma_nn<<<dim3(768 / 128, 4096 / 128), dim3(256), 0, stream>>>(
        ws_out1, proj_w, proj_b, out, 768, 768, 768, 768);
}

// Round 5
// 445.406 us; speedup vs baseline: 1.4231x; 1.1471x over previous
//
#include <hip/hip_runtime.h>
#include <hip/hip_bf16.h>
#include <math.h>

#define B_ 4
#define N_ 1024
#define C_ 768
#define H_ 12
#define D_ 64
#define TOPK_ 32
#define EPS_ 1e-9f

#define LDA_ 40   // LDS row stride (bf16 elems): 32 used + 8 pad = 80 B

typedef __attribute__((ext_vector_type(8))) short bf16x8;
typedef __attribute__((ext_vector_type(4))) float f32x4;
typedef unsigned short u16;

struct TopkRec { unsigned int cnt; unsigned short c[62]; };  // 128 B

__device__ __forceinline__ u16 f2bf(float f) {
    unsigned int u = __float_as_uint(f);
    u += 0x7fffu + ((u >> 16) & 1u);
    return (u16)(u >> 16);
}
__device__ __forceinline__ float bf2f(u16 h) {
    return __uint_as_float(((unsigned int)h) << 16);
}

// ---------------------------------------------------------------------------
// Weight convert: W f32 [K][Ncols] -> Wt_h, Wt_l bf16 [Ncols][K] (transposed
// hi/lo split). 64x64 LDS tile.
// ---------------------------------------------------------------------------
__global__ __launch_bounds__(256) void conv_w_nt(
    const float* __restrict__ W, u16* __restrict__ Wt_h, u16* __restrict__ Wt_l,
    int Kdim, int Ncols)
{
    __shared__ float Ts[64][65];
    const int t  = threadIdx.x;
    const int r  = t >> 2;            // 0..63
    const int cq = (t & 3) * 16;      // 0,16,32,48
    const int n0 = blockIdx.x * 64, k0 = blockIdx.y * 64;

    #pragma unroll
    for (int q = 0; q < 4; ++q) {
        float4 v = *(const float4*)&W[(size_t)(k0 + r) * Ncols + n0 + cq + q * 4];
        Ts[r][cq + q * 4 + 0] = v.x;
        Ts[r][cq + q * 4 + 1] = v.y;
        Ts[r][cq + q * 4 + 2] = v.z;
        Ts[r][cq + q * 4 + 3] = v.w;
    }
    __syncthreads();
    u16 hb[16], lb[16];
    #pragma unroll
    for (int i = 0; i < 16; ++i) {
        float val = Ts[cq + i][r];          // transpose
        u16 hi = f2bf(val);
        hb[i] = hi;
        lb[i] = f2bf(val - bf2f(hi));
    }
    const size_t obase = (size_t)(n0 + r) * Kdim + k0 + cq;
    *(bf16x8*)&Wt_h[obase]     = *(const bf16x8*)&hb[0];
    *(bf16x8*)&Wt_h[obase + 8] = *(const bf16x8*)&hb[8];
    *(bf16x8*)&Wt_l[obase]     = *(const bf16x8*)&lb[0];
    *(bf16x8*)&Wt_l[obase + 8] = *(const bf16x8*)&lb[8];
}

// ---------------------------------------------------------------------------
// qkv GEMM: qkv = x @ qkv_w + b, written as hi/lo bf16 planes.
// A = x f32 (in-reg split during staging), B = pre-split W^T planes (NT).
// 128x128 tile, BK=32 real, 3-term split: Ah.Bh + Ah.Bl + Al.Bh.
// ---------------------------------------------------------------------------
__global__ __launch_bounds__(256) void gemm_qkv(
    const float* __restrict__ A, const u16* __restrict__ Bth,
    const u16* __restrict__ Btl, const float* __restrict__ bias,
    u16* __restrict__ Ch, u16* __restrict__ Cl)
{
    __shared__ u16 Ah[128 * LDA_], Al[128 * LDA_];
    __shared__ u16 Bh[128 * LDA_], Bl[128 * LDA_];
    const int t    = threadIdx.x;
    const int m0   = blockIdx.y * 128, n0 = blockIdx.x * 128;
    const int lane = t & 63, w = t >> 6;
    const int wm   = (w >> 1) * 64, wn = (w & 1) * 64;
    const int fr   = lane & 15, kg8 = lane >> 4;
    const int srow = t >> 1, shalf = t & 1;       // staging: row, 16-k half

    f32x4 acc[4][4];
    #pragma unroll
    for (int i = 0; i < 4; ++i)
        #pragma unroll
        for (int j = 0; j < 4; ++j)
            acc[i][j] = (f32x4){0.f, 0.f, 0.f, 0.f};

    for (int k0 = 0; k0 < C_; k0 += 32) {
        float4 a4[4];
        #pragma unroll
        for (int q = 0; q < 4; ++q)
            a4[q] = *(const float4*)&A[(size_t)(m0 + srow) * C_ + k0 + shalf * 16 + q * 4];
        const size_t bbase = (size_t)(n0 + srow) * C_ + k0 + shalf * 16;
        bf16x8 bh0 = *(const bf16x8*)&Bth[bbase];
        bf16x8 bh1 = *(const bf16x8*)&Bth[bbase + 8];
        bf16x8 bl0 = *(const bf16x8*)&Btl[bbase];
        bf16x8 bl1 = *(const bf16x8*)&Btl[bbase + 8];

        u16 ah[16], al[16];
        #pragma unroll
        for (int q = 0; q < 4; ++q) {
            float av[4] = {a4[q].x, a4[q].y, a4[q].z, a4[q].w};
            #pragma unroll
            for (int c = 0; c < 4; ++c) {
                u16 hi = f2bf(av[c]);
                ah[q * 4 + c] = hi;
                al[q * 4 + c] = f2bf(av[c] - bf2f(hi));
            }
        }

        __syncthreads();
        const int sb = srow * LDA_ + shalf * 16;
        *(bf16x8*)&Ah[sb]     = *(const bf16x8*)&ah[0];
        *(bf16x8*)&Ah[sb + 8] = *(const bf16x8*)&ah[8];
        *(bf16x8*)&Al[sb]     = *(const bf16x8*)&al[0];
        *(bf16x8*)&Al[sb + 8] = *(const bf16x8*)&al[8];
        *(bf16x8*)&Bh[sb]     = bh0;
        *(bf16x8*)&Bh[sb + 8] = bh1;
        *(bf16x8*)&Bl[sb]     = bl0;
        *(bf16x8*)&Bl[sb + 8] = bl1;
        __syncthreads();

        bf16x8 aF[4], bF[4], a2F[4], b2F[4];
        #pragma unroll
        for (int fm = 0; fm < 4; ++fm)
            aF[fm] = *(const bf16x8*)&Ah[(wm + fm * 16 + fr) * LDA_ + kg8 * 8];
        #pragma unroll
        for (int fn = 0; fn < 4; ++fn)
            bF[fn] = *(const bf16x8*)&Bh[(wn + fn * 16 + fr) * LDA_ + kg8 * 8];
        #pragma unroll
        for (int fm = 0; fm < 4; ++fm)
            #pragma unroll
            for (int fn = 0; fn < 4; ++fn)
                acc[fm][fn] = __builtin_amdgcn_mfma_f32_16x16x32_bf16(
                    aF[fm], bF[fn], acc[fm][fn], 0, 0, 0);
        #pragma unroll
        for (int fn = 0; fn < 4; ++fn)
            b2F[fn] = *(const bf16x8*)&Bl[(wn + fn * 16 + fr) * LDA_ + kg8 * 8];
        #pragma unroll
        for (int fm = 0; fm < 4; ++fm)
            #pragma unroll
            for (int fn = 0; fn < 4; ++fn)
                acc[fm][fn] = __builtin_amdgcn_mfma_f32_16x16x32_bf16(
                    aF[fm], b2F[fn], acc[fm][fn], 0, 0, 0);
        #pragma unroll
        for (int fm = 0; fm < 4; ++fm)
            a2F[fm] = *(const bf16x8*)&Al[(wm + fm * 16 + fr) * LDA_ + kg8 * 8];
        #pragma unroll
        for (int fm = 0; fm < 4; ++fm)
            #pragma unroll
            for (int fn = 0; fn < 4; ++fn)
                acc[fm][fn] = __builtin_amdgcn_mfma_f32_16x16x32_bf16(
                    a2F[fm], bF[fn], acc[fm][fn], 0, 0, 0);
    }

    const int r4 = (lane >> 4) * 4;
    #pragma unroll
    for (int fn = 0; fn < 4; ++fn) {
        const int col = n0 + wn + fn * 16 + fr;
        const float bv = bias[col];
        #pragma unroll
        for (int fm = 0; fm < 4; ++fm)
            #pragma unroll
            for (int i = 0; i < 4; ++i) {
                const size_t o = (size_t)(m0 + wm + fm * 16 + r4 + i) * 2304 + col;
                float val = acc[fm][fn][i] + bv;
                u16 hi = f2bf(val);
                Ch[o] = hi;
                Cl[o] = f2bf(val - bf2f(hi));
            }
    }
}

// ---------------------------------------------------------------------------
// zscore (NT, both operands from qkv planes, no conversion):
// z[b,n,m] = (scale/H) * Qc[n,:].Kc[m,:] + gumbel(u).
// ---------------------------------------------------------------------------
__global__ __launch_bounds__(256) void zscore_mfma(
    const u16* __restrict__ Qh, const u16* __restrict__ Ql,
    const float* __restrict__ u, float* __restrict__ z)
{
    __shared__ u16 Ah[128 * LDA_], Al[128 * LDA_];
    __shared__ u16 Bh[128 * LDA_], Bl[128 * LDA_];
    const int t    = threadIdx.x;
    const int b    = blockIdx.z;
    const int n0   = blockIdx.y * 128, m0 = blockIdx.x * 128;
    const int lane = t & 63, w = t >> 6;
    const int wm   = (w >> 1) * 64, wn = (w & 1) * 64;
    const int fr   = lane & 15, kg8 = lane >> 4;
    const int srow = t >> 1, shalf = t & 1;

    f32x4 acc[4][4];
    #pragma unroll
    for (int i = 0; i < 4; ++i)
        #pragma unroll
        for (int j = 0; j < 4; ++j)
            acc[i][j] = (f32x4){0.f, 0.f, 0.f, 0.f};

    for (int k0 = 0; k0 < C_; k0 += 32) {
        const size_t abase = (size_t)(b * N_ + n0 + srow) * 2304 + k0 + shalf * 16;
        const size_t bbase = (size_t)(b * N_ + m0 + srow) * 2304 + 768 + k0 + shalf * 16;
        bf16x8 ah0 = *(const bf16x8*)&Qh[abase];
        bf16x8 ah1 = *(const bf16x8*)&Qh[abase + 8];
        bf16x8 al0 = *(const bf16x8*)&Ql[abase];
        bf16x8 al1 = *(const bf16x8*)&Ql[abase + 8];
        bf16x8 bh0 = *(const bf16x8*)&Qh[bbase];
        bf16x8 bh1 = *(const bf16x8*)&Qh[bbase + 8];
        bf16x8 bl0 = *(const bf16x8*)&Ql[bbase];
        bf16x8 bl1 = *(const bf16x8*)&Ql[bbase + 8];

        __syncthreads();
        const int sb = srow * LDA_ + shalf * 16;
        *(bf16x8*)&Ah[sb]     = ah0;  *(bf16x8*)&Ah[sb + 8] = ah1;
        *(bf16x8*)&Al[sb]     = al0;  *(bf16x8*)&Al[sb + 8] = al1;
        *(bf16x8*)&Bh[sb]     = bh0;  *(bf16x8*)&Bh[sb + 8] = bh1;
        *(bf16x8*)&Bl[sb]     = bl0;  *(bf16x8*)&Bl[sb + 8] = bl1;
        __syncthreads();

        bf16x8 aF[4], bF[4], a2F[4], b2F[4];
        #pragma unroll
        for (int fm = 0; fm < 4; ++fm)
            aF[fm] = *(const bf16x8*)&Ah[(wm + fm * 16 + fr) * LDA_ + kg8 * 8];
        #pragma unroll
        for (int fn = 0; fn < 4; ++fn)
            bF[fn] = *(const bf16x8*)&Bh[(wn + fn * 16 + fr) * LDA_ + kg8 * 8];
        #pragma unroll
        for (int fm = 0; fm < 4; ++fm)
            #pragma unroll
            for (int fn = 0; fn < 4; ++fn)
                acc[fm][fn] = __builtin_amdgcn_mfma_f32_16x16x32_bf16(
                    aF[fm], bF[fn], acc[fm][fn], 0, 0, 0);
        #pragma unroll
        for (int fn = 0; fn < 4; ++fn)
            b2F[fn] = *(const bf16x8*)&Bl[(wn + fn * 16 + fr) * LDA_ + kg8 * 8];
        #pragma unroll
        for (int fm = 0; fm < 4; ++fm)
            #pragma unroll
            for (int fn = 0; fn < 4; ++fn)
                acc[fm][fn] = __builtin_amdgcn_mfma_f32_16x16x32_bf16(
                    aF[fm], b2F[fn], acc[fm][fn], 0, 0, 0);
        #pragma unroll
        for (int fm = 0; fm < 4; ++fm)
            a2F[fm] = *(const bf16x8*)&Al[(wm + fm * 16 + fr) * LDA_ + kg8 * 8];
        #pragma unroll
        for (int fm = 0; fm < 4; ++fm)
            #pragma unroll
            for (int fn = 0; fn < 4; ++fn)
                acc[fm][fn] = __builtin_amdgcn_mfma_f32_16x16x32_bf16(
                    a2F[fm], bF[fn], acc[fm][fn], 0, 0, 0);
    }

    const float sc = 0.125f / 12.0f;
    const int r4 = (lane >> 4) * 4;
    #pragma unroll
    for (int fn = 0; fn < 4; ++fn) {
        const int m = m0 + wn + fn * 16 + fr;
        #pragma unroll
        for (int fm = 0; fm < 4; ++fm)
            #pragma unroll
            for (int i = 0; i < 4; ++i) {
                const int n = n0 + wm + fm * 16 + r4 + i;
                const float uv = u[((size_t)(b * N_ + n)) * N_ + m];
                const float g  = -logf(-logf(uv + EPS_) + EPS_);
                z[((size_t)(b * N_ + n)) * N_ + m] = acc[fm][fn][i] * sc + g;
            }
    }
}

// ---------------------------------------------------------------------------
// Per row: exact 32nd-largest of z; emit all cols >= thresh (cap 62).
// ---------------------------------------------------------------------------
__global__ __launch_bounds__(64) void topk_cols_kernel(
    const float* __restrict__ z, TopkRec* __restrict__ recs)
{
    const int row  = blockIdx.x;
    const int lane = threadIdx.x;
    const float* zr = z + (size_t)row * N_;
    float zv[16], wk[16];
    #pragma unroll
    for (int j = 0; j < 16; ++j) { zv[j] = zr[lane + 64 * j]; wk[j] = zv[j]; }

    float thresh = -INFINITY;
    for (int it = 0; it < TOPK_; ++it) {
        float lm = wk[0]; int li = 0;
        #pragma unroll
        for (int j = 1; j < 16; ++j)
            if (wk[j] > lm) { lm = wk[j]; li = j; }
        float gm = lm;
        gm = fmaxf(gm, __shfl_xor(gm, 1));
        gm = fmaxf(gm, __shfl_xor(gm, 2));
        gm = fmaxf(gm, __shfl_xor(gm, 4));
        gm = fmaxf(gm, __shfl_xor(gm, 8));
        gm = fmaxf(gm, __shfl_xor(gm, 16));
        gm = fmaxf(gm, __shfl_xor(gm, 32));
        unsigned long long has = __ballot(lm == gm);
        int first = __ffsll((unsigned long long)has) - 1;
        if (lane == first) wk[li] = -INFINITY;
        thresh = gm;
    }

    const unsigned long long below = ((unsigned long long)1 << lane) - 1;
    unsigned int basec = 0;
    TopkRec* rec = recs + row;
    #pragma unroll
    for (int j = 0; j < 16; ++j) {
        unsigned long long wmask = __ballot(zv[j] >= thresh);
        if (zv[j] >= thresh) {
            unsigned int pos = basec + (unsigned int)__popcll(wmask & below);
            if (pos < 62u) rec->c[pos] = (unsigned short)(lane + 64 * j);
        }
        basec += (unsigned int)__popcll(wmask);
    }
    if (lane == 0) rec->cnt = basec > 62u ? 62u : basec;
}

// ---------------------------------------------------------------------------
// Pass A: per (b,h,row): softmax max m and denominator l over all 1024 cols.
// Q/K reconstructed from hi/lo planes during staging.
// ---------------------------------------------------------------------------
__global__ __launch_bounds__(256) void attn_ml_kernel(
    const u16* __restrict__ qh, const u16* __restrict__ ql,
    float2* __restrict__ ml)
{
    __shared__ float Qs[64][68];
    __shared__ float Ks[64][68];

    const int t  = threadIdx.x;
    const int tx = t & 15, ty = t >> 4;
    const int n0 = blockIdx.x * 64;
    const int hd = blockIdx.y;
    const int b  = blockIdx.z;
    const int lr = t >> 2;
    const int dq = (t & 3) * 16;

    {
        const size_t qb = (size_t)(b * N_ + n0 + lr) * 2304 + hd * 64 + dq;
        bf16x8 h0 = *(const bf16x8*)&qh[qb],     h1 = *(const bf16x8*)&qh[qb + 8];
        bf16x8 l0 = *(const bf16x8*)&ql[qb],     l1 = *(const bf16x8*)&ql[qb + 8];
        #pragma unroll
        for (int i = 0; i < 8; ++i) {
            Qs[dq + i][lr]     = bf2f((u16)h0[i]) + bf2f((u16)l0[i]);
            Qs[dq + 8 + i][lr] = bf2f((u16)h1[i]) + bf2f((u16)l1[i]);
        }
    }

    float mrun[4], lsum[4];
    #pragma unroll
    for (int i = 0; i < 4; ++i) { mrun[i] = -INFINITY; lsum[i] = 0.f; }

    for (int m0 = 0; m0 < N_; m0 += 64) {
        const size_t kb = (size_t)(b * N_ + m0 + lr) * 2304 + 768 + hd * 64 + dq;
        bf16x8 h0 = *(const bf16x8*)&qh[kb],     h1 = *(const bf16x8*)&qh[kb + 8];
        bf16x8 l0 = *(const bf16x8*)&ql[kb],     l1 = *(const bf16x8*)&ql[kb + 8];

        __syncthreads();
        #pragma unroll
        for (int i = 0; i < 8; ++i) {
            Ks[dq + i][lr]     = bf2f((u16)h0[i]) + bf2f((u16)l0[i]);
            Ks[dq + 8 + i][lr] = bf2f((u16)h1[i]) + bf2f((u16)l1[i]);
        }
        __syncthreads();

        float s[4][4] = {{0.f, 0.f, 0.f, 0.f}, {0.f, 0.f, 0.f, 0.f},
                         {0.f, 0.f, 0.f, 0.f}, {0.f, 0.f, 0.f, 0.f}};
        #pragma unroll 8
        for (int d = 0; d < 64; ++d) {
            float4 a  = *(const float4*)&Qs[d][ty * 4];
            float4 b4 = *(const float4*)&Ks[d][tx * 4];
            float ar[4] = {a.x, a.y, a.z, a.w};
            float br[4] = {b4.x, b4.y, b4.z, b4.w};
            #pragma unroll
            for (int i = 0; i < 4; ++i)
                #pragma unroll
                for (int j = 0; j < 4; ++j)
                    s[i][j] += ar[i] * br[j];
        }

        #pragma unroll
        for (int i = 0; i < 4; ++i) {
            float tmax = fmaxf(fmaxf(s[i][0], s[i][1]), fmaxf(s[i][2], s[i][3]));
            tmax *= 0.125f;
            tmax = fmaxf(tmax, __shfl_xor(tmax, 1));
            tmax = fmaxf(tmax, __shfl_xor(tmax, 2));
            tmax = fmaxf(tmax, __shfl_xor(tmax, 4));
            tmax = fmaxf(tmax, __shfl_xor(tmax, 8));
            float mnew  = fmaxf(mrun[i], tmax);
            float alpha = expf(mrun[i] - mnew);
            float tsum = 0.f;
            #pragma unroll
            for (int j = 0; j < 4; ++j)
                tsum += expf(s[i][j] * 0.125f - mnew);
            tsum += __shfl_xor(tsum, 1);
            tsum += __shfl_xor(tsum, 2);
            tsum += __shfl_xor(tsum, 4);
            tsum += __shfl_xor(tsum, 8);
            lsum[i] = lsum[i] * alpha + tsum;
            mrun[i] = mnew;
        }
    }

    if (tx == 0) {
        #pragma unroll
        for (int i = 0; i < 4; ++i)
            ml[((size_t)(b * H_ + hd)) * N_ + n0 + ty * 4 + i] =
                make_float2(mrun[i], lsum[i]);
    }
}

// ---------------------------------------------------------------------------
// Pass B: sparse gather numerator; writes out1 as hi/lo planes for proj GEMM.
// ---------------------------------------------------------------------------
__global__ __launch_bounds__(256) void sparse_pv_kernel(
    const u16* __restrict__ qh, const u16* __restrict__ ql,
    const TopkRec* __restrict__ recs, const float2* __restrict__ ml,
    const float* __restrict__ head_scores,
    u16* __restrict__ out1h, u16* __restrict__ out1l)
{
    __shared__ int cols_s[62];
    __shared__ int cnt_s;

    const int t    = threadIdx.x;
    const int lane = t & 63, wv = t >> 6;
    const int row  = blockIdx.x;              // b*N + n
    const int b    = row >> 10, n = row & 1023;

    const TopkRec* rec = recs + row;
    if (t == 0) cnt_s = (int)min(rec->cnt, 62u);
    if (t < 62) cols_s[t] = rec->c[t];

    float hsum = 0.f;
    #pragma unroll
    for (int i = 0; i < H_; ++i) hsum += head_scores[i];
    const float hs_mean = hsum * (1.0f / 12.0f);
    __syncthreads();
    const int cnt = cnt_s;

    for (int hd = wv; hd < H_; hd += 4) {
        const size_t qb = (size_t)row * 2304 + hd * 64 + lane;
        const float q = bf2f(qh[qb]) + bf2f(ql[qb]);
        const float2 mlv = ml[((size_t)(b * H_ + hd)) * N_ + n];
        float acc = 0.f;
        for (int j0 = 0; j0 < cnt; j0 += 4) {
            int nj = cnt - j0; if (nj > 4) nj = 4;
            float pr[4], vvv[4];
            #pragma unroll
            for (int jj = 0; jj < 4; ++jj) {
                int idx = j0 + jj; if (idx >= cnt) idx = cnt - 1;
                const size_t cb = (size_t)(b * N_ + cols_s[idx]) * 2304 + hd * 64 + lane;
                pr[jj]  = q * (bf2f(qh[cb + 768]) + bf2f(ql[cb + 768]));
                vvv[jj] = bf2f(qh[cb + 1536]) + bf2f(ql[cb + 1536]);
            }
            #pragma unroll
            for (int d = 1; d < 64; d <<= 1) {
                pr[0] += __shfl_xor(pr[0], d);
                pr[1] += __shfl_xor(pr[1], d);
                pr[2] += __shfl_xor(pr[2], d);
                pr[3] += __shfl_xor(pr[3], d);
            }
            #pragma unroll
            for (int jj = 0; jj < 4; ++jj)
                if (jj < nj) acc += expf(pr[jj] * 0.125f - mlv.x) * vvv[jj];
        }
        const float val = acc * (hs_mean / mlv.y);
        const u16 hi = f2bf(val);
        out1h[(size_t)row * C_ + hd * 64 + lane] = hi;
        out1l[(size_t)row * C_ + hd * 64 + lane] = f2bf(val - bf2f(hi));
    }
}

// ---------------------------------------------------------------------------
// proj GEMM: out = out1 @ proj_w + b (f32 out). A = out1 planes, B = W^T
// planes (NT). Pure-bf16, no in-loop conversion.
// ---------------------------------------------------------------------------
__global__ __launch_bounds__(256) void gemm_proj(
    const u16* __restrict__ Ath, const u16* __restrict__ Atl,
    const u16* __restrict__ Bth, const u16* __restrict__ Btl,
    const float* __restrict__ bias, float* __restrict__ Cm)
{
    __shared__ u16 Ah[128 * LDA_], Al[128 * LDA_];
    __shared__ u16 Bh[128 * LDA_], Bl[128 * LDA_];
    const int t    = threadIdx.x;
    const int m0   = blockIdx.y * 128, n0 = blockIdx.x * 128;
    const int lane = t & 63, w = t >> 6;
    const int wm   = (w >> 1) * 64, wn = (w & 1) * 64;
    const int fr   = lane & 15, kg8 = lane >> 4;
    const int srow = t >> 1, shalf = t & 1;

    f32x4 acc[4][4];
    #pragma unroll
    for (int i = 0; i < 4; ++i)
        #pragma unroll
        for (int j = 0; j < 4; ++j)
            acc[i][j] = (f32x4){0.f, 0.f, 0.f, 0.f};

    for (int k0 = 0; k0 < C_; k0 += 32) {
        const size_t abase = (size_t)(m0 + srow) * C_ + k0 + shalf * 16;
        const size_t bbase = (size_t)(n0 + srow) * C_ + k0 + shalf * 16;
        bf16x8 ah0 = *(const bf16x8*)&Ath[abase];
        bf16x8 ah1 = *(const bf16x8*)&Ath[abase + 8];
        bf16x8 al0 = *(const bf16x8*)&Atl[abase];
        bf16x8 al1 = *(const bf16x8*)&Atl[abase + 8];
        bf16x8 bh0 = *(const bf16x8*)&Bth[bbase];
        bf16x8 bh1 = *(const bf16x8*)&Bth[bbase + 8];
        bf16x8 bl0 = *(const bf16x8*)&Btl[bbase];
        bf16x8 bl1 = *(const bf16x8*)&Btl[bbase + 8];

        __syncthreads();
        const int sb = srow * LDA_ + shalf * 16;
        *(bf16x8*)&Ah[sb]     = ah0;  *(bf16x8*)&Ah[sb + 8] = ah1;
        *(bf16x8*)&Al[sb]     = al0;  *(bf16x8*)&Al[sb + 8] = al1;
        *(bf16x8*)&Bh[sb]     = bh0;  *(bf16x8*)&Bh[sb + 8] = bh1;
        *(bf16x8*)&Bl[sb]     = bl0;  *(bf16x8*)&Bl[sb + 8] = bl1;
        __syncthreads();

        bf16x8 aF[4], bF[4], a2F[4], b2F[4];
        #pragma unroll
        for (int fm = 0; fm < 4; ++fm)
            aF[fm] = *(const bf16x8*)&Ah[(wm + fm * 16 + fr) * LDA_ + kg8 * 8];
        #pragma unroll
        for (int fn = 0; fn < 4; ++fn)
            bF[fn] = *(const bf16x8*)&Bh[(wn + fn * 16 + fr) * LDA_ + kg8 * 8];
        #pragma unroll
        for (int fm = 0; fm < 4; ++fm)
            #pragma unroll
            for (int fn = 0; fn < 4; ++fn)
                acc[fm][fn] = __builtin_amdgcn_mfma_f32_16x16x32_bf16(
                    aF[fm], bF[fn], acc[fm][fn], 0, 0, 0);
        #pragma unroll
        for (int fn = 0; fn < 4; ++fn)
            b2F[fn] = *(const bf16x8*)&Bl[(wn + fn * 16 + fr) * LDA_ + kg8 * 8];
        #pragma unroll
        for (int fm = 0; fm < 4; ++fm)
            #pragma unroll
            for (int fn = 0; fn < 4; ++fn)
                acc[fm][fn] = __builtin_amdgcn_mfma_f32_16x16x32_bf16(
                    aF[fm], b2F[fn], acc[fm][fn], 0, 0, 0);
        #pragma unroll
        for (int fm = 0; fm < 4; ++fm)
            a2F[fm] = *(const bf16x8*)&Al[(wm + fm * 16 + fr) * LDA_ + kg8 * 8];
        #pragma unroll
        for (int fm = 0; fm < 4; ++fm)
            #pragma unroll
            for (int fn = 0; fn < 4; ++fn)
                acc[fm][fn] = __builtin_amdgcn_mfma_f32_16x16x32_bf16(
                    a2F[fm], bF[fn], acc[fm][fn], 0, 0, 0);
    }

    const int r4 = (lane >> 4) * 4;
    #pragma unroll
    for (int fn = 0; fn < 4; ++fn) {
        const int col = n0 + wn + fn * 16 + fr;
        const float bv = bias[col];
        #pragma unroll
        for (int fm = 0; fm < 4; ++fm)
            #pragma unroll
            for (int i = 0; i < 4; ++i)
                Cm[(size_t)(m0 + wm + fm * 16 + r4 + i) * C_ + col] =
                    acc[fm][fn][i] + bv;
    }
}

// ---------------------------------------------------------------------------
extern "C" void kernel_launch(void* const* d_in, const int* in_sizes, int n_in,
                              void* d_out, int out_size, void* d_ws, size_t ws_size,
                              hipStream_t stream)
{
    (void)in_sizes; (void)n_in; (void)out_size; (void)ws_size;
    const float* x           = (const float*)d_in[0];
    const float* u           = (const float*)d_in[1];
    const float* qkv_w       = (const float*)d_in[2];
    const float* qkv_b       = (const float*)d_in[3];
    const float* proj_w      = (const float*)d_in[4];
    const float* proj_b      = (const float*)d_in[5];
    const float* head_scores = (const float*)d_in[6];
    float* out = (float*)d_out;

    // Workspace (proven 55,050,240-byte footprint), time-shared tail region:
    //   [0, 18874368)            qkv_h  bf16 [4096][2304]
    //   [18874368, 37748736)     qkv_l
    //   R = [37748736, 55050240) (17,301,504 B):
    //     phase1 (pre-qkv-GEMM): wq_t_h (3,538,944) | wq_t_l (3,538,944)
    //     phase2 (zscore->topk): z f32 (16,777,216 overlaps wq planes, dead)
    //                            recs (524,288) at R+16,777,216 (tail, exact)
    //     phase3 (post-topk, z dead): wp_t_h (1,179,648) | wp_t_l (1,179,648)
    //                            | ml (393,216) | out1_h (6,291,456)
    //                            | out1_l (6,291,456)  = 15,335,424 <= z size
    char* ws = (char*)d_ws;
    u16*     qkv_h  = (u16*)ws;
    u16*     qkv_l  = (u16*)(ws + 18874368);
    char*    R      = ws + 37748736;
    u16*     wq_t_h = (u16*)R;
    u16*     wq_t_l = (u16*)(R + 3538944);
    float*   z      = (float*)R;
    TopkRec* recs   = (TopkRec*)(R + 16777216);
    u16*     wp_t_h = (u16*)R;
    u16*     wp_t_l = (u16*)(R + 1179648);
    float2*  ml     = (float2*)(R + 2359296);
    u16*     out1h  = (u16*)(R + 2752512);
    u16*     out1l  = (u16*)(R + 9043968);

    // 1) convert qkv_w -> transposed split planes [2304][768]
    conv_w_nt<<<dim3(2304 / 64, 768 / 64), dim3(256), 0, stream>>>(
        qkv_w, wq_t_h, wq_t_l, 768, 2304);

    // 2) qkv = x @ qkv_w + b  -> hi/lo planes
    gemm_qkv<<<dim3(2304 / 128, 4096 / 128), dim3(256), 0, stream>>>(
        x, wq_t_h, wq_t_l, qkv_b, qkv_h, qkv_l);

    // 3) z = (scale/H) Qc.Kc^T + gumbel(u)   [overwrites wq planes: dead]
    zscore_mfma<<<dim3(8, 8, B_), dim3(256), 0, stream>>>(qkv_h, qkv_l, u, z);

    // 4) exact top-32 -> column records
    topk_cols_kernel<<<dim3(B_ * N_), dim3(64), 0, stream>>>(z, recs);

    // 5) convert proj_w -> transposed split planes [768][768]  (z now dead)
    conv_w_nt<<<dim3(768 / 64, 768 / 64), dim3(256), 0, stream>>>(
        proj_w, wp_t_h, wp_t_l, 768, 768);

    // 6) per-head softmax max + denominator
    attn_ml_kernel<<<dim3(16, H_, B_), dim3(256), 0, stream>>>(qkv_h, qkv_l, ml);

    // 7) sparse gather numerator -> out1 planes
    sparse_pv_kernel<<<dim3(B_ * N_), dim3(256), 0, stream>>>(
        qkv_h, qkv_l, recs, ml, head_scores, out1h, out1l);

    // 8) out = out1 @ proj_w + b
    gemm_proj<<<dim3(768 / 128, 4096 / 128), dim3(256), 0, stream>>>(
        out1h, out1l, wp_t_h, wp_t_l, proj_b, out);
}

// Round 6
// 371.058 us; speedup vs baseline: 1.7082x; 1.2004x over previous
//
#include <hip/hip_runtime.h>
#include <hip/hip_bf16.h>
#include <math.h>

#define B_ 4
#define N_ 1024
#define C_ 768
#define H_ 12
#define D_ 64
#define TOPK_ 32
#define EPS_ 1e-9f

#define LDA_ 40   // GEMM LDS row stride (bf16 elems): 32 used + 8 pad = 80 B
#define LK_  72   // attn LDS row stride: 64 used + 8 pad = 144 B (2-way = free)

typedef __attribute__((ext_vector_type(8))) short bf16x8;
typedef __attribute__((ext_vector_type(4))) float f32x4;
typedef unsigned short u16;

struct TopkRec { unsigned int cnt; unsigned short c[62]; };  // 128 B

__device__ __forceinline__ u16 f2bf(float f) {
    unsigned int u = __float_as_uint(f);
    u += 0x7fffu + ((u >> 16) & 1u);
    return (u16)(u >> 16);
}
__device__ __forceinline__ float bf2f(u16 h) {
    return __uint_as_float(((unsigned int)h) << 16);
}

// ---------------------------------------------------------------------------
// Weight convert: W f32 [K][Ncols] -> Wt_h, Wt_l bf16 [Ncols][K] (transposed
// hi/lo split). 64x64 LDS tile.
// ---------------------------------------------------------------------------
__global__ __launch_bounds__(256) void conv_w_nt(
    const float* __restrict__ W, u16* __restrict__ Wt_h, u16* __restrict__ Wt_l,
    int Kdim, int Ncols)
{
    __shared__ float Ts[64][65];
    const int t  = threadIdx.x;
    const int r  = t >> 2;            // 0..63
    const int cq = (t & 3) * 16;      // 0,16,32,48
    const int n0 = blockIdx.x * 64, k0 = blockIdx.y * 64;

    #pragma unroll
    for (int q = 0; q < 4; ++q) {
        float4 v = *(const float4*)&W[(size_t)(k0 + r) * Ncols + n0 + cq + q * 4];
        Ts[r][cq + q * 4 + 0] = v.x;
        Ts[r][cq + q * 4 + 1] = v.y;
        Ts[r][cq + q * 4 + 2] = v.z;
        Ts[r][cq + q * 4 + 3] = v.w;
    }
    __syncthreads();
    u16 hb[16], lb[16];
    #pragma unroll
    for (int i = 0; i < 16; ++i) {
        float val = Ts[cq + i][r];          // transpose
        u16 hi = f2bf(val);
        hb[i] = hi;
        lb[i] = f2bf(val - bf2f(hi));
    }
    const size_t obase = (size_t)(n0 + r) * Kdim + k0 + cq;
    *(bf16x8*)&Wt_h[obase]     = *(const bf16x8*)&hb[0];
    *(bf16x8*)&Wt_h[obase + 8] = *(const bf16x8*)&hb[8];
    *(bf16x8*)&Wt_l[obase]     = *(const bf16x8*)&lb[0];
    *(bf16x8*)&Wt_l[obase + 8] = *(const bf16x8*)&lb[8];
}

// ---------------------------------------------------------------------------
// qkv GEMM: qkv = x @ qkv_w + b, written as hi/lo bf16 planes.
// ---------------------------------------------------------------------------
__global__ __launch_bounds__(256) void gemm_qkv(
    const float* __restrict__ A, const u16* __restrict__ Bth,
    const u16* __restrict__ Btl, const float* __restrict__ bias,
    u16* __restrict__ Ch, u16* __restrict__ Cl)
{
    __shared__ u16 Ah[128 * LDA_], Al[128 * LDA_];
    __shared__ u16 Bh[128 * LDA_], Bl[128 * LDA_];
    const int t    = threadIdx.x;
    const int m0   = blockIdx.y * 128, n0 = blockIdx.x * 128;
    const int lane = t & 63, w = t >> 6;
    const int wm   = (w >> 1) * 64, wn = (w & 1) * 64;
    const int fr   = lane & 15, kg8 = lane >> 4;
    const int srow = t >> 1, shalf = t & 1;       // staging: row, 16-k half

    f32x4 acc[4][4];
    #pragma unroll
    for (int i = 0; i < 4; ++i)
        #pragma unroll
        for (int j = 0; j < 4; ++j)
            acc[i][j] = (f32x4){0.f, 0.f, 0.f, 0.f};

    for (int k0 = 0; k0 < C_; k0 += 32) {
        float4 a4[4];
        #pragma unroll
        for (int q = 0; q < 4; ++q)
            a4[q] = *(const float4*)&A[(size_t)(m0 + srow) * C_ + k0 + shalf * 16 + q * 4];
        const size_t bbase = (size_t)(n0 + srow) * C_ + k0 + shalf * 16;
        bf16x8 bh0 = *(const bf16x8*)&Bth[bbase];
        bf16x8 bh1 = *(const bf16x8*)&Bth[bbase + 8];
        bf16x8 bl0 = *(const bf16x8*)&Btl[bbase];
        bf16x8 bl1 = *(const bf16x8*)&Btl[bbase + 8];

        u16 ah[16], al[16];
        #pragma unroll
        for (int q = 0; q < 4; ++q) {
            float av[4] = {a4[q].x, a4[q].y, a4[q].z, a4[q].w};
            #pragma unroll
            for (int c = 0; c < 4; ++c) {
                u16 hi = f2bf(av[c]);
                ah[q * 4 + c] = hi;
                al[q * 4 + c] = f2bf(av[c] - bf2f(hi));
            }
        }

        __syncthreads();
        const int sb = srow * LDA_ + shalf * 16;
        *(bf16x8*)&Ah[sb]     = *(const bf16x8*)&ah[0];
        *(bf16x8*)&Ah[sb + 8] = *(const bf16x8*)&ah[8];
        *(bf16x8*)&Al[sb]     = *(const bf16x8*)&al[0];
        *(bf16x8*)&Al[sb + 8] = *(const bf16x8*)&al[8];
        *(bf16x8*)&Bh[sb]     = bh0;
        *(bf16x8*)&Bh[sb + 8] = bh1;
        *(bf16x8*)&Bl[sb]     = bl0;
        *(bf16x8*)&Bl[sb + 8] = bl1;
        __syncthreads();

        bf16x8 aF[4], bF[4], a2F[4], b2F[4];
        #pragma unroll
        for (int fm = 0; fm < 4; ++fm)
            aF[fm] = *(const bf16x8*)&Ah[(wm + fm * 16 + fr) * LDA_ + kg8 * 8];
        #pragma unroll
        for (int fn = 0; fn < 4; ++fn)
            bF[fn] = *(const bf16x8*)&Bh[(wn + fn * 16 + fr) * LDA_ + kg8 * 8];
        #pragma unroll
        for (int fm = 0; fm < 4; ++fm)
            #pragma unroll
            for (int fn = 0; fn < 4; ++fn)
                acc[fm][fn] = __builtin_amdgcn_mfma_f32_16x16x32_bf16(
                    aF[fm], bF[fn], acc[fm][fn], 0, 0, 0);
        #pragma unroll
        for (int fn = 0; fn < 4; ++fn)
            b2F[fn] = *(const bf16x8*)&Bl[(wn + fn * 16 + fr) * LDA_ + kg8 * 8];
        #pragma unroll
        for (int fm = 0; fm < 4; ++fm)
            #pragma unroll
            for (int fn = 0; fn < 4; ++fn)
                acc[fm][fn] = __builtin_amdgcn_mfma_f32_16x16x32_bf16(
                    aF[fm], b2F[fn], acc[fm][fn], 0, 0, 0);
        #pragma unroll
        for (int fm = 0; fm < 4; ++fm)
            a2F[fm] = *(const bf16x8*)&Al[(wm + fm * 16 + fr) * LDA_ + kg8 * 8];
        #pragma unroll
        for (int fm = 0; fm < 4; ++fm)
            #pragma unroll
            for (int fn = 0; fn < 4; ++fn)
                acc[fm][fn] = __builtin_amdgcn_mfma_f32_16x16x32_bf16(
                    a2F[fm], bF[fn], acc[fm][fn], 0, 0, 0);
    }

    const int r4 = (lane >> 4) * 4;
    #pragma unroll
    for (int fn = 0; fn < 4; ++fn) {
        const int col = n0 + wn + fn * 16 + fr;
        const float bv = bias[col];
        #pragma unroll
        for (int fm = 0; fm < 4; ++fm)
            #pragma unroll
            for (int i = 0; i < 4; ++i) {
                const size_t o = (size_t)(m0 + wm + fm * 16 + r4 + i) * 2304 + col;
                float val = acc[fm][fn][i] + bv;
                u16 hi = f2bf(val);
                Ch[o] = hi;
                Cl[o] = f2bf(val - bf2f(hi));
            }
    }
}

// ---------------------------------------------------------------------------
// zscore (NT, both operands from qkv planes, no conversion):
// z[b,n,m] = (scale/H) * Qc[n,:].Kc[m,:] + gumbel(u).
// ---------------------------------------------------------------------------
__global__ __launch_bounds__(256) void zscore_mfma(
    const u16* __restrict__ Qh, const u16* __restrict__ Ql,
    const float* __restrict__ u, float* __restrict__ z)
{
    __shared__ u16 Ah[128 * LDA_], Al[128 * LDA_];
    __shared__ u16 Bh[128 * LDA_], Bl[128 * LDA_];
    const int t    = threadIdx.x;
    const int b    = blockIdx.z;
    const int n0   = blockIdx.y * 128, m0 = blockIdx.x * 128;
    const int lane = t & 63, w = t >> 6;
    const int wm   = (w >> 1) * 64, wn = (w & 1) * 64;
    const int fr   = lane & 15, kg8 = lane >> 4;
    const int srow = t >> 1, shalf = t & 1;

    f32x4 acc[4][4];
    #pragma unroll
    for (int i = 0; i < 4; ++i)
        #pragma unroll
        for (int j = 0; j < 4; ++j)
            acc[i][j] = (f32x4){0.f, 0.f, 0.f, 0.f};

    for (int k0 = 0; k0 < C_; k0 += 32) {
        const size_t abase = (size_t)(b * N_ + n0 + srow) * 2304 + k0 + shalf * 16;
        const size_t bbase = (size_t)(b * N_ + m0 + srow) * 2304 + 768 + k0 + shalf * 16;
        bf16x8 ah0 = *(const bf16x8*)&Qh[abase];
        bf16x8 ah1 = *(const bf16x8*)&Qh[abase + 8];
        bf16x8 al0 = *(const bf16x8*)&Ql[abase];
        bf16x8 al1 = *(const bf16x8*)&Ql[abase + 8];
        bf16x8 bh0 = *(const bf16x8*)&Qh[bbase];
        bf16x8 bh1 = *(const bf16x8*)&Qh[bbase + 8];
        bf16x8 bl0 = *(const bf16x8*)&Ql[bbase];
        bf16x8 bl1 = *(const bf16x8*)&Ql[bbase + 8];

        __syncthreads();
        const int sb = srow * LDA_ + shalf * 16;
        *(bf16x8*)&Ah[sb]     = ah0;  *(bf16x8*)&Ah[sb + 8] = ah1;
        *(bf16x8*)&Al[sb]     = al0;  *(bf16x8*)&Al[sb + 8] = al1;
        *(bf16x8*)&Bh[sb]     = bh0;  *(bf16x8*)&Bh[sb + 8] = bh1;
        *(bf16x8*)&Bl[sb]     = bl0;  *(bf16x8*)&Bl[sb + 8] = bl1;
        __syncthreads();

        bf16x8 aF[4], bF[4], a2F[4], b2F[4];
        #pragma unroll
        for (int fm = 0; fm < 4; ++fm)
            aF[fm] = *(const bf16x8*)&Ah[(wm + fm * 16 + fr) * LDA_ + kg8 * 8];
        #pragma unroll
        for (int fn = 0; fn < 4; ++fn)
            bF[fn] = *(const bf16x8*)&Bh[(wn + fn * 16 + fr) * LDA_ + kg8 * 8];
        #pragma unroll
        for (int fm = 0; fm < 4; ++fm)
            #pragma unroll
            for (int fn = 0; fn < 4; ++fn)
                acc[fm][fn] = __builtin_amdgcn_mfma_f32_16x16x32_bf16(
                    aF[fm], bF[fn], acc[fm][fn], 0, 0, 0);
        #pragma unroll
        for (int fn = 0; fn < 4; ++fn)
            b2F[fn] = *(const bf16x8*)&Bl[(wn + fn * 16 + fr) * LDA_ + kg8 * 8];
        #pragma unroll
        for (int fm = 0; fm < 4; ++fm)
            #pragma unroll
            for (int fn = 0; fn < 4; ++fn)
                acc[fm][fn] = __builtin_amdgcn_mfma_f32_16x16x32_bf16(
                    aF[fm], b2F[fn], acc[fm][fn], 0, 0, 0);
        #pragma unroll
        for (int fm = 0; fm < 4; ++fm)
            a2F[fm] = *(const bf16x8*)&Al[(wm + fm * 16 + fr) * LDA_ + kg8 * 8];
        #pragma unroll
        for (int fm = 0; fm < 4; ++fm)
            #pragma unroll
            for (int fn = 0; fn < 4; ++fn)
                acc[fm][fn] = __builtin_amdgcn_mfma_f32_16x16x32_bf16(
                    a2F[fm], bF[fn], acc[fm][fn], 0, 0, 0);
    }

    const float sc = 0.125f / 12.0f;
    const int r4 = (lane >> 4) * 4;
    #pragma unroll
    for (int fn = 0; fn < 4; ++fn) {
        const int m = m0 + wn + fn * 16 + fr;
        #pragma unroll
        for (int fm = 0; fm < 4; ++fm)
            #pragma unroll
            for (int i = 0; i < 4; ++i) {
                const int n = n0 + wm + fm * 16 + r4 + i;
                const float uv = u[((size_t)(b * N_ + n)) * N_ + m];
                const float g  = -logf(-logf(uv + EPS_) + EPS_);
                z[((size_t)(b * N_ + n)) * N_ + m] = acc[fm][fn][i] * sc + g;
            }
    }
}

// ---------------------------------------------------------------------------
// Per row: exact 32nd-largest of z; emit all cols >= thresh (cap 62).
// ---------------------------------------------------------------------------
__global__ __launch_bounds__(64) void topk_cols_kernel(
    const float* __restrict__ z, TopkRec* __restrict__ recs)
{
    const int row  = blockIdx.x;
    const int lane = threadIdx.x;
    const float* zr = z + (size_t)row * N_;
    float zv[16], wk[16];
    #pragma unroll
    for (int j = 0; j < 16; ++j) { zv[j] = zr[lane + 64 * j]; wk[j] = zv[j]; }

    float thresh = -INFINITY;
    for (int it = 0; it < TOPK_; ++it) {
        float lm = wk[0]; int li = 0;
        #pragma unroll
        for (int j = 1; j < 16; ++j)
            if (wk[j] > lm) { lm = wk[j]; li = j; }
        float gm = lm;
        gm = fmaxf(gm, __shfl_xor(gm, 1));
        gm = fmaxf(gm, __shfl_xor(gm, 2));
        gm = fmaxf(gm, __shfl_xor(gm, 4));
        gm = fmaxf(gm, __shfl_xor(gm, 8));
        gm = fmaxf(gm, __shfl_xor(gm, 16));
        gm = fmaxf(gm, __shfl_xor(gm, 32));
        unsigned long long has = __ballot(lm == gm);
        int first = __ffsll((unsigned long long)has) - 1;
        if (lane == first) wk[li] = -INFINITY;
        thresh = gm;
    }

    const unsigned long long below = ((unsigned long long)1 << lane) - 1;
    unsigned int basec = 0;
    TopkRec* rec = recs + row;
    #pragma unroll
    for (int j = 0; j < 16; ++j) {
        unsigned long long wmask = __ballot(zv[j] >= thresh);
        if (zv[j] >= thresh) {
            unsigned int pos = basec + (unsigned int)__popcll(wmask & below);
            if (pos < 62u) rec->c[pos] = (unsigned short)(lane + 64 * j);
        }
        basec += (unsigned int)__popcll(wmask);
    }
    if (lane == 0) rec->cnt = basec > 62u ? 62u : basec;
}

// ---------------------------------------------------------------------------
// Pass A (MFMA): per (b,h,64-row q-tile): softmax max m and denominator l
// over all 1024 cols. 4 waves; wave w owns rows [w*16, w*16+16) x 128 cols
// per K-tile. Q fragments loaded global->VGPR once; K staged hi/lo in LDS.
// Scores via 3-term split: Ah.Bh + Ah.Bl + Al.Bh.
// ---------------------------------------------------------------------------
__global__ __launch_bounds__(256) void attn_ml_mfma(
    const u16* __restrict__ qh, const u16* __restrict__ ql,
    float2* __restrict__ ml)
{
    __shared__ u16 KsH[128 * LK_], KsL[128 * LK_];

    const int t    = threadIdx.x;
    const int lane = t & 63, w = t >> 6;
    const int fr   = lane & 15, kg8 = lane >> 4;
    const int n0   = blockIdx.x * 64;
    const int hd   = blockIdx.y;
    const int b    = blockIdx.z;

    // Q fragments direct to regs: row n0 + w*16 + fr, k-slice kk*32 + kg8*8
    bf16x8 aH[2], aL[2];
    {
        const size_t qb = (size_t)(b * N_ + n0 + w * 16 + fr) * 2304 + hd * 64 + kg8 * 8;
        aH[0] = *(const bf16x8*)&qh[qb];
        aH[1] = *(const bf16x8*)&qh[qb + 32];
        aL[0] = *(const bf16x8*)&ql[qb];
        aL[1] = *(const bf16x8*)&ql[qb + 32];
    }

    float mrun[4], lsum[4];
    #pragma unroll
    for (int i = 0; i < 4; ++i) { mrun[i] = -INFINITY; lsum[i] = 0.f; }

    const int kr = t >> 1, kd = (t & 1) * 32;   // K staging: row, 32-d half

    for (int m0 = 0; m0 < N_; m0 += 128) {
        const size_t kb = (size_t)(b * N_ + m0 + kr) * 2304 + 768 + hd * 64 + kd;
        bf16x8 h0 = *(const bf16x8*)&qh[kb];
        bf16x8 h1 = *(const bf16x8*)&qh[kb + 8];
        bf16x8 h2 = *(const bf16x8*)&qh[kb + 16];
        bf16x8 h3 = *(const bf16x8*)&qh[kb + 24];
        bf16x8 l0 = *(const bf16x8*)&ql[kb];
        bf16x8 l1 = *(const bf16x8*)&ql[kb + 8];
        bf16x8 l2 = *(const bf16x8*)&ql[kb + 16];
        bf16x8 l3 = *(const bf16x8*)&ql[kb + 24];

        __syncthreads();                 // prev tile's fragment reads done
        const int sb = kr * LK_ + kd;
        *(bf16x8*)&KsH[sb]      = h0;  *(bf16x8*)&KsH[sb + 8]  = h1;
        *(bf16x8*)&KsH[sb + 16] = h2;  *(bf16x8*)&KsH[sb + 24] = h3;
        *(bf16x8*)&KsL[sb]      = l0;  *(bf16x8*)&KsL[sb + 8]  = l1;
        *(bf16x8*)&KsL[sb + 16] = l2;  *(bf16x8*)&KsL[sb + 24] = l3;
        __syncthreads();

        f32x4 acc[8];
        #pragma unroll
        for (int fn = 0; fn < 8; ++fn) acc[fn] = (f32x4){0.f, 0.f, 0.f, 0.f};

        #pragma unroll
        for (int kk = 0; kk < 2; ++kk) {
            #pragma unroll
            for (int fn = 0; fn < 8; ++fn) {
                const int bidx = (fn * 16 + fr) * LK_ + kk * 32 + kg8 * 8;
                bf16x8 bH = *(const bf16x8*)&KsH[bidx];
                bf16x8 bL = *(const bf16x8*)&KsL[bidx];
                acc[fn] = __builtin_amdgcn_mfma_f32_16x16x32_bf16(
                    aH[kk], bH, acc[fn], 0, 0, 0);
                acc[fn] = __builtin_amdgcn_mfma_f32_16x16x32_bf16(
                    aH[kk], bL, acc[fn], 0, 0, 0);
                acc[fn] = __builtin_amdgcn_mfma_f32_16x16x32_bf16(
                    aL[kk], bH, acc[fn], 0, 0, 0);
            }
        }

        // online softmax update; row = kg8*4 + reg, col = fn*16 + fr
        #pragma unroll
        for (int reg = 0; reg < 4; ++reg) {
            float tmax = acc[0][reg];
            #pragma unroll
            for (int fn = 1; fn < 8; ++fn) tmax = fmaxf(tmax, acc[fn][reg]);
            tmax *= 0.125f;
            tmax = fmaxf(tmax, __shfl_xor(tmax, 1));
            tmax = fmaxf(tmax, __shfl_xor(tmax, 2));
            tmax = fmaxf(tmax, __shfl_xor(tmax, 4));
            tmax = fmaxf(tmax, __shfl_xor(tmax, 8));
            float mnew  = fmaxf(mrun[reg], tmax);
            float alpha = expf(mrun[reg] - mnew);
            float tsum = 0.f;
            #pragma unroll
            for (int fn = 0; fn < 8; ++fn)
                tsum += expf(acc[fn][reg] * 0.125f - mnew);
            tsum += __shfl_xor(tsum, 1);
            tsum += __shfl_xor(tsum, 2);
            tsum += __shfl_xor(tsum, 4);
            tsum += __shfl_xor(tsum, 8);
            lsum[reg] = lsum[reg] * alpha + tsum;
            mrun[reg] = mnew;
        }
    }

    if (fr == 0) {
        #pragma unroll
        for (int reg = 0; reg < 4; ++reg)
            ml[((size_t)(b * H_ + hd)) * N_ + n0 + w * 16 + kg8 * 4 + reg] =
                make_float2(mrun[reg], lsum[reg]);
    }
}

// ---------------------------------------------------------------------------
// Pass B: sparse gather numerator; writes out1 as hi/lo planes for proj GEMM.
// ---------------------------------------------------------------------------
__global__ __launch_bounds__(256) void sparse_pv_kernel(
    const u16* __restrict__ qh, const u16* __restrict__ ql,
    const TopkRec* __restrict__ recs, const float2* __restrict__ ml,
    const float* __restrict__ head_scores,
    u16* __restrict__ out1h, u16* __restrict__ out1l)
{
    __shared__ int cols_s[62];
    __shared__ int cnt_s;

    const int t    = threadIdx.x;
    const int lane = t & 63, wv = t >> 6;
    const int row  = blockIdx.x;              // b*N + n
    const int b    = row >> 10, n = row & 1023;

    const TopkRec* rec = recs + row;
    if (t == 0) cnt_s = (int)min(rec->cnt, 62u);
    if (t < 62) cols_s[t] = rec->c[t];

    float hsum = 0.f;
    #pragma unroll
    for (int i = 0; i < H_; ++i) hsum += head_scores[i];
    const float hs_mean = hsum * (1.0f / 12.0f);
    __syncthreads();
    const int cnt = cnt_s;

    for (int hd = wv; hd < H_; hd += 4) {
        const size_t qb = (size_t)row * 2304 + hd * 64 + lane;
        const float q = bf2f(qh[qb]) + bf2f(ql[qb]);
        const float2 mlv = ml[((size_t)(b * H_ + hd)) * N_ + n];
        float acc = 0.f;
        for (int j0 = 0; j0 < cnt; j0 += 4) {
            int nj = cnt - j0; if (nj > 4) nj = 4;
            float pr[4], vvv[4];
            #pragma unroll
            for (int jj = 0; jj < 4; ++jj) {
                int idx = j0 + jj; if (idx >= cnt) idx = cnt - 1;
                const size_t cb = (size_t)(b * N_ + cols_s[idx]) * 2304 + hd * 64 + lane;
                pr[jj]  = q * (bf2f(qh[cb + 768]) + bf2f(ql[cb + 768]));
                vvv[jj] = bf2f(qh[cb + 1536]) + bf2f(ql[cb + 1536]);
            }
            #pragma unroll
            for (int d = 1; d < 64; d <<= 1) {
                pr[0] += __shfl_xor(pr[0], d);
                pr[1] += __shfl_xor(pr[1], d);
                pr[2] += __shfl_xor(pr[2], d);
                pr[3] += __shfl_xor(pr[3], d);
            }
            #pragma unroll
            for (int jj = 0; jj < 4; ++jj)
                if (jj < nj) acc += expf(pr[jj] * 0.125f - mlv.x) * vvv[jj];
        }
        const float val = acc * (hs_mean / mlv.y);
        const u16 hi = f2bf(val);
        out1h[(size_t)row * C_ + hd * 64 + lane] = hi;
        out1l[(size_t)row * C_ + hd * 64 + lane] = f2bf(val - bf2f(hi));
    }
}

// ---------------------------------------------------------------------------
// proj GEMM: out = out1 @ proj_w + b (f32 out). Pure-bf16 planes (NT).
// ---------------------------------------------------------------------------
__global__ __launch_bounds__(256) void gemm_proj(
    const u16* __restrict__ Ath, const u16* __restrict__ Atl,
    const u16* __restrict__ Bth, const u16* __restrict__ Btl,
    const float* __restrict__ bias, float* __restrict__ Cm)
{
    __shared__ u16 Ah[128 * LDA_], Al[128 * LDA_];
    __shared__ u16 Bh[128 * LDA_], Bl[128 * LDA_];
    const int t    = threadIdx.x;
    const int m0   = blockIdx.y * 128, n0 = blockIdx.x * 128;
    const int lane = t & 63, w = t >> 6;
    const int wm   = (w >> 1) * 64, wn = (w & 1) * 64;
    const int fr   = lane & 15, kg8 = lane >> 4;
    const int srow = t >> 1, shalf = t & 1;

    f32x4 acc[4][4];
    #pragma unroll
    for (int i = 0; i < 4; ++i)
        #pragma unroll
        for (int j = 0; j < 4; ++j)
            acc[i][j] = (f32x4){0.f, 0.f, 0.f, 0.f};

    for (int k0 = 0; k0 < C_; k0 += 32) {
        const size_t abase = (size_t)(m0 + srow) * C_ + k0 + shalf * 16;
        const size_t bbase = (size_t)(n0 + srow) * C_ + k0 + shalf * 16;
        bf16x8 ah0 = *(const bf16x8*)&Ath[abase];
        bf16x8 ah1 = *(const bf16x8*)&Ath[abase + 8];
        bf16x8 al0 = *(const bf16x8*)&Atl[abase];
        bf16x8 al1 = *(const bf16x8*)&Atl[abase + 8];
        bf16x8 bh0 = *(const bf16x8*)&Bth[bbase];
        bf16x8 bh1 = *(const bf16x8*)&Bth[bbase + 8];
        bf16x8 bl0 = *(const bf16x8*)&Btl[bbase];
        bf16x8 bl1 = *(const bf16x8*)&Btl[bbase + 8];

        __syncthreads();
        const int sb = srow * LDA_ + shalf * 16;
        *(bf16x8*)&Ah[sb]     = ah0;  *(bf16x8*)&Ah[sb + 8] = ah1;
        *(bf16x8*)&Al[sb]     = al0;  *(bf16x8*)&Al[sb + 8] = al1;
        *(bf16x8*)&Bh[sb]     = bh0;  *(bf16x8*)&Bh[sb + 8] = bh1;
        *(bf16x8*)&Bl[sb]     = bl0;  *(bf16x8*)&Bl[sb + 8] = bl1;
        __syncthreads();

        bf16x8 aF[4], bF[4], a2F[4], b2F[4];
        #pragma unroll
        for (int fm = 0; fm < 4; ++fm)
            aF[fm] = *(const bf16x8*)&Ah[(wm + fm * 16 + fr) * LDA_ + kg8 * 8];
        #pragma unroll
        for (int fn = 0; fn < 4; ++fn)
            bF[fn] = *(const bf16x8*)&Bh[(wn + fn * 16 + fr) * LDA_ + kg8 * 8];
        #pragma unroll
        for (int fm = 0; fm < 4; ++fm)
            #pragma unroll
            for (int fn = 0; fn < 4; ++fn)
                acc[fm][fn] = __builtin_amdgcn_mfma_f32_16x16x32_bf16(
                    aF[fm], bF[fn], acc[fm][fn], 0, 0, 0);
        #pragma unroll
        for (int fn = 0; fn < 4; ++fn)
            b2F[fn] = *(const bf16x8*)&Bl[(wn + fn * 16 + fr) * LDA_ + kg8 * 8];
        #pragma unroll
        for (int fm = 0; fm < 4; ++fm)
            #pragma unroll
            for (int fn = 0; fn < 4; ++fn)
                acc[fm][fn] = __builtin_amdgcn_mfma_f32_16x16x32_bf16(
                    aF[fm], b2F[fn], acc[fm][fn], 0, 0, 0);
        #pragma unroll
        for (int fm = 0; fm < 4; ++fm)
            a2F[fm] = *(const bf16x8*)&Al[(wm + fm * 16 + fr) * LDA_ + kg8 * 8];
        #pragma unroll
        for (int fm = 0; fm < 4; ++fm)
            #pragma unroll
            for (int fn = 0; fn < 4; ++fn)
                acc[fm][fn] = __builtin_amdgcn_mfma_f32_16x16x32_bf16(
                    a2F[fm], bF[fn], acc[fm][fn], 0, 0, 0);
    }

    const int r4 = (lane >> 4) * 4;
    #pragma unroll
    for (int fn = 0; fn < 4; ++fn) {
        const int col = n0 + wn + fn * 16 + fr;
        const float bv = bias[col];
        #pragma unroll
        for (int fm = 0; fm < 4; ++fm)
            #pragma unroll
            for (int i = 0; i < 4; ++i)
                Cm[(size_t)(m0 + wm + fm * 16 + r4 + i) * C_ + col] =
                    acc[fm][fn][i] + bv;
    }
}

// ---------------------------------------------------------------------------
extern "C" void kernel_launch(void* const* d_in, const int* in_sizes, int n_in,
                              void* d_out, int out_size, void* d_ws, size_t ws_size,
                              hipStream_t stream)
{
    (void)in_sizes; (void)n_in; (void)out_size; (void)ws_size;
    const float* x           = (const float*)d_in[0];
    const float* u           = (const float*)d_in[1];
    const float* qkv_w       = (const float*)d_in[2];
    const float* qkv_b       = (const float*)d_in[3];
    const float* proj_w      = (const float*)d_in[4];
    const float* proj_b      = (const float*)d_in[5];
    const float* head_scores = (const float*)d_in[6];
    float* out = (float*)d_out;

    // Workspace (proven 55,050,240-byte footprint), time-shared tail region:
    //   [0, 18874368)            qkv_h  bf16 [4096][2304]
    //   [18874368, 37748736)     qkv_l
    //   R = [37748736, 55050240) (17,301,504 B):
    //     phase1 (pre-qkv-GEMM): wq_t_h (3,538,944) | wq_t_l (3,538,944)
    //     phase2 (zscore->topk): z f32 (16,777,216; wq planes dead)
    //                            recs (524,288) at R+16,777,216
    //     phase3 (post-topk, z dead): wp_t_h | wp_t_l | ml | out1_h | out1_l
    char* ws = (char*)d_ws;
    u16*     qkv_h  = (u16*)ws;
    u16*     qkv_l  = (u16*)(ws + 18874368);
    char*    R      = ws + 37748736;
    u16*     wq_t_h = (u16*)R;
    u16*     wq_t_l = (u16*)(R + 3538944);
    float*   z      = (float*)R;
    TopkRec* recs   = (TopkRec*)(R + 16777216);
    u16*     wp_t_h = (u16*)R;
    u16*     wp_t_l = (u16*)(R + 1179648);
    float2*  ml     = (float2*)(R + 2359296);
    u16*     out1h  = (u16*)(R + 2752512);
    u16*     out1l  = (u16*)(R + 9043968);

    // 1) convert qkv_w -> transposed split planes [2304][768]
    conv_w_nt<<<dim3(2304 / 64, 768 / 64), dim3(256), 0, stream>>>(
        qkv_w, wq_t_h, wq_t_l, 768, 2304);

    // 2) qkv = x @ qkv_w + b  -> hi/lo planes
    gemm_qkv<<<dim3(2304 / 128, 4096 / 128), dim3(256), 0, stream>>>(
        x, wq_t_h, wq_t_l, qkv_b, qkv_h, qkv_l);

    // 3) z = (scale/H) Qc.Kc^T + gumbel(u)   [overwrites wq planes: dead]
    zscore_mfma<<<dim3(8, 8, B_), dim3(256), 0, stream>>>(qkv_h, qkv_l, u, z);

    // 4) exact top-32 -> column records
    topk_cols_kernel<<<dim3(B_ * N_), dim3(64), 0, stream>>>(z, recs);

    // 5) convert proj_w -> transposed split planes [768][768]  (z now dead)
    conv_w_nt<<<dim3(768 / 64, 768 / 64), dim3(256), 0, stream>>>(
        proj_w, wp_t_h, wp_t_l, 768, 768);

    // 6) per-head softmax max + denominator (MFMA)
    attn_ml_mfma<<<dim3(16, H_, B_), dim3(256), 0, stream>>>(qkv_h, qkv_l, ml);

    // 7) sparse gather numerator -> out1 planes
    sparse_pv_kernel<<<dim3(B_ * N_), dim3(256), 0, stream>>>(
        qkv_h, qkv_l, recs, ml, head_scores, out1h, out1l);

    // 8) out = out1 @ proj_w + b
    gemm_proj<<<dim3(768 / 128, 4096 / 128), dim3(256), 0, stream>>>(
        out1h, out1l, wp_t_h, wp_t_l, proj_b, out);
}

// Round 7
// 321.966 us; speedup vs baseline: 1.9687x; 1.1525x over previous
//
#include <hip/hip_runtime.h>
#include <hip/hip_bf16.h>
#include <math.h>

#define B_ 4
#define N_ 1024
#define C_ 768
#define H_ 12
#define D_ 64
#define TOPK_ 32
#define EPS_ 1e-9f

#define LDA_ 40   // GEMM LDS row stride (bf16 elems): 32 used + 8 pad = 80 B
#define LK_  72   // attn LDS row stride: 64 used + 8 pad = 144 B (2-way = free)
#define QKS_ 1536 // Q,K plane row stride (elems): heads 0..23 (Q,K only)

typedef __attribute__((ext_vector_type(8))) short bf16x8;
typedef __attribute__((ext_vector_type(4))) float f32x4;
typedef unsigned short u16;

struct TopkRec { unsigned int cnt; unsigned short c[62]; };  // 128 B

__device__ __forceinline__ u16 f2bf(float f) {
    unsigned int u = __float_as_uint(f);
    u += 0x7fffu + ((u >> 16) & 1u);
    return (u16)(u >> 16);
}
__device__ __forceinline__ float bf2f(u16 h) {
    return __uint_as_float(((unsigned int)h) << 16);
}

// ---------------------------------------------------------------------------
// Weight convert: W f32 [K][Ncols] -> Wt_h, Wt_l bf16 [Ncols][K] (transposed
// hi/lo split). 64x64 LDS tile.
// ---------------------------------------------------------------------------
__global__ __launch_bounds__(256) void conv_w_nt(
    const float* __restrict__ W, u16* __restrict__ Wt_h, u16* __restrict__ Wt_l,
    int Kdim, int Ncols)
{
    __shared__ float Ts[64][65];
    const int t  = threadIdx.x;
    const int r  = t >> 2;            // 0..63
    const int cq = (t & 3) * 16;      // 0,16,32,48
    const int n0 = blockIdx.x * 64, k0 = blockIdx.y * 64;

    #pragma unroll
    for (int q = 0; q < 4; ++q) {
        float4 v = *(const float4*)&W[(size_t)(k0 + r) * Ncols + n0 + cq + q * 4];
        Ts[r][cq + q * 4 + 0] = v.x;
        Ts[r][cq + q * 4 + 1] = v.y;
        Ts[r][cq + q * 4 + 2] = v.z;
        Ts[r][cq + q * 4 + 3] = v.w;
    }
    __syncthreads();
    u16 hb[16], lb[16];
    #pragma unroll
    for (int i = 0; i < 16; ++i) {
        float val = Ts[cq + i][r];          // transpose
        u16 hi = f2bf(val);
        hb[i] = hi;
        lb[i] = f2bf(val - bf2f(hi));
    }
    const size_t obase = (size_t)(n0 + r) * Kdim + k0 + cq;
    *(bf16x8*)&Wt_h[obase]     = *(const bf16x8*)&hb[0];
    *(bf16x8*)&Wt_h[obase + 8] = *(const bf16x8*)&hb[8];
    *(bf16x8*)&Wt_l[obase]     = *(const bf16x8*)&lb[0];
    *(bf16x8*)&Wt_l[obase + 8] = *(const bf16x8*)&lb[8];
}

// ---------------------------------------------------------------------------
// qkv GEMM: qkv = x @ qkv_w + b.
// Output: cols [0,1536) (Q,K) -> hi/lo planes stride 1536;
//         cols [1536,2304) (V) -> f32 [4096][768].
// ---------------------------------------------------------------------------
__global__ __launch_bounds__(256) void gemm_qkv(
    const float* __restrict__ A, const u16* __restrict__ Bth,
    const u16* __restrict__ Btl, const float* __restrict__ bias,
    u16* __restrict__ Ch, u16* __restrict__ Cl, float* __restrict__ Vf)
{
    __shared__ u16 Ah[128 * LDA_], Al[128 * LDA_];
    __shared__ u16 Bh[128 * LDA_], Bl[128 * LDA_];
    const int t    = threadIdx.x;
    const int m0   = blockIdx.y * 128, n0 = blockIdx.x * 128;
    const int lane = t & 63, w = t >> 6;
    const int wm   = (w >> 1) * 64, wn = (w & 1) * 64;
    const int fr   = lane & 15, kg8 = lane >> 4;
    const int srow = t >> 1, shalf = t & 1;       // staging: row, 16-k half

    f32x4 acc[4][4];
    #pragma unroll
    for (int i = 0; i < 4; ++i)
        #pragma unroll
        for (int j = 0; j < 4; ++j)
            acc[i][j] = (f32x4){0.f, 0.f, 0.f, 0.f};

    for (int k0 = 0; k0 < C_; k0 += 32) {
        float4 a4[4];
        #pragma unroll
        for (int q = 0; q < 4; ++q)
            a4[q] = *(const float4*)&A[(size_t)(m0 + srow) * C_ + k0 + shalf * 16 + q * 4];
        const size_t bbase = (size_t)(n0 + srow) * C_ + k0 + shalf * 16;
        bf16x8 bh0 = *(const bf16x8*)&Bth[bbase];
        bf16x8 bh1 = *(const bf16x8*)&Bth[bbase + 8];
        bf16x8 bl0 = *(const bf16x8*)&Btl[bbase];
        bf16x8 bl1 = *(const bf16x8*)&Btl[bbase + 8];

        u16 ah[16], al[16];
        #pragma unroll
        for (int q = 0; q < 4; ++q) {
            float av[4] = {a4[q].x, a4[q].y, a4[q].z, a4[q].w};
            #pragma unroll
            for (int c = 0; c < 4; ++c) {
                u16 hi = f2bf(av[c]);
                ah[q * 4 + c] = hi;
                al[q * 4 + c] = f2bf(av[c] - bf2f(hi));
            }
        }

        __syncthreads();
        const int sb = srow * LDA_ + shalf * 16;
        *(bf16x8*)&Ah[sb]     = *(const bf16x8*)&ah[0];
        *(bf16x8*)&Ah[sb + 8] = *(const bf16x8*)&ah[8];
        *(bf16x8*)&Al[sb]     = *(const bf16x8*)&al[0];
        *(bf16x8*)&Al[sb + 8] = *(const bf16x8*)&al[8];
        *(bf16x8*)&Bh[sb]     = bh0;
        *(bf16x8*)&Bh[sb + 8] = bh1;
        *(bf16x8*)&Bl[sb]     = bl0;
        *(bf16x8*)&Bl[sb + 8] = bl1;
        __syncthreads();

        bf16x8 aF[4], bF[4], a2F[4], b2F[4];
        #pragma unroll
        for (int fm = 0; fm < 4; ++fm)
            aF[fm] = *(const bf16x8*)&Ah[(wm + fm * 16 + fr) * LDA_ + kg8 * 8];
        #pragma unroll
        for (int fn = 0; fn < 4; ++fn)
            bF[fn] = *(const bf16x8*)&Bh[(wn + fn * 16 + fr) * LDA_ + kg8 * 8];
        #pragma unroll
        for (int fm = 0; fm < 4; ++fm)
            #pragma unroll
            for (int fn = 0; fn < 4; ++fn)
                acc[fm][fn] = __builtin_amdgcn_mfma_f32_16x16x32_bf16(
                    aF[fm], bF[fn], acc[fm][fn], 0, 0, 0);
        #pragma unroll
        for (int fn = 0; fn < 4; ++fn)
            b2F[fn] = *(const bf16x8*)&Bl[(wn + fn * 16 + fr) * LDA_ + kg8 * 8];
        #pragma unroll
        for (int fm = 0; fm < 4; ++fm)
            #pragma unroll
            for (int fn = 0; fn < 4; ++fn)
                acc[fm][fn] = __builtin_amdgcn_mfma_f32_16x16x32_bf16(
                    aF[fm], b2F[fn], acc[fm][fn], 0, 0, 0);
        #pragma unroll
        for (int fm = 0; fm < 4; ++fm)
            a2F[fm] = *(const bf16x8*)&Al[(wm + fm * 16 + fr) * LDA_ + kg8 * 8];
        #pragma unroll
        for (int fm = 0; fm < 4; ++fm)
            #pragma unroll
            for (int fn = 0; fn < 4; ++fn)
                acc[fm][fn] = __builtin_amdgcn_mfma_f32_16x16x32_bf16(
                    a2F[fm], bF[fn], acc[fm][fn], 0, 0, 0);
    }

    const int r4 = (lane >> 4) * 4;
    const bool isV = (n0 >= 1536);
    #pragma unroll
    for (int fn = 0; fn < 4; ++fn) {
        const int col = n0 + wn + fn * 16 + fr;
        const float bv = bias[col];
        #pragma unroll
        for (int fm = 0; fm < 4; ++fm)
            #pragma unroll
            for (int i = 0; i < 4; ++i) {
                const int rown = m0 + wm + fm * 16 + r4 + i;
                float val = acc[fm][fn][i] + bv;
                if (isV) {
                    Vf[(size_t)rown * C_ + col - 1536] = val;
                } else {
                    const size_t o = (size_t)rown * QKS_ + col;
                    u16 hi = f2bf(val);
                    Ch[o] = hi;
                    Cl[o] = f2bf(val - bf2f(hi));
                }
            }
    }
}

// ---------------------------------------------------------------------------
// zscore (NT, both operands from Q,K planes, no conversion):
// z[b,n,m] = (scale/H) * Qc[n,:].Kc[m,:] + gumbel(u).
// ---------------------------------------------------------------------------
__global__ __launch_bounds__(256) void zscore_mfma(
    const u16* __restrict__ Qh, const u16* __restrict__ Ql,
    const float* __restrict__ u, float* __restrict__ z)
{
    __shared__ u16 Ah[128 * LDA_], Al[128 * LDA_];
    __shared__ u16 Bh[128 * LDA_], Bl[128 * LDA_];
    const int t    = threadIdx.x;
    const int b    = blockIdx.z;
    const int n0   = blockIdx.y * 128, m0 = blockIdx.x * 128;
    const int lane = t & 63, w = t >> 6;
    const int wm   = (w >> 1) * 64, wn = (w & 1) * 64;
    const int fr   = lane & 15, kg8 = lane >> 4;
    const int srow = t >> 1, shalf = t & 1;

    f32x4 acc[4][4];
    #pragma unroll
    for (int i = 0; i < 4; ++i)
        #pragma unroll
        for (int j = 0; j < 4; ++j)
            acc[i][j] = (f32x4){0.f, 0.f, 0.f, 0.f};

    for (int k0 = 0; k0 < C_; k0 += 32) {
        const size_t abase = (size_t)(b * N_ + n0 + srow) * QKS_ + k0 + shalf * 16;
        const size_t bbase = (size_t)(b * N_ + m0 + srow) * QKS_ + 768 + k0 + shalf * 16;
        bf16x8 ah0 = *(const bf16x8*)&Qh[abase];
        bf16x8 ah1 = *(const bf16x8*)&Qh[abase + 8];
        bf16x8 al0 = *(const bf16x8*)&Ql[abase];
        bf16x8 al1 = *(const bf16x8*)&Ql[abase + 8];
        bf16x8 bh0 = *(const bf16x8*)&Qh[bbase];
        bf16x8 bh1 = *(const bf16x8*)&Qh[bbase + 8];
        bf16x8 bl0 = *(const bf16x8*)&Ql[bbase];
        bf16x8 bl1 = *(const bf16x8*)&Ql[bbase + 8];

        __syncthreads();
        const int sb = srow * LDA_ + shalf * 16;
        *(bf16x8*)&Ah[sb]     = ah0;  *(bf16x8*)&Ah[sb + 8] = ah1;
        *(bf16x8*)&Al[sb]     = al0;  *(bf16x8*)&Al[sb + 8] = al1;
        *(bf16x8*)&Bh[sb]     = bh0;  *(bf16x8*)&Bh[sb + 8] = bh1;
        *(bf16x8*)&Bl[sb]     = bl0;  *(bf16x8*)&Bl[sb + 8] = bl1;
        __syncthreads();

        bf16x8 aF[4], bF[4], a2F[4], b2F[4];
        #pragma unroll
        for (int fm = 0; fm < 4; ++fm)
            aF[fm] = *(const bf16x8*)&Ah[(wm + fm * 16 + fr) * LDA_ + kg8 * 8];
        #pragma unroll
        for (int fn = 0; fn < 4; ++fn)
            bF[fn] = *(const bf16x8*)&Bh[(wn + fn * 16 + fr) * LDA_ + kg8 * 8];
        #pragma unroll
        for (int fm = 0; fm < 4; ++fm)
            #pragma unroll
            for (int fn = 0; fn < 4; ++fn)
                acc[fm][fn] = __builtin_amdgcn_mfma_f32_16x16x32_bf16(
                    aF[fm], bF[fn], acc[fm][fn], 0, 0, 0);
        #pragma unroll
        for (int fn = 0; fn < 4; ++fn)
            b2F[fn] = *(const bf16x8*)&Bl[(wn + fn * 16 + fr) * LDA_ + kg8 * 8];
        #pragma unroll
        for (int fm = 0; fm < 4; ++fm)
            #pragma unroll
            for (int fn = 0; fn < 4; ++fn)
                acc[fm][fn] = __builtin_amdgcn_mfma_f32_16x16x32_bf16(
                    aF[fm], b2F[fn], acc[fm][fn], 0, 0, 0);
        #pragma unroll
        for (int fm = 0; fm < 4; ++fm)
            a2F[fm] = *(const bf16x8*)&Al[(wm + fm * 16 + fr) * LDA_ + kg8 * 8];
        #pragma unroll
        for (int fm = 0; fm < 4; ++fm)
            #pragma unroll
            for (int fn = 0; fn < 4; ++fn)
                acc[fm][fn] = __builtin_amdgcn_mfma_f32_16x16x32_bf16(
                    a2F[fm], bF[fn], acc[fm][fn], 0, 0, 0);
    }

    const float sc = 0.125f / 12.0f;
    const int r4 = (lane >> 4) * 4;
    #pragma unroll
    for (int fn = 0; fn < 4; ++fn) {
        const int m = m0 + wn + fn * 16 + fr;
        #pragma unroll
        for (int fm = 0; fm < 4; ++fm)
            #pragma unroll
            for (int i = 0; i < 4; ++i) {
                const int n = n0 + wm + fm * 16 + r4 + i;
                const float uv = u[((size_t)(b * N_ + n)) * N_ + m];
                const float g  = -logf(-logf(uv + EPS_) + EPS_);
                z[((size_t)(b * N_ + n)) * N_ + m] = acc[fm][fn][i] * sc + g;
            }
    }
}

// ---------------------------------------------------------------------------
// Per row: exact 32nd-largest of z; emit all cols >= thresh (cap 62).
// ---------------------------------------------------------------------------
__global__ __launch_bounds__(64) void topk_cols_kernel(
    const float* __restrict__ z, TopkRec* __restrict__ recs)
{
    const int row  = blockIdx.x;
    const int lane = threadIdx.x;
    const float* zr = z + (size_t)row * N_;
    float zv[16], wk[16];
    #pragma unroll
    for (int j = 0; j < 16; ++j) { zv[j] = zr[lane + 64 * j]; wk[j] = zv[j]; }

    float thresh = -INFINITY;
    for (int it = 0; it < TOPK_; ++it) {
        float lm = wk[0]; int li = 0;
        #pragma unroll
        for (int j = 1; j < 16; ++j)
            if (wk[j] > lm) { lm = wk[j]; li = j; }
        float gm = lm;
        gm = fmaxf(gm, __shfl_xor(gm, 1));
        gm = fmaxf(gm, __shfl_xor(gm, 2));
        gm = fmaxf(gm, __shfl_xor(gm, 4));
        gm = fmaxf(gm, __shfl_xor(gm, 8));
        gm = fmaxf(gm, __shfl_xor(gm, 16));
        gm = fmaxf(gm, __shfl_xor(gm, 32));
        unsigned long long has = __ballot(lm == gm);
        int first = __ffsll((unsigned long long)has) - 1;
        if (lane == first) wk[li] = -INFINITY;
        thresh = gm;
    }

    const unsigned long long below = ((unsigned long long)1 << lane) - 1;
    unsigned int basec = 0;
    TopkRec* rec = recs + row;
    #pragma unroll
    for (int j = 0; j < 16; ++j) {
        unsigned long long wmask = __ballot(zv[j] >= thresh);
        if (zv[j] >= thresh) {
            unsigned int pos = basec + (unsigned int)__popcll(wmask & below);
            if (pos < 62u) rec->c[pos] = (unsigned short)(lane + 64 * j);
        }
        basec += (unsigned int)__popcll(wmask);
    }
    if (lane == 0) rec->cnt = basec > 62u ? 62u : basec;
}

// ---------------------------------------------------------------------------
// Pass A (MFMA): per (b,h,64-row q-tile): softmax max m and denominator l
// over all 1024 cols. 4 waves; Q fragments in regs; K staged hi/lo in LDS.
// ---------------------------------------------------------------------------
__global__ __launch_bounds__(256) void attn_ml_mfma(
    const u16* __restrict__ qh, const u16* __restrict__ ql,
    float2* __restrict__ ml)
{
    __shared__ u16 KsH[128 * LK_], KsL[128 * LK_];

    const int t    = threadIdx.x;
    const int lane = t & 63, w = t >> 6;
    const int fr   = lane & 15, kg8 = lane >> 4;
    const int n0   = blockIdx.x * 64;
    const int hd   = blockIdx.y;
    const int b    = blockIdx.z;

    bf16x8 aH[2], aL[2];
    {
        const size_t qb = (size_t)(b * N_ + n0 + w * 16 + fr) * QKS_ + hd * 64 + kg8 * 8;
        aH[0] = *(const bf16x8*)&qh[qb];
        aH[1] = *(const bf16x8*)&qh[qb + 32];
        aL[0] = *(const bf16x8*)&ql[qb];
        aL[1] = *(const bf16x8*)&ql[qb + 32];
    }

    float mrun[4], lsum[4];
    #pragma unroll
    for (int i = 0; i < 4; ++i) { mrun[i] = -INFINITY; lsum[i] = 0.f; }

    const int kr = t >> 1, kd = (t & 1) * 32;   // K staging: row, 32-d half

    for (int m0 = 0; m0 < N_; m0 += 128) {
        const size_t kb = (size_t)(b * N_ + m0 + kr) * QKS_ + 768 + hd * 64 + kd;
        bf16x8 h0 = *(const bf16x8*)&qh[kb];
        bf16x8 h1 = *(const bf16x8*)&qh[kb + 8];
        bf16x8 h2 = *(const bf16x8*)&qh[kb + 16];
        bf16x8 h3 = *(const bf16x8*)&qh[kb + 24];
        bf16x8 l0 = *(const bf16x8*)&ql[kb];
        bf16x8 l1 = *(const bf16x8*)&ql[kb + 8];
        bf16x8 l2 = *(const bf16x8*)&ql[kb + 16];
        bf16x8 l3 = *(const bf16x8*)&ql[kb + 24];

        __syncthreads();
        const int sb = kr * LK_ + kd;
        *(bf16x8*)&KsH[sb]      = h0;  *(bf16x8*)&KsH[sb + 8]  = h1;
        *(bf16x8*)&KsH[sb + 16] = h2;  *(bf16x8*)&KsH[sb + 24] = h3;
        *(bf16x8*)&KsL[sb]      = l0;  *(bf16x8*)&KsL[sb + 8]  = l1;
        *(bf16x8*)&KsL[sb + 16] = l2;  *(bf16x8*)&KsL[sb + 24] = l3;
        __syncthreads();

        f32x4 acc[8];
        #pragma unroll
        for (int fn = 0; fn < 8; ++fn) acc[fn] = (f32x4){0.f, 0.f, 0.f, 0.f};

        #pragma unroll
        for (int kk = 0; kk < 2; ++kk) {
            #pragma unroll
            for (int fn = 0; fn < 8; ++fn) {
                const int bidx = (fn * 16 + fr) * LK_ + kk * 32 + kg8 * 8;
                bf16x8 bH = *(const bf16x8*)&KsH[bidx];
                bf16x8 bL = *(const bf16x8*)&KsL[bidx];
                acc[fn] = __builtin_amdgcn_mfma_f32_16x16x32_bf16(
                    aH[kk], bH, acc[fn], 0, 0, 0);
                acc[fn] = __builtin_amdgcn_mfma_f32_16x16x32_bf16(
                    aH[kk], bL, acc[fn], 0, 0, 0);
                acc[fn] = __builtin_amdgcn_mfma_f32_16x16x32_bf16(
                    aL[kk], bH, acc[fn], 0, 0, 0);
            }
        }

        #pragma unroll
        for (int reg = 0; reg < 4; ++reg) {
            float tmax = acc[0][reg];
            #pragma unroll
            for (int fn = 1; fn < 8; ++fn) tmax = fmaxf(tmax, acc[fn][reg]);
            tmax *= 0.125f;
            tmax = fmaxf(tmax, __shfl_xor(tmax, 1));
            tmax = fmaxf(tmax, __shfl_xor(tmax, 2));
            tmax = fmaxf(tmax, __shfl_xor(tmax, 4));
            tmax = fmaxf(tmax, __shfl_xor(tmax, 8));
            float mnew  = fmaxf(mrun[reg], tmax);
            float alpha = expf(mrun[reg] - mnew);
            float tsum = 0.f;
            #pragma unroll
            for (int fn = 0; fn < 8; ++fn)
                tsum += expf(acc[fn][reg] * 0.125f - mnew);
            tsum += __shfl_xor(tsum, 1);
            tsum += __shfl_xor(tsum, 2);
            tsum += __shfl_xor(tsum, 4);
            tsum += __shfl_xor(tsum, 8);
            lsum[reg] = lsum[reg] * alpha + tsum;
            mrun[reg] = mnew;
        }
    }

    if (fr == 0) {
        #pragma unroll
        for (int reg = 0; reg < 4; ++reg)
            ml[((size_t)(b * H_ + hd)) * N_ + n0 + w * 16 + kg8 * 4 + reg] =
                make_float2(mrun[reg], lsum[reg]);
    }
}

// ---------------------------------------------------------------------------
// Pass B: sparse gather numerator. Lane = (c,dq): c=lane>>2 owns a column,
// dq=lane&3 owns 16 dims. Dot: 16 reg-FMA + 2 shfl; PV: per-lane acc[16],
// one 4-level cross-c reduce per head. V read as f32 (no reconstruction).
// ---------------------------------------------------------------------------
__global__ __launch_bounds__(256) void sparse_pv_kernel(
    const u16* __restrict__ qh, const u16* __restrict__ ql,
    const float* __restrict__ Vf,
    const TopkRec* __restrict__ recs, const float2* __restrict__ ml,
    const float* __restrict__ head_scores,
    u16* __restrict__ out1h, u16* __restrict__ out1l)
{
    __shared__ int cols_s[62];
    __shared__ int cnt_s;

    const int t    = threadIdx.x;
    const int lane = t & 63, wv = t >> 6;
    const int c4   = lane >> 2;      // column slot 0..15
    const int dq   = lane & 3;       // 16-dim quarter
    const int row  = blockIdx.x;     // b*N + n
    const int b    = row >> 10, n = row & 1023;

    const TopkRec* rec = recs + row;
    if (t == 0) cnt_s = (int)min(rec->cnt, 62u);
    if (t < 62) cols_s[t] = rec->c[t];

    float hsum = 0.f;
    #pragma unroll
    for (int i = 0; i < H_; ++i) hsum += head_scores[i];
    const float hs_mean = hsum * (1.0f / 12.0f);
    __syncthreads();
    const int cnt = cnt_s;
    const int nbatch = (cnt + 15) >> 4;

    for (int hd = wv; hd < H_; hd += 4) {
        // q slice for this lane's 16 dims
        float qv[16];
        {
            const size_t qb = (size_t)row * QKS_ + hd * 64 + dq * 16;
            bf16x8 qh0 = *(const bf16x8*)&qh[qb], qh1 = *(const bf16x8*)&qh[qb + 8];
            bf16x8 ql0 = *(const bf16x8*)&ql[qb], ql1 = *(const bf16x8*)&ql[qb + 8];
            #pragma unroll
            for (int i = 0; i < 8; ++i) {
                qv[i]     = bf2f((u16)qh0[i]) + bf2f((u16)ql0[i]);
                qv[i + 8] = bf2f((u16)qh1[i]) + bf2f((u16)ql1[i]);
            }
        }
        const float2 mlv = ml[((size_t)(b * H_ + hd)) * N_ + n];

        float acc[16];
        #pragma unroll
        for (int i = 0; i < 16; ++i) acc[i] = 0.f;

        for (int batch = 0; batch < nbatch; ++batch) {
            const int cidx  = batch * 16 + c4;
            const bool valid = (cidx < cnt);
            const int col   = cols_s[valid ? cidx : cnt - 1];

            // K dot over this lane's 16 dims
            const size_t kb = (size_t)(b * N_ + col) * QKS_ + 768 + hd * 64 + dq * 16;
            bf16x8 kh0 = *(const bf16x8*)&qh[kb], kh1 = *(const bf16x8*)&qh[kb + 8];
            bf16x8 kl0 = *(const bf16x8*)&ql[kb], kl1 = *(const bf16x8*)&ql[kb + 8];
            float dot = 0.f;
            #pragma unroll
            for (int i = 0; i < 8; ++i) {
                dot += qv[i]     * (bf2f((u16)kh0[i]) + bf2f((u16)kl0[i]));
                dot += qv[i + 8] * (bf2f((u16)kh1[i]) + bf2f((u16)kl1[i]));
            }
            dot += __shfl_xor(dot, 1);
            dot += __shfl_xor(dot, 2);
            float p = valid ? expf(dot * 0.125f - mlv.x) : 0.f;

            // V accumulate (f32, 4x float4)
            const float* vb = &Vf[(size_t)(b * N_ + col) * C_ + hd * 64 + dq * 16];
            #pragma unroll
            for (int q = 0; q < 4; ++q) {
                float4 v4 = *(const float4*)&vb[q * 4];
                acc[q * 4 + 0] += p * v4.x;
                acc[q * 4 + 1] += p * v4.y;
                acc[q * 4 + 2] += p * v4.z;
                acc[q * 4 + 3] += p * v4.w;
            }
        }

        // reduce over the 16 column slots (lane bits 2..5)
        #pragma unroll
        for (int d = 4; d < 64; d <<= 1)
            #pragma unroll
            for (int i = 0; i < 16; ++i)
                acc[i] += __shfl_xor(acc[i], d);

        if (c4 == 0) {
            const float s = hs_mean / mlv.y;
            u16 hb[16], lb[16];
            #pragma unroll
            for (int i = 0; i < 16; ++i) {
                float val = acc[i] * s;
                u16 hi = f2bf(val);
                hb[i] = hi;
                lb[i] = f2bf(val - bf2f(hi));
            }
            const size_t ob = (size_t)row * C_ + hd * 64 + dq * 16;
            *(bf16x8*)&out1h[ob]     = *(const bf16x8*)&hb[0];
            *(bf16x8*)&out1h[ob + 8] = *(const bf16x8*)&hb[8];
            *(bf16x8*)&out1l[ob]     = *(const bf16x8*)&lb[0];
            *(bf16x8*)&out1l[ob + 8] = *(const bf16x8*)&lb[8];
        }
    }
}

// ---------------------------------------------------------------------------
// proj GEMM: out = out1 @ proj_w + b (f32 out). Pure-bf16 planes (NT).
// ---------------------------------------------------------------------------
__global__ __launch_bounds__(256) void gemm_proj(
    const u16* __restrict__ Ath, const u16* __restrict__ Atl,
    const u16* __restrict__ Bth, const u16* __restrict__ Btl,
    const float* __restrict__ bias, float* __restrict__ Cm)
{
    __shared__ u16 Ah[128 * LDA_], Al[128 * LDA_];
    __shared__ u16 Bh[128 * LDA_], Bl[128 * LDA_];
    const int t    = threadIdx.x;
    const int m0   = blockIdx.y * 128, n0 = blockIdx.x * 128;
    const int lane = t & 63, w = t >> 6;
    const int wm   = (w >> 1) * 64, wn = (w & 1) * 64;
    const int fr   = lane & 15, kg8 = lane >> 4;
    const int srow = t >> 1, shalf = t & 1;

    f32x4 acc[4][4];
    #pragma unroll
    for (int i = 0; i < 4; ++i)
        #pragma unroll
        for (int j = 0; j < 4; ++j)
            acc[i][j] = (f32x4){0.f, 0.f, 0.f, 0.f};

    for (int k0 = 0; k0 < C_; k0 += 32) {
        const size_t abase = (size_t)(m0 + srow) * C_ + k0 + shalf * 16;
        const size_t bbase = (size_t)(n0 + srow) * C_ + k0 + shalf * 16;
        bf16x8 ah0 = *(const bf16x8*)&Ath[abase];
        bf16x8 ah1 = *(const bf16x8*)&Ath[abase + 8];
        bf16x8 al0 = *(const bf16x8*)&Atl[abase];
        bf16x8 al1 = *(const bf16x8*)&Atl[abase + 8];
        bf16x8 bh0 = *(const bf16x8*)&Bth[bbase];
        bf16x8 bh1 = *(const bf16x8*)&Bth[bbase + 8];
        bf16x8 bl0 = *(const bf16x8*)&Btl[bbase];
        bf16x8 bl1 = *(const bf16x8*)&Btl[bbase + 8];

        __syncthreads();
        const int sb = srow * LDA_ + shalf * 16;
        *(bf16x8*)&Ah[sb]     = ah0;  *(bf16x8*)&Ah[sb + 8] = ah1;
        *(bf16x8*)&Al[sb]     = al0;  *(bf16x8*)&Al[sb + 8] = al1;
        *(bf16x8*)&Bh[sb]     = bh0;  *(bf16x8*)&Bh[sb + 8] = bh1;
        *(bf16x8*)&Bl[sb]     = bl0;  *(bf16x8*)&Bl[sb + 8] = bl1;
        __syncthreads();

        bf16x8 aF[4], bF[4], a2F[4], b2F[4];
        #pragma unroll
        for (int fm = 0; fm < 4; ++fm)
            aF[fm] = *(const bf16x8*)&Ah[(wm + fm * 16 + fr) * LDA_ + kg8 * 8];
        #pragma unroll
        for (int fn = 0; fn < 4; ++fn)
            bF[fn] = *(const bf16x8*)&Bh[(wn + fn * 16 + fr) * LDA_ + kg8 * 8];
        #pragma unroll
        for (int fm = 0; fm < 4; ++fm)
            #pragma unroll
            for (int fn = 0; fn < 4; ++fn)
                acc[fm][fn] = __builtin_amdgcn_mfma_f32_16x16x32_bf16(
                    aF[fm], bF[fn], acc[fm][fn], 0, 0, 0);
        #pragma unroll
        for (int fn = 0; fn < 4; ++fn)
            b2F[fn] = *(const bf16x8*)&Bl[(wn + fn * 16 + fr) * LDA_ + kg8 * 8];
        #pragma unroll
        for (int fm = 0; fm < 4; ++fm)
            #pragma unroll
            for (int fn = 0; fn < 4; ++fn)
                acc[fm][fn] = __builtin_amdgcn_mfma_f32_16x16x32_bf16(
                    aF[fm], b2F[fn], acc[fm][fn], 0, 0, 0);
        #pragma unroll
        for (int fm = 0; fm < 4; ++fm)
            a2F[fm] = *(const bf16x8*)&Al[(wm + fm * 16 + fr) * LDA_ + kg8 * 8];
        #pragma unroll
        for (int fm = 0; fm < 4; ++fm)
            #pragma unroll
            for (int fn = 0; fn < 4; ++fn)
                acc[fm][fn] = __builtin_amdgcn_mfma_f32_16x16x32_bf16(
                    a2F[fm], bF[fn], acc[fm][fn], 0, 0, 0);
    }

    const int r4 = (lane >> 4) * 4;
    #pragma unroll
    for (int fn = 0; fn < 4; ++fn) {
        const int col = n0 + wn + fn * 16 + fr;
        const float bv = bias[col];
        #pragma unroll
        for (int fm = 0; fm < 4; ++fm)
            #pragma unroll
            for (int i = 0; i < 4; ++i)
                Cm[(size_t)(m0 + wm + fm * 16 + r4 + i) * C_ + col] =
                    acc[fm][fn][i] + bv;
    }
}

// ---------------------------------------------------------------------------
extern "C" void kernel_launch(void* const* d_in, const int* in_sizes, int n_in,
                              void* d_out, int out_size, void* d_ws, size_t ws_size,
                              hipStream_t stream)
{
    (void)in_sizes; (void)n_in; (void)out_size; (void)ws_size;
    const float* x           = (const float*)d_in[0];
    const float* u           = (const float*)d_in[1];
    const float* qkv_w       = (const float*)d_in[2];
    const float* qkv_b       = (const float*)d_in[3];
    const float* proj_w      = (const float*)d_in[4];
    const float* proj_b      = (const float*)d_in[5];
    const float* head_scores = (const float*)d_in[6];
    float* out = (float*)d_out;

    // Workspace (proven 55,050,240-byte footprint):
    //   [0, 12582912)            qkv_h  bf16 [4096][1536]  (Q,K planes)
    //   [12582912, 25165824)     qkv_l
    //   [25165824, 37748736)     V f32 [4096][768]
    //   R = [37748736, 55050240) (17,301,504 B), time-shared:
    //     phase1: wq_t_h (3,538,944) | wq_t_l (3,538,944)
    //     phase2: z f32 (16,777,216; wq planes dead) + recs (524,288)
    //     phase3 (z dead): wp_t_h | wp_t_l | ml | out1_h | out1_l
    char* ws = (char*)d_ws;
    u16*     qkv_h  = (u16*)ws;
    u16*     qkv_l  = (u16*)(ws + 12582912);
    float*   Vf     = (float*)(ws + 25165824);
    char*    R      = ws + 37748736;
    u16*     wq_t_h = (u16*)R;
    u16*     wq_t_l = (u16*)(R + 3538944);
    float*   z      = (float*)R;
    TopkRec* recs   = (TopkRec*)(R + 16777216);
    u16*     wp_t_h = (u16*)R;
    u16*     wp_t_l = (u16*)(R + 1179648);
    float2*  ml     = (float2*)(R + 2359296);
    u16*     out1h  = (u16*)(R + 2752512);
    u16*     out1l  = (u16*)(R + 9043968);

    // 1) convert qkv_w -> transposed split planes [2304][768]
    conv_w_nt<<<dim3(2304 / 64, 768 / 64), dim3(256), 0, stream>>>(
        qkv_w, wq_t_h, wq_t_l, 768, 2304);

    // 2) qkv = x @ qkv_w + b  -> Q,K planes + V f32
    gemm_qkv<<<dim3(2304 / 128, 4096 / 128), dim3(256), 0, stream>>>(
        x, wq_t_h, wq_t_l, qkv_b, qkv_h, qkv_l, Vf);

    // 3) z = (scale/H) Qc.Kc^T + gumbel(u)   [overwrites wq planes: dead]
    zscore_mfma<<<dim3(8, 8, B_), dim3(256), 0, stream>>>(qkv_h, qkv_l, u, z);

    // 4) exact top-32 -> column records
    topk_cols_kernel<<<dim3(B_ * N_), dim3(64), 0, stream>>>(z, recs);

    // 5) convert proj_w -> transposed split planes [768][768]  (z now dead)
    conv_w_nt<<<dim3(768 / 64, 768 / 64), dim3(256), 0, stream>>>(
        proj_w, wp_t_h, wp_t_l, 768, 768);

    // 6) per-head softmax max + denominator (MFMA)
    attn_ml_mfma<<<dim3(16, H_, B_), dim3(256), 0, stream>>>(qkv_h, qkv_l, ml);

    // 7) sparse gather numerator -> out1 planes
    sparse_pv_kernel<<<dim3(B_ * N_), dim3(256), 0, stream>>>(
        qkv_h, qkv_l, Vf, recs, ml, head_scores, out1h, out1l);

    // 8) out = out1 @ proj_w + b
    gemm_proj<<<dim3(768 / 128, 4096 / 128), dim3(256), 0, stream>>>(
        out1h, out1l, wp_t_h, wp_t_l, proj_b, out);
}

// Round 8
// 313.609 us; speedup vs baseline: 2.0212x; 1.0266x over previous
//
#include <hip/hip_runtime.h>
#include <hip/hip_bf16.h>
#include <math.h>

#define B_ 4
#define N_ 1024
#define C_ 768
#define H_ 12
#define D_ 64
#define TOPK_ 32
#define EPS_ 1e-9f

#define LDA_ 40   // GEMM LDS row stride (bf16 elems): 32 used + 8 pad = 80 B
#define LK_  72   // attn LDS row stride: 64 used + 8 pad = 144 B (2-way = free)
#define QKS_ 1536 // Q,K plane row stride (elems)

typedef __attribute__((ext_vector_type(8))) short bf16x8;
typedef __attribute__((ext_vector_type(4))) float f32x4;
typedef unsigned short u16;

struct TopkRec { unsigned int cnt; unsigned short c[62]; };  // 128 B

__device__ __forceinline__ u16 f2bf(float f) {
    unsigned int u = __float_as_uint(f);
    u += 0x7fffu + ((u >> 16) & 1u);
    return (u16)(u >> 16);
}
__device__ __forceinline__ float bf2f(u16 h) {
    return __uint_as_float(((unsigned int)h) << 16);
}

// ---------------------------------------------------------------------------
// x convert (elementwise, no transpose): x f32 [M][K] -> hi/lo bf16 planes.
// ---------------------------------------------------------------------------
__global__ __launch_bounds__(256) void conv_x(
    const float* __restrict__ X, u16* __restrict__ Xh, u16* __restrict__ Xl)
{
    const size_t off = ((size_t)blockIdx.x * 256 + threadIdx.x) * 8;
    float4 a = *(const float4*)&X[off];
    float4 b = *(const float4*)&X[off + 4];
    float v[8] = {a.x, a.y, a.z, a.w, b.x, b.y, b.z, b.w};
    u16 hb[8], lb[8];
    #pragma unroll
    for (int i = 0; i < 8; ++i) {
        u16 hi = f2bf(v[i]);
        hb[i] = hi;
        lb[i] = f2bf(v[i] - bf2f(hi));
    }
    *(bf16x8*)&Xh[off] = *(const bf16x8*)&hb[0];
    *(bf16x8*)&Xl[off] = *(const bf16x8*)&lb[0];
}

// ---------------------------------------------------------------------------
// Weight convert: W f32 [K][Ncols] -> Wt_h, Wt_l bf16 [Ncols][K] (transposed
// hi/lo split). 64x64 LDS tile.
// ---------------------------------------------------------------------------
__global__ __launch_bounds__(256) void conv_w_nt(
    const float* __restrict__ W, u16* __restrict__ Wt_h, u16* __restrict__ Wt_l,
    int Kdim, int Ncols)
{
    __shared__ float Ts[64][65];
    const int t  = threadIdx.x;
    const int r  = t >> 2;            // 0..63
    const int cq = (t & 3) * 16;      // 0,16,32,48
    const int n0 = blockIdx.x * 64, k0 = blockIdx.y * 64;

    #pragma unroll
    for (int q = 0; q < 4; ++q) {
        float4 v = *(const float4*)&W[(size_t)(k0 + r) * Ncols + n0 + cq + q * 4];
        Ts[r][cq + q * 4 + 0] = v.x;
        Ts[r][cq + q * 4 + 1] = v.y;
        Ts[r][cq + q * 4 + 2] = v.z;
        Ts[r][cq + q * 4 + 3] = v.w;
    }
    __syncthreads();
    u16 hb[16], lb[16];
    #pragma unroll
    for (int i = 0; i < 16; ++i) {
        float val = Ts[cq + i][r];          // transpose
        u16 hi = f2bf(val);
        hb[i] = hi;
        lb[i] = f2bf(val - bf2f(hi));
    }
    const size_t obase = (size_t)(n0 + r) * Kdim + k0 + cq;
    *(bf16x8*)&Wt_h[obase]     = *(const bf16x8*)&hb[0];
    *(bf16x8*)&Wt_h[obase + 8] = *(const bf16x8*)&hb[8];
    *(bf16x8*)&Wt_l[obase]     = *(const bf16x8*)&lb[0];
    *(bf16x8*)&Wt_l[obase + 8] = *(const bf16x8*)&lb[8];
}

// ---------------------------------------------------------------------------
// qkv GEMM: qkv = x @ qkv_w + b. Pure-plane NT (A planes pre-split).
// Output: cols [0,1536) (Q,K) -> hi/lo planes stride 1536;
//         cols [1536,2304) (V) -> f32 [4096][768].
// ---------------------------------------------------------------------------
__global__ __launch_bounds__(256) void gemm_qkv(
    const u16* __restrict__ Ath, const u16* __restrict__ Atl,
    const u16* __restrict__ Bth, const u16* __restrict__ Btl,
    const float* __restrict__ bias,
    u16* __restrict__ Ch, u16* __restrict__ Cl, float* __restrict__ Vf)
{
    __shared__ u16 Ah[128 * LDA_], Al[128 * LDA_];
    __shared__ u16 Bh[128 * LDA_], Bl[128 * LDA_];
    const int t    = threadIdx.x;
    const int m0   = blockIdx.y * 128, n0 = blockIdx.x * 128;
    const int lane = t & 63, w = t >> 6;
    const int wm   = (w >> 1) * 64, wn = (w & 1) * 64;
    const int fr   = lane & 15, kg8 = lane >> 4;
    const int srow = t >> 1, shalf = t & 1;

    f32x4 acc[4][4];
    #pragma unroll
    for (int i = 0; i < 4; ++i)
        #pragma unroll
        for (int j = 0; j < 4; ++j)
            acc[i][j] = (f32x4){0.f, 0.f, 0.f, 0.f};

    for (int k0 = 0; k0 < C_; k0 += 32) {
        const size_t abase = (size_t)(m0 + srow) * C_ + k0 + shalf * 16;
        const size_t bbase = (size_t)(n0 + srow) * C_ + k0 + shalf * 16;
        bf16x8 ah0 = *(const bf16x8*)&Ath[abase];
        bf16x8 ah1 = *(const bf16x8*)&Ath[abase + 8];
        bf16x8 al0 = *(const bf16x8*)&Atl[abase];
        bf16x8 al1 = *(const bf16x8*)&Atl[abase + 8];
        bf16x8 bh0 = *(const bf16x8*)&Bth[bbase];
        bf16x8 bh1 = *(const bf16x8*)&Bth[bbase + 8];
        bf16x8 bl0 = *(const bf16x8*)&Btl[bbase];
        bf16x8 bl1 = *(const bf16x8*)&Btl[bbase + 8];

        __syncthreads();
        const int sb = srow * LDA_ + shalf * 16;
        *(bf16x8*)&Ah[sb]     = ah0;  *(bf16x8*)&Ah[sb + 8] = ah1;
        *(bf16x8*)&Al[sb]     = al0;  *(bf16x8*)&Al[sb + 8] = al1;
        *(bf16x8*)&Bh[sb]     = bh0;  *(bf16x8*)&Bh[sb + 8] = bh1;
        *(bf16x8*)&Bl[sb]     = bl0;  *(bf16x8*)&Bl[sb + 8] = bl1;
        __syncthreads();

        bf16x8 aF[4], bF[4], a2F[4], b2F[4];
        #pragma unroll
        for (int fm = 0; fm < 4; ++fm)
            aF[fm] = *(const bf16x8*)&Ah[(wm + fm * 16 + fr) * LDA_ + kg8 * 8];
        #pragma unroll
        for (int fn = 0; fn < 4; ++fn)
            bF[fn] = *(const bf16x8*)&Bh[(wn + fn * 16 + fr) * LDA_ + kg8 * 8];
        #pragma unroll
        for (int fm = 0; fm < 4; ++fm)
            #pragma unroll
            for (int fn = 0; fn < 4; ++fn)
                acc[fm][fn] = __builtin_amdgcn_mfma_f32_16x16x32_bf16(
                    aF[fm], bF[fn], acc[fm][fn], 0, 0, 0);
        #pragma unroll
        for (int fn = 0; fn < 4; ++fn)
            b2F[fn] = *(const bf16x8*)&Bl[(wn + fn * 16 + fr) * LDA_ + kg8 * 8];
        #pragma unroll
        for (int fm = 0; fm < 4; ++fm)
            #pragma unroll
            for (int fn = 0; fn < 4; ++fn)
                acc[fm][fn] = __builtin_amdgcn_mfma_f32_16x16x32_bf16(
                    aF[fm], b2F[fn], acc[fm][fn], 0, 0, 0);
        #pragma unroll
        for (int fm = 0; fm < 4; ++fm)
            a2F[fm] = *(const bf16x8*)&Al[(wm + fm * 16 + fr) * LDA_ + kg8 * 8];
        #pragma unroll
        for (int fm = 0; fm < 4; ++fm)
            #pragma unroll
            for (int fn = 0; fn < 4; ++fn)
                acc[fm][fn] = __builtin_amdgcn_mfma_f32_16x16x32_bf16(
                    a2F[fm], bF[fn], acc[fm][fn], 0, 0, 0);
    }

    const int r4 = (lane >> 4) * 4;
    const bool isV = (n0 >= 1536);
    #pragma unroll
    for (int fn = 0; fn < 4; ++fn) {
        const int col = n0 + wn + fn * 16 + fr;
        const float bv = bias[col];
        #pragma unroll
        for (int fm = 0; fm < 4; ++fm)
            #pragma unroll
            for (int i = 0; i < 4; ++i) {
                const int rown = m0 + wm + fm * 16 + r4 + i;
                float val = acc[fm][fn][i] + bv;
                if (isV) {
                    Vf[(size_t)rown * C_ + col - 1536] = val;
                } else {
                    const size_t o = (size_t)rown * QKS_ + col;
                    u16 hi = f2bf(val);
                    Ch[o] = hi;
                    Cl[o] = f2bf(val - bf2f(hi));
                }
            }
    }
}

// ---------------------------------------------------------------------------
// zscore (NT, both operands from Q,K planes, no conversion):
// z[b,n,m] = (scale/H) * Qc[n,:].Kc[m,:] + gumbel(u).
// ---------------------------------------------------------------------------
__global__ __launch_bounds__(256) void zscore_mfma(
    const u16* __restrict__ Qh, const u16* __restrict__ Ql,
    const float* __restrict__ u, float* __restrict__ z)
{
    __shared__ u16 Ah[128 * LDA_], Al[128 * LDA_];
    __shared__ u16 Bh[128 * LDA_], Bl[128 * LDA_];
    const int t    = threadIdx.x;
    const int b    = blockIdx.z;
    const int n0   = blockIdx.y * 128, m0 = blockIdx.x * 128;
    const int lane = t & 63, w = t >> 6;
    const int wm   = (w >> 1) * 64, wn = (w & 1) * 64;
    const int fr   = lane & 15, kg8 = lane >> 4;
    const int srow = t >> 1, shalf = t & 1;

    f32x4 acc[4][4];
    #pragma unroll
    for (int i = 0; i < 4; ++i)
        #pragma unroll
        for (int j = 0; j < 4; ++j)
            acc[i][j] = (f32x4){0.f, 0.f, 0.f, 0.f};

    for (int k0 = 0; k0 < C_; k0 += 32) {
        const size_t abase = (size_t)(b * N_ + n0 + srow) * QKS_ + k0 + shalf * 16;
        const size_t bbase = (size_t)(b * N_ + m0 + srow) * QKS_ + 768 + k0 + shalf * 16;
        bf16x8 ah0 = *(const bf16x8*)&Qh[abase];
        bf16x8 ah1 = *(const bf16x8*)&Qh[abase + 8];
        bf16x8 al0 = *(const bf16x8*)&Ql[abase];
        bf16x8 al1 = *(const bf16x8*)&Ql[abase + 8];
        bf16x8 bh0 = *(const bf16x8*)&Qh[bbase];
        bf16x8 bh1 = *(const bf16x8*)&Qh[bbase + 8];
        bf16x8 bl0 = *(const bf16x8*)&Ql[bbase];
        bf16x8 bl1 = *(const bf16x8*)&Ql[bbase + 8];

        __syncthreads();
        const int sb = srow * LDA_ + shalf * 16;
        *(bf16x8*)&Ah[sb]     = ah0;  *(bf16x8*)&Ah[sb + 8] = ah1;
        *(bf16x8*)&Al[sb]     = al0;  *(bf16x8*)&Al[sb + 8] = al1;
        *(bf16x8*)&Bh[sb]     = bh0;  *(bf16x8*)&Bh[sb + 8] = bh1;
        *(bf16x8*)&Bl[sb]     = bl0;  *(bf16x8*)&Bl[sb + 8] = bl1;
        __syncthreads();

        bf16x8 aF[4], bF[4], a2F[4], b2F[4];
        #pragma unroll
        for (int fm = 0; fm < 4; ++fm)
            aF[fm] = *(const bf16x8*)&Ah[(wm + fm * 16 + fr) * LDA_ + kg8 * 8];
        #pragma unroll
        for (int fn = 0; fn < 4; ++fn)
            bF[fn] = *(const bf16x8*)&Bh[(wn + fn * 16 + fr) * LDA_ + kg8 * 8];
        #pragma unroll
        for (int fm = 0; fm < 4; ++fm)
            #pragma unroll
            for (int fn = 0; fn < 4; ++fn)
                acc[fm][fn] = __builtin_amdgcn_mfma_f32_16x16x32_bf16(
                    aF[fm], bF[fn], acc[fm][fn], 0, 0, 0);
        #pragma unroll
        for (int fn = 0; fn < 4; ++fn)
            b2F[fn] = *(const bf16x8*)&Bl[(wn + fn * 16 + fr) * LDA_ + kg8 * 8];
        #pragma unroll
        for (int fm = 0; fm < 4; ++fm)
            #pragma unroll
            for (int fn = 0; fn < 4; ++fn)
                acc[fm][fn] = __builtin_amdgcn_mfma_f32_16x16x32_bf16(
                    aF[fm], b2F[fn], acc[fm][fn], 0, 0, 0);
        #pragma unroll
        for (int fm = 0; fm < 4; ++fm)
            a2F[fm] = *(const bf16x8*)&Al[(wm + fm * 16 + fr) * LDA_ + kg8 * 8];
        #pragma unroll
        for (int fm = 0; fm < 4; ++fm)
            #pragma unroll
            for (int fn = 0; fn < 4; ++fn)
                acc[fm][fn] = __builtin_amdgcn_mfma_f32_16x16x32_bf16(
                    a2F[fm], bF[fn], acc[fm][fn], 0, 0, 0);
    }

    const float sc = 0.125f / 12.0f;
    const int r4 = (lane >> 4) * 4;
    #pragma unroll
    for (int fn = 0; fn < 4; ++fn) {
        const int m = m0 + wn + fn * 16 + fr;
        #pragma unroll
        for (int fm = 0; fm < 4; ++fm)
            #pragma unroll
            for (int i = 0; i < 4; ++i) {
                const int n = n0 + wm + fm * 16 + r4 + i;
                const float uv = u[((size_t)(b * N_ + n)) * N_ + m];
                const float g  = -logf(-logf(uv + EPS_) + EPS_);
                z[((size_t)(b * N_ + n)) * N_ + m] = acc[fm][fn][i] * sc + g;
            }
    }
}

// ---------------------------------------------------------------------------
// Per row: exact 32nd-largest of z; emit all cols >= thresh (cap 62).
// ---------------------------------------------------------------------------
__global__ __launch_bounds__(64) void topk_cols_kernel(
    const float* __restrict__ z, TopkRec* __restrict__ recs)
{
    const int row  = blockIdx.x;
    const int lane = threadIdx.x;
    const float* zr = z + (size_t)row * N_;
    float zv[16], wk[16];
    #pragma unroll
    for (int j = 0; j < 16; ++j) { zv[j] = zr[lane + 64 * j]; wk[j] = zv[j]; }

    float thresh = -INFINITY;
    for (int it = 0; it < TOPK_; ++it) {
        float lm = wk[0]; int li = 0;
        #pragma unroll
        for (int j = 1; j < 16; ++j)
            if (wk[j] > lm) { lm = wk[j]; li = j; }
        float gm = lm;
        gm = fmaxf(gm, __shfl_xor(gm, 1));
        gm = fmaxf(gm, __shfl_xor(gm, 2));
        gm = fmaxf(gm, __shfl_xor(gm, 4));
        gm = fmaxf(gm, __shfl_xor(gm, 8));
        gm = fmaxf(gm, __shfl_xor(gm, 16));
        gm = fmaxf(gm, __shfl_xor(gm, 32));
        unsigned long long has = __ballot(lm == gm);
        int first = __ffsll((unsigned long long)has) - 1;
        if (lane == first) wk[li] = -INFINITY;
        thresh = gm;
    }

    const unsigned long long below = ((unsigned long long)1 << lane) - 1;
    unsigned int basec = 0;
    TopkRec* rec = recs + row;
    #pragma unroll
    for (int j = 0; j < 16; ++j) {
        unsigned long long wmask = __ballot(zv[j] >= thresh);
        if (zv[j] >= thresh) {
            unsigned int pos = basec + (unsigned int)__popcll(wmask & below);
            if (pos < 62u) rec->c[pos] = (unsigned short)(lane + 64 * j);
        }
        basec += (unsigned int)__popcll(wmask);
    }
    if (lane == 0) rec->cnt = basec > 62u ? 62u : basec;
}

// ---------------------------------------------------------------------------
// Pass A (MFMA): per (b,h,64-row q-tile): softmax max m and denominator l
// over all 1024 cols. 4 waves; Q fragments in regs; K staged hi/lo in LDS.
// ---------------------------------------------------------------------------
__global__ __launch_bounds__(256) void attn_ml_mfma(
    const u16* __restrict__ qh, const u16* __restrict__ ql,
    float2* __restrict__ ml)
{
    __shared__ u16 KsH[128 * LK_], KsL[128 * LK_];

    const int t    = threadIdx.x;
    const int lane = t & 63, w = t >> 6;
    const int fr   = lane & 15, kg8 = lane >> 4;
    const int n0   = blockIdx.x * 64;
    const int hd   = blockIdx.y;
    const int b    = blockIdx.z;

    bf16x8 aH[2], aL[2];
    {
        const size_t qb = (size_t)(b * N_ + n0 + w * 16 + fr) * QKS_ + hd * 64 + kg8 * 8;
        aH[0] = *(const bf16x8*)&qh[qb];
        aH[1] = *(const bf16x8*)&qh[qb + 32];
        aL[0] = *(const bf16x8*)&ql[qb];
        aL[1] = *(const bf16x8*)&ql[qb + 32];
    }

    float mrun[4], lsum[4];
    #pragma unroll
    for (int i = 0; i < 4; ++i) { mrun[i] = -INFINITY; lsum[i] = 0.f; }

    const int kr = t >> 1, kd = (t & 1) * 32;   // K staging: row, 32-d half

    for (int m0 = 0; m0 < N_; m0 += 128) {
        const size_t kb = (size_t)(b * N_ + m0 + kr) * QKS_ + 768 + hd * 64 + kd;
        bf16x8 h0 = *(const bf16x8*)&qh[kb];
        bf16x8 h1 = *(const bf16x8*)&qh[kb + 8];
        bf16x8 h2 = *(const bf16x8*)&qh[kb + 16];
        bf16x8 h3 = *(const bf16x8*)&qh[kb + 24];
        bf16x8 l0 = *(const bf16x8*)&ql[kb];
        bf16x8 l1 = *(const bf16x8*)&ql[kb + 8];
        bf16x8 l2 = *(const bf16x8*)&ql[kb + 16];
        bf16x8 l3 = *(const bf16x8*)&ql[kb + 24];

        __syncthreads();
        const int sb = kr * LK_ + kd;
        *(bf16x8*)&KsH[sb]      = h0;  *(bf16x8*)&KsH[sb + 8]  = h1;
        *(bf16x8*)&KsH[sb + 16] = h2;  *(bf16x8*)&KsH[sb + 24] = h3;
        *(bf16x8*)&KsL[sb]      = l0;  *(bf16x8*)&KsL[sb + 8]  = l1;
        *(bf16x8*)&KsL[sb + 16] = l2;  *(bf16x8*)&KsL[sb + 24] = l3;
        __syncthreads();

        f32x4 acc[8];
        #pragma unroll
        for (int fn = 0; fn < 8; ++fn) acc[fn] = (f32x4){0.f, 0.f, 0.f, 0.f};

        #pragma unroll
        for (int kk = 0; kk < 2; ++kk) {
            #pragma unroll
            for (int fn = 0; fn < 8; ++fn) {
                const int bidx = (fn * 16 + fr) * LK_ + kk * 32 + kg8 * 8;
                bf16x8 bH = *(const bf16x8*)&KsH[bidx];
                bf16x8 bL = *(const bf16x8*)&KsL[bidx];
                acc[fn] = __builtin_amdgcn_mfma_f32_16x16x32_bf16(
                    aH[kk], bH, acc[fn], 0, 0, 0);
                acc[fn] = __builtin_amdgcn_mfma_f32_16x16x32_bf16(
                    aH[kk], bL, acc[fn], 0, 0, 0);
                acc[fn] = __builtin_amdgcn_mfma_f32_16x16x32_bf16(
                    aL[kk], bH, acc[fn], 0, 0, 0);
            }
        }

        #pragma unroll
        for (int reg = 0; reg < 4; ++reg) {
            float tmax = acc[0][reg];
            #pragma unroll
            for (int fn = 1; fn < 8; ++fn) tmax = fmaxf(tmax, acc[fn][reg]);
            tmax *= 0.125f;
            tmax = fmaxf(tmax, __shfl_xor(tmax, 1));
            tmax = fmaxf(tmax, __shfl_xor(tmax, 2));
            tmax = fmaxf(tmax, __shfl_xor(tmax, 4));
            tmax = fmaxf(tmax, __shfl_xor(tmax, 8));
            float mnew  = fmaxf(mrun[reg], tmax);
            float alpha = expf(mrun[reg] - mnew);
            float tsum = 0.f;
            #pragma unroll
            for (int fn = 0; fn < 8; ++fn)
                tsum += expf(acc[fn][reg] * 0.125f - mnew);
            tsum += __shfl_xor(tsum, 1);
            tsum += __shfl_xor(tsum, 2);
            tsum += __shfl_xor(tsum, 4);
            tsum += __shfl_xor(tsum, 8);
            lsum[reg] = lsum[reg] * alpha + tsum;
            mrun[reg] = mnew;
        }
    }

    if (fr == 0) {
        #pragma unroll
        for (int reg = 0; reg < 4; ++reg)
            ml[((size_t)(b * H_ + hd)) * N_ + n0 + w * 16 + kg8 * 4 + reg] =
                make_float2(mrun[reg], lsum[reg]);
    }
}

// ---------------------------------------------------------------------------
// Pass B: sparse gather numerator. Lane = (c,dq): c=lane>>2 owns a column,
// dq=lane&3 owns 16 dims. V read as f32.
// ---------------------------------------------------------------------------
__global__ __launch_bounds__(256) void sparse_pv_kernel(
    const u16* __restrict__ qh, const u16* __restrict__ ql,
    const float* __restrict__ Vf,
    const TopkRec* __restrict__ recs, const float2* __restrict__ ml,
    const float* __restrict__ head_scores,
    u16* __restrict__ out1h, u16* __restrict__ out1l)
{
    __shared__ int cols_s[62];
    __shared__ int cnt_s;

    const int t    = threadIdx.x;
    const int lane = t & 63, wv = t >> 6;
    const int c4   = lane >> 2;      // column slot 0..15
    const int dq   = lane & 3;       // 16-dim quarter
    const int row  = blockIdx.x;     // b*N + n
    const int b    = row >> 10, n = row & 1023;

    const TopkRec* rec = recs + row;
    if (t == 0) cnt_s = (int)min(rec->cnt, 62u);
    if (t < 62) cols_s[t] = rec->c[t];

    float hsum = 0.f;
    #pragma unroll
    for (int i = 0; i < H_; ++i) hsum += head_scores[i];
    const float hs_mean = hsum * (1.0f / 12.0f);
    __syncthreads();
    const int cnt = cnt_s;
    const int nbatch = (cnt + 15) >> 4;

    for (int hd = wv; hd < H_; hd += 4) {
        float qv[16];
        {
            const size_t qb = (size_t)row * QKS_ + hd * 64 + dq * 16;
            bf16x8 qh0 = *(const bf16x8*)&qh[qb], qh1 = *(const bf16x8*)&qh[qb + 8];
            bf16x8 ql0 = *(const bf16x8*)&ql[qb], ql1 = *(const bf16x8*)&ql[qb + 8];
            #pragma unroll
            for (int i = 0; i < 8; ++i) {
                qv[i]     = bf2f((u16)qh0[i]) + bf2f((u16)ql0[i]);
                qv[i + 8] = bf2f((u16)qh1[i]) + bf2f((u16)ql1[i]);
            }
        }
        const float2 mlv = ml[((size_t)(b * H_ + hd)) * N_ + n];

        float acc[16];
        #pragma unroll
        for (int i = 0; i < 16; ++i) acc[i] = 0.f;

        for (int batch = 0; batch < nbatch; ++batch) {
            const int cidx  = batch * 16 + c4;
            const bool valid = (cidx < cnt);
            const int col   = cols_s[valid ? cidx : cnt - 1];

            const size_t kb = (size_t)(b * N_ + col) * QKS_ + 768 + hd * 64 + dq * 16;
            bf16x8 kh0 = *(const bf16x8*)&qh[kb], kh1 = *(const bf16x8*)&qh[kb + 8];
            bf16x8 kl0 = *(const bf16x8*)&ql[kb], kl1 = *(const bf16x8*)&ql[kb + 8];
            float dot = 0.f;
            #pragma unroll
            for (int i = 0; i < 8; ++i) {
                dot += qv[i]     * (bf2f((u16)kh0[i]) + bf2f((u16)kl0[i]));
                dot += qv[i + 8] * (bf2f((u16)kh1[i]) + bf2f((u16)kl1[i]));
            }
            dot += __shfl_xor(dot, 1);
            dot += __shfl_xor(dot, 2);
            float p = valid ? expf(dot * 0.125f - mlv.x) : 0.f;

            const float* vb = &Vf[(size_t)(b * N_ + col) * C_ + hd * 64 + dq * 16];
            #pragma unroll
            for (int q = 0; q < 4; ++q) {
                float4 v4 = *(const float4*)&vb[q * 4];
                acc[q * 4 + 0] += p * v4.x;
                acc[q * 4 + 1] += p * v4.y;
                acc[q * 4 + 2] += p * v4.z;
                acc[q * 4 + 3] += p * v4.w;
            }
        }

        #pragma unroll
        for (int d = 4; d < 64; d <<= 1)
            #pragma unroll
            for (int i = 0; i < 16; ++i)
                acc[i] += __shfl_xor(acc[i], d);

        if (c4 == 0) {
            const float s = hs_mean / mlv.y;
            u16 hb[16], lb[16];
            #pragma unroll
            for (int i = 0; i < 16; ++i) {
                float val = acc[i] * s;
                u16 hi = f2bf(val);
                hb[i] = hi;
                lb[i] = f2bf(val - bf2f(hi));
            }
            const size_t ob = (size_t)row * C_ + hd * 64 + dq * 16;
            *(bf16x8*)&out1h[ob]     = *(const bf16x8*)&hb[0];
            *(bf16x8*)&out1h[ob + 8] = *(const bf16x8*)&hb[8];
            *(bf16x8*)&out1l[ob]     = *(const bf16x8*)&lb[0];
            *(bf16x8*)&out1l[ob + 8] = *(const bf16x8*)&lb[8];
        }
    }
}

// ---------------------------------------------------------------------------
// proj GEMM: out = out1 @ proj_w + b (f32 out). Pure-bf16 planes (NT).
// ---------------------------------------------------------------------------
__global__ __launch_bounds__(256) void gemm_proj(
    const u16* __restrict__ Ath, const u16* __restrict__ Atl,
    const u16* __restrict__ Bth, const u16* __restrict__ Btl,
    const float* __restrict__ bias, float* __restrict__ Cm)
{
    __shared__ u16 Ah[128 * LDA_], Al[128 * LDA_];
    __shared__ u16 Bh[128 * LDA_], Bl[128 * LDA_];
    const int t    = threadIdx.x;
    const int m0   = blockIdx.y * 128, n0 = blockIdx.x * 128;
    const int lane = t & 63, w = t >> 6;
    const int wm   = (w >> 1) * 64, wn = (w & 1) * 64;
    const int fr   = lane & 15, kg8 = lane >> 4;
    const int srow = t >> 1, shalf = t & 1;

    f32x4 acc[4][4];
    #pragma unroll
    for (int i = 0; i < 4; ++i)
        #pragma unroll
        for (int j = 0; j < 4; ++j)
            acc[i][j] = (f32x4){0.f, 0.f, 0.f, 0.f};

    for (int k0 = 0; k0 < C_; k0 += 32) {
        const size_t abase = (size_t)(m0 + srow) * C_ + k0 + shalf * 16;
        const size_t bbase = (size_t)(n0 + srow) * C_ + k0 + shalf * 16;
        bf16x8 ah0 = *(const bf16x8*)&Ath[abase];
        bf16x8 ah1 = *(const bf16x8*)&Ath[abase + 8];
        bf16x8 al0 = *(const bf16x8*)&Atl[abase];
        bf16x8 al1 = *(const bf16x8*)&Atl[abase + 8];
        bf16x8 bh0 = *(const bf16x8*)&Bth[bbase];
        bf16x8 bh1 = *(const bf16x8*)&Bth[bbase + 8];
        bf16x8 bl0 = *(const bf16x8*)&Btl[bbase];
        bf16x8 bl1 = *(const bf16x8*)&Btl[bbase + 8];

        __syncthreads();
        const int sb = srow * LDA_ + shalf * 16;
        *(bf16x8*)&Ah[sb]     = ah0;  *(bf16x8*)&Ah[sb + 8] = ah1;
        *(bf16x8*)&Al[sb]     = al0;  *(bf16x8*)&Al[sb + 8] = al1;
        *(bf16x8*)&Bh[sb]     = bh0;  *(bf16x8*)&Bh[sb + 8] = bh1;
        *(bf16x8*)&Bl[sb]     = bl0;  *(bf16x8*)&Bl[sb + 8] = bl1;
        __syncthreads();

        bf16x8 aF[4], bF[4], a2F[4], b2F[4];
        #pragma unroll
        for (int fm = 0; fm < 4; ++fm)
            aF[fm] = *(const bf16x8*)&Ah[(wm + fm * 16 + fr) * LDA_ + kg8 * 8];
        #pragma unroll
        for (int fn = 0; fn < 4; ++fn)
            bF[fn] = *(const bf16x8*)&Bh[(wn + fn * 16 + fr) * LDA_ + kg8 * 8];
        #pragma unroll
        for (int fm = 0; fm < 4; ++fm)
            #pragma unroll
            for (int fn = 0; fn < 4; ++fn)
                acc[fm][fn] = __builtin_amdgcn_mfma_f32_16x16x32_bf16(
                    aF[fm], bF[fn], acc[fm][fn], 0, 0, 0);
        #pragma unroll
        for (int fn = 0; fn < 4; ++fn)
            b2F[fn] = *(const bf16x8*)&Bl[(wn + fn * 16 + fr) * LDA_ + kg8 * 8];
        #pragma unroll
        for (int fm = 0; fm < 4; ++fm)
            #pragma unroll
            for (int fn = 0; fn < 4; ++fn)
                acc[fm][fn] = __builtin_amdgcn_mfma_f32_16x16x32_bf16(
                    aF[fm], b2F[fn], acc[fm][fn], 0, 0, 0);
        #pragma unroll
        for (int fm = 0; fm < 4; ++fm)
            a2F[fm] = *(const bf16x8*)&Al[(wm + fm * 16 + fr) * LDA_ + kg8 * 8];
        #pragma unroll
        for (int fm = 0; fm < 4; ++fm)
            #pragma unroll
            for (int fn = 0; fn < 4; ++fn)
                acc[fm][fn] = __builtin_amdgcn_mfma_f32_16x16x32_bf16(
                    a2F[fm], bF[fn], acc[fm][fn], 0, 0, 0);
    }

    const int r4 = (lane >> 4) * 4;
    #pragma unroll
    for (int fn = 0; fn < 4; ++fn) {
        const int col = n0 + wn + fn * 16 + fr;
        const float bv = bias[col];
        #pragma unroll
        for (int fm = 0; fm < 4; ++fm)
            #pragma unroll
            for (int i = 0; i < 4; ++i)
                Cm[(size_t)(m0 + wm + fm * 16 + r4 + i) * C_ + col] =
                    acc[fm][fn][i] + bv;
    }
}

// ---------------------------------------------------------------------------
extern "C" void kernel_launch(void* const* d_in, const int* in_sizes, int n_in,
                              void* d_out, int out_size, void* d_ws, size_t ws_size,
                              hipStream_t stream)
{
    (void)in_sizes; (void)n_in; (void)out_size; (void)ws_size;
    const float* x           = (const float*)d_in[0];
    const float* u           = (const float*)d_in[1];
    const float* qkv_w       = (const float*)d_in[2];
    const float* qkv_b       = (const float*)d_in[3];
    const float* proj_w      = (const float*)d_in[4];
    const float* proj_b      = (const float*)d_in[5];
    const float* head_scores = (const float*)d_in[6];
    float* out = (float*)d_out;

    // Workspace (proven 55,050,240-byte footprint):
    //   [0, 12582912)            qkv_h  bf16 [4096][1536]  (Q,K planes)
    //   [12582912, 25165824)     qkv_l
    //   [25165824, 37748736)     V f32 [4096][768]
    //   R = [37748736, 55050240) (17,301,504 B), time-shared:
    //     phase1: wq_t_h (3,538,944) | wq_t_l (3,538,944)
    //     phase2: z f32 (16,777,216; wq planes dead) + recs (524,288)
    //     phase3 (z dead): wp_t_h | wp_t_l | ml | out1_h | out1_l
    // d_out (12,582,912 B) time-shared: x_h | x_l planes (dead after gemm_qkv;
    //   overwritten by gemm_proj at the end).
    char* ws = (char*)d_ws;
    u16*     qkv_h  = (u16*)ws;
    u16*     qkv_l  = (u16*)(ws + 12582912);
    float*   Vf     = (float*)(ws + 25165824);
    char*    R      = ws + 37748736;
    u16*     wq_t_h = (u16*)R;
    u16*     wq_t_l = (u16*)(R + 3538944);
    float*   z      = (float*)R;
    TopkRec* recs   = (TopkRec*)(R + 16777216);
    u16*     wp_t_h = (u16*)R;
    u16*     wp_t_l = (u16*)(R + 1179648);
    float2*  ml     = (float2*)(R + 2359296);
    u16*     out1h  = (u16*)(R + 2752512);
    u16*     out1l  = (u16*)(R + 9043968);
    u16*     x_h    = (u16*)d_out;                      // 6,291,456 B
    u16*     x_l    = (u16*)((char*)d_out + 6291456);   // 6,291,456 B

    // 0) pre-split x -> hi/lo planes (stored in d_out, dead before proj)
    conv_x<<<dim3(4096 * 768 / 8 / 256), dim3(256), 0, stream>>>(x, x_h, x_l);

    // 1) convert qkv_w -> transposed split planes [2304][768]
    conv_w_nt<<<dim3(2304 / 64, 768 / 64), dim3(256), 0, stream>>>(
        qkv_w, wq_t_h, wq_t_l, 768, 2304);

    // 2) qkv = x @ qkv_w + b  -> Q,K planes + V f32  (pure-plane NT)
    gemm_qkv<<<dim3(2304 / 128, 4096 / 128), dim3(256), 0, stream>>>(
        x_h, x_l, wq_t_h, wq_t_l, qkv_b, qkv_h, qkv_l, Vf);

    // 3) z = (scale/H) Qc.Kc^T + gumbel(u)   [overwrites wq planes: dead]
    zscore_mfma<<<dim3(8, 8, B_), dim3(256), 0, stream>>>(qkv_h, qkv_l, u, z);

    // 4) exact top-32 -> column records
    topk_cols_kernel<<<dim3(B_ * N_), dim3(64), 0, stream>>>(z, recs);

    // 5) convert proj_w -> transposed split planes [768][768]  (z now dead)
    conv_w_nt<<<dim3(768 / 64, 768 / 64), dim3(256), 0, stream>>>(
        proj_w, wp_t_h, wp_t_l, 768, 768);

    // 6) per-head softmax max + denominator (MFMA)
    attn_ml_mfma<<<dim3(16, H_, B_), dim3(256), 0, stream>>>(qkv_h, qkv_l, ml);

    // 7) sparse gather numerator -> out1 planes
    sparse_pv_kernel<<<dim3(B_ * N_), dim3(256), 0, stream>>>(
        qkv_h, qkv_l, Vf, recs, ml, head_scores, out1h, out1l);

    // 8) out = out1 @ proj_w + b
    gemm_proj<<<dim3(768 / 128, 4096 / 128), dim3(256), 0, stream>>>(
        out1h, out1l, wp_t_h, wp_t_l, proj_b, out);
}

// Round 9
// 313.033 us; speedup vs baseline: 2.0249x; 1.0018x over previous
//
#include <hip/hip_runtime.h>
#include <hip/hip_bf16.h>
#include <math.h>

#define B_ 4
#define N_ 1024
#define C_ 768
#define H_ 12
#define D_ 64
#define TOPK_ 32
#define EPS_ 1e-9f

#define LDN_ 32   // linear LDS row stride (u16) for global_load_lds staging
#define LK_  72   // attn LDS row stride: 64 used + 8 pad = 144 B
#define QKS_ 1536 // Q,K plane row stride (elems)

typedef __attribute__((ext_vector_type(8))) short bf16x8;
typedef __attribute__((ext_vector_type(4))) float f32x4;
typedef unsigned short u16;

struct TopkRec { unsigned int cnt; unsigned short c[62]; };  // 128 B

__device__ __forceinline__ u16 f2bf(float f) {
    unsigned int u = __float_as_uint(f);
    u += 0x7fffu + ((u >> 16) & 1u);
    return (u16)(u >> 16);
}
__device__ __forceinline__ float bf2f(u16 h) {
    return __uint_as_float(((unsigned int)h) << 16);
}

// async global->LDS, 16B per lane; LDS dest is wave-uniform base + lane*16.
__device__ __forceinline__ void gll16(const void* g, void* l) {
    __builtin_amdgcn_global_load_lds(
        (const __attribute__((address_space(1))) void*)g,
        (__attribute__((address_space(3))) void*)l, 16, 0, 0);
}

// ---------------------------------------------------------------------------
// x convert (elementwise): x f32 [M][K] -> hi/lo bf16 planes.
// ---------------------------------------------------------------------------
__global__ __launch_bounds__(256) void conv_x(
    const float* __restrict__ X, u16* __restrict__ Xh, u16* __restrict__ Xl)
{
    const size_t off = ((size_t)blockIdx.x * 256 + threadIdx.x) * 8;
    float4 a = *(const float4*)&X[off];
    float4 b = *(const float4*)&X[off + 4];
    float v[8] = {a.x, a.y, a.z, a.w, b.x, b.y, b.z, b.w};
    u16 hb[8], lb[8];
    #pragma unroll
    for (int i = 0; i < 8; ++i) {
        u16 hi = f2bf(v[i]);
        hb[i] = hi;
        lb[i] = f2bf(v[i] - bf2f(hi));
    }
    *(bf16x8*)&Xh[off] = *(const bf16x8*)&hb[0];
    *(bf16x8*)&Xl[off] = *(const bf16x8*)&lb[0];
}

// ---------------------------------------------------------------------------
// Weight convert: W f32 [K][Ncols] -> Wt_h, Wt_l bf16 [Ncols][K] transposed.
// ---------------------------------------------------------------------------
__global__ __launch_bounds__(256) void conv_w_nt(
    const float* __restrict__ W, u16* __restrict__ Wt_h, u16* __restrict__ Wt_l,
    int Kdim, int Ncols)
{
    __shared__ float Ts[64][65];
    const int t  = threadIdx.x;
    const int r  = t >> 2;
    const int cq = (t & 3) * 16;
    const int n0 = blockIdx.x * 64, k0 = blockIdx.y * 64;

    #pragma unroll
    for (int q = 0; q < 4; ++q) {
        float4 v = *(const float4*)&W[(size_t)(k0 + r) * Ncols + n0 + cq + q * 4];
        Ts[r][cq + q * 4 + 0] = v.x;
        Ts[r][cq + q * 4 + 1] = v.y;
        Ts[r][cq + q * 4 + 2] = v.z;
        Ts[r][cq + q * 4 + 3] = v.w;
    }
    __syncthreads();
    u16 hb[16], lb[16];
    #pragma unroll
    for (int i = 0; i < 16; ++i) {
        float val = Ts[cq + i][r];
        u16 hi = f2bf(val);
        hb[i] = hi;
        lb[i] = f2bf(val - bf2f(hi));
    }
    const size_t obase = (size_t)(n0 + r) * Kdim + k0 + cq;
    *(bf16x8*)&Wt_h[obase]     = *(const bf16x8*)&hb[0];
    *(bf16x8*)&Wt_h[obase + 8] = *(const bf16x8*)&hb[8];
    *(bf16x8*)&Wt_l[obase]     = *(const bf16x8*)&lb[0];
    *(bf16x8*)&Wt_l[obase + 8] = *(const bf16x8*)&lb[8];
}

// ---------------------------------------------------------------------------
// qkv GEMM: pure-plane NT, global_load_lds staging, linear LDS.
// ---------------------------------------------------------------------------
__global__ __launch_bounds__(256) void gemm_qkv(
    const u16* __restrict__ Ath, const u16* __restrict__ Atl,
    const u16* __restrict__ Bth, const u16* __restrict__ Btl,
    const float* __restrict__ bias,
    u16* __restrict__ Ch, u16* __restrict__ Cl, float* __restrict__ Vf)
{
    __shared__ u16 Ah[128 * LDN_], Al[128 * LDN_];
    __shared__ u16 Bh[128 * LDN_], Bl[128 * LDN_];
    const int t    = threadIdx.x;
    const int m0   = blockIdx.y * 128, n0 = blockIdx.x * 128;
    const int lane = t & 63, w = t >> 6;
    const int wm   = (w >> 1) * 64, wn = (w & 1) * 64;
    const int fr   = lane & 15, kg8 = lane >> 4;
    const int w16  = w * 16;
    const int r4s  = lane >> 2, q4s = (lane & 3) * 8;   // staging row/col

    f32x4 acc[4][4];
    #pragma unroll
    for (int i = 0; i < 4; ++i)
        #pragma unroll
        for (int j = 0; j < 4; ++j)
            acc[i][j] = (f32x4){0.f, 0.f, 0.f, 0.f};

    for (int k0 = 0; k0 < C_; k0 += 32) {
        __syncthreads();                 // prev MFMA fragment reads done
        {
            const size_t ga0 = (size_t)(m0 + w16 + r4s) * C_ + k0 + q4s;
            const size_t ga1 = ga0 + (size_t)64 * C_;
            const size_t gb0 = (size_t)(n0 + w16 + r4s) * C_ + k0 + q4s;
            const size_t gb1 = gb0 + (size_t)64 * C_;
            gll16(&Ath[ga0], &Ah[w16 * LDN_]);
            gll16(&Ath[ga1], &Ah[(64 + w16) * LDN_]);
            gll16(&Atl[ga0], &Al[w16 * LDN_]);
            gll16(&Atl[ga1], &Al[(64 + w16) * LDN_]);
            gll16(&Bth[gb0], &Bh[w16 * LDN_]);
            gll16(&Bth[gb1], &Bh[(64 + w16) * LDN_]);
            gll16(&Btl[gb0], &Bl[w16 * LDN_]);
            gll16(&Btl[gb1], &Bl[(64 + w16) * LDN_]);
        }
        __syncthreads();                 // vmcnt drained -> LDS visible

        bf16x8 aF[4], bF[4], a2F[4], b2F[4];
        #pragma unroll
        for (int fm = 0; fm < 4; ++fm)
            aF[fm] = *(const bf16x8*)&Ah[(wm + fm * 16 + fr) * LDN_ + kg8 * 8];
        #pragma unroll
        for (int fn = 0; fn < 4; ++fn)
            bF[fn] = *(const bf16x8*)&Bh[(wn + fn * 16 + fr) * LDN_ + kg8 * 8];
        #pragma unroll
        for (int fm = 0; fm < 4; ++fm)
            #pragma unroll
            for (int fn = 0; fn < 4; ++fn)
                acc[fm][fn] = __builtin_amdgcn_mfma_f32_16x16x32_bf16(
                    aF[fm], bF[fn], acc[fm][fn], 0, 0, 0);
        #pragma unroll
        for (int fn = 0; fn < 4; ++fn)
            b2F[fn] = *(const bf16x8*)&Bl[(wn + fn * 16 + fr) * LDN_ + kg8 * 8];
        #pragma unroll
        for (int fm = 0; fm < 4; ++fm)
            #pragma unroll
            for (int fn = 0; fn < 4; ++fn)
                acc[fm][fn] = __builtin_amdgcn_mfma_f32_16x16x32_bf16(
                    aF[fm], b2F[fn], acc[fm][fn], 0, 0, 0);
        #pragma unroll
        for (int fm = 0; fm < 4; ++fm)
            a2F[fm] = *(const bf16x8*)&Al[(wm + fm * 16 + fr) * LDN_ + kg8 * 8];
        #pragma unroll
        for (int fm = 0; fm < 4; ++fm)
            #pragma unroll
            for (int fn = 0; fn < 4; ++fn)
                acc[fm][fn] = __builtin_amdgcn_mfma_f32_16x16x32_bf16(
                    a2F[fm], bF[fn], acc[fm][fn], 0, 0, 0);
    }

    const int r4 = (lane >> 4) * 4;
    const bool isV = (n0 >= 1536);
    #pragma unroll
    for (int fn = 0; fn < 4; ++fn) {
        const int col = n0 + wn + fn * 16 + fr;
        const float bv = bias[col];
        #pragma unroll
        for (int fm = 0; fm < 4; ++fm)
            #pragma unroll
            for (int i = 0; i < 4; ++i) {
                const int rown = m0 + wm + fm * 16 + r4 + i;
                float val = acc[fm][fn][i] + bv;
                if (isV) {
                    Vf[(size_t)rown * C_ + col - 1536] = val;
                } else {
                    const size_t o = (size_t)rown * QKS_ + col;
                    u16 hi = f2bf(val);
                    Ch[o] = hi;
                    Cl[o] = f2bf(val - bf2f(hi));
                }
            }
    }
}

// ---------------------------------------------------------------------------
// zscore (NT from Q,K planes), global_load_lds staging, linear LDS.
// z[b,n,m] = (scale/H) * Qc[n,:].Kc[m,:] + gumbel(u).
// ---------------------------------------------------------------------------
__global__ __launch_bounds__(256) void zscore_mfma(
    const u16* __restrict__ Qh, const u16* __restrict__ Ql,
    const float* __restrict__ u, float* __restrict__ z)
{
    __shared__ u16 Ah[128 * LDN_], Al[128 * LDN_];
    __shared__ u16 Bh[128 * LDN_], Bl[128 * LDN_];
    const int t    = threadIdx.x;
    const int b    = blockIdx.z;
    const int n0   = blockIdx.y * 128, m0 = blockIdx.x * 128;
    const int lane = t & 63, w = t >> 6;
    const int wm   = (w >> 1) * 64, wn = (w & 1) * 64;
    const int fr   = lane & 15, kg8 = lane >> 4;
    const int w16  = w * 16;
    const int r4s  = lane >> 2, q4s = (lane & 3) * 8;

    f32x4 acc[4][4];
    #pragma unroll
    for (int i = 0; i < 4; ++i)
        #pragma unroll
        for (int j = 0; j < 4; ++j)
            acc[i][j] = (f32x4){0.f, 0.f, 0.f, 0.f};

    for (int k0 = 0; k0 < C_; k0 += 32) {
        __syncthreads();
        {
            const size_t ga0 = (size_t)(b * N_ + n0 + w16 + r4s) * QKS_ + k0 + q4s;
            const size_t ga1 = ga0 + (size_t)64 * QKS_;
            const size_t gb0 = (size_t)(b * N_ + m0 + w16 + r4s) * QKS_ + 768 + k0 + q4s;
            const size_t gb1 = gb0 + (size_t)64 * QKS_;
            gll16(&Qh[ga0], &Ah[w16 * LDN_]);
            gll16(&Qh[ga1], &Ah[(64 + w16) * LDN_]);
            gll16(&Ql[ga0], &Al[w16 * LDN_]);
            gll16(&Ql[ga1], &Al[(64 + w16) * LDN_]);
            gll16(&Qh[gb0], &Bh[w16 * LDN_]);
            gll16(&Qh[gb1], &Bh[(64 + w16) * LDN_]);
            gll16(&Ql[gb0], &Bl[w16 * LDN_]);
            gll16(&Ql[gb1], &Bl[(64 + w16) * LDN_]);
        }
        __syncthreads();

        bf16x8 aF[4], bF[4], a2F[4], b2F[4];
        #pragma unroll
        for (int fm = 0; fm < 4; ++fm)
            aF[fm] = *(const bf16x8*)&Ah[(wm + fm * 16 + fr) * LDN_ + kg8 * 8];
        #pragma unroll
        for (int fn = 0; fn < 4; ++fn)
            bF[fn] = *(const bf16x8*)&Bh[(wn + fn * 16 + fr) * LDN_ + kg8 * 8];
        #pragma unroll
        for (int fm = 0; fm < 4; ++fm)
            #pragma unroll
            for (int fn = 0; fn < 4; ++fn)
                acc[fm][fn] = __builtin_amdgcn_mfma_f32_16x16x32_bf16(
                    aF[fm], bF[fn], acc[fm][fn], 0, 0, 0);
        #pragma unroll
        for (int fn = 0; fn < 4; ++fn)
            b2F[fn] = *(const bf16x8*)&Bl[(wn + fn * 16 + fr) * LDN_ + kg8 * 8];
        #pragma unroll
        for (int fm = 0; fm < 4; ++fm)
            #pragma unroll
            for (int fn = 0; fn < 4; ++fn)
                acc[fm][fn] = __builtin_amdgcn_mfma_f32_16x16x32_bf16(
                    aF[fm], b2F[fn], acc[fm][fn], 0, 0, 0);
        #pragma unroll
        for (int fm = 0; fm < 4; ++fm)
            a2F[fm] = *(const bf16x8*)&Al[(wm + fm * 16 + fr) * LDN_ + kg8 * 8];
        #pragma unroll
        for (int fm = 0; fm < 4; ++fm)
            #pragma unroll
            for (int fn = 0; fn < 4; ++fn)
                acc[fm][fn] = __builtin_amdgcn_mfma_f32_16x16x32_bf16(
                    a2F[fm], bF[fn], acc[fm][fn], 0, 0, 0);
    }

    const float sc = 0.125f / 12.0f;
    const int r4 = (lane >> 4) * 4;
    #pragma unroll
    for (int fn = 0; fn < 4; ++fn) {
        const int m = m0 + wn + fn * 16 + fr;
        #pragma unroll
        for (int fm = 0; fm < 4; ++fm)
            #pragma unroll
            for (int i = 0; i < 4; ++i) {
                const int n = n0 + wm + fm * 16 + r4 + i;
                const float uv = u[((size_t)(b * N_ + n)) * N_ + m];
                const float g  = -logf(-logf(uv + EPS_) + EPS_);
                z[((size_t)(b * N_ + n)) * N_ + m] = acc[fm][fn][i] * sc + g;
            }
    }
}

// ---------------------------------------------------------------------------
// Per row: exact 32nd-largest of z; emit all cols >= thresh (cap 62).
// ---------------------------------------------------------------------------
__global__ __launch_bounds__(64) void topk_cols_kernel(
    const float* __restrict__ z, TopkRec* __restrict__ recs)
{
    const int row  = blockIdx.x;
    const int lane = threadIdx.x;
    const float* zr = z + (size_t)row * N_;
    float zv[16], wk[16];
    #pragma unroll
    for (int j = 0; j < 16; ++j) { zv[j] = zr[lane + 64 * j]; wk[j] = zv[j]; }

    float thresh = -INFINITY;
    for (int it = 0; it < TOPK_; ++it) {
        float lm = wk[0]; int li = 0;
        #pragma unroll
        for (int j = 1; j < 16; ++j)
            if (wk[j] > lm) { lm = wk[j]; li = j; }
        float gm = lm;
        gm = fmaxf(gm, __shfl_xor(gm, 1));
        gm = fmaxf(gm, __shfl_xor(gm, 2));
        gm = fmaxf(gm, __shfl_xor(gm, 4));
        gm = fmaxf(gm, __shfl_xor(gm, 8));
        gm = fmaxf(gm, __shfl_xor(gm, 16));
        gm = fmaxf(gm, __shfl_xor(gm, 32));
        unsigned long long has = __ballot(lm == gm);
        int first = __ffsll((unsigned long long)has) - 1;
        if (lane == first) wk[li] = -INFINITY;
        thresh = gm;
    }

    const unsigned long long below = ((unsigned long long)1 << lane) - 1;
    unsigned int basec = 0;
    TopkRec* rec = recs + row;
    #pragma unroll
    for (int j = 0; j < 16; ++j) {
        unsigned long long wmask = __ballot(zv[j] >= thresh);
        if (zv[j] >= thresh) {
            unsigned int pos = basec + (unsigned int)__popcll(wmask & below);
            if (pos < 62u) rec->c[pos] = (unsigned short)(lane + 64 * j);
        }
        basec += (unsigned int)__popcll(wmask);
    }
    if (lane == 0) rec->cnt = basec > 62u ? 62u : basec;
}

// ---------------------------------------------------------------------------
// Pass A (MFMA): per (b,h,64-row q-tile): softmax max m and denominator l
// over all 1024 cols. Q fragments in regs; K staged hi/lo in LDS (padded).
// ---------------------------------------------------------------------------
__global__ __launch_bounds__(256) void attn_ml_mfma(
    const u16* __restrict__ qh, const u16* __restrict__ ql,
    float2* __restrict__ ml)
{
    __shared__ u16 KsH[128 * LK_], KsL[128 * LK_];

    const int t    = threadIdx.x;
    const int lane = t & 63, w = t >> 6;
    const int fr   = lane & 15, kg8 = lane >> 4;
    const int n0   = blockIdx.x * 64;
    const int hd   = blockIdx.y;
    const int b    = blockIdx.z;

    bf16x8 aH[2], aL[2];
    {
        const size_t qb = (size_t)(b * N_ + n0 + w * 16 + fr) * QKS_ + hd * 64 + kg8 * 8;
        aH[0] = *(const bf16x8*)&qh[qb];
        aH[1] = *(const bf16x8*)&qh[qb + 32];
        aL[0] = *(const bf16x8*)&ql[qb];
        aL[1] = *(const bf16x8*)&ql[qb + 32];
    }

    float mrun[4], lsum[4];
    #pragma unroll
    for (int i = 0; i < 4; ++i) { mrun[i] = -INFINITY; lsum[i] = 0.f; }

    const int kr = t >> 1, kd = (t & 1) * 32;

    for (int m0 = 0; m0 < N_; m0 += 128) {
        const size_t kb = (size_t)(b * N_ + m0 + kr) * QKS_ + 768 + hd * 64 + kd;
        bf16x8 h0 = *(const bf16x8*)&qh[kb];
        bf16x8 h1 = *(const bf16x8*)&qh[kb + 8];
        bf16x8 h2 = *(const bf16x8*)&qh[kb + 16];
        bf16x8 h3 = *(const bf16x8*)&qh[kb + 24];
        bf16x8 l0 = *(const bf16x8*)&ql[kb];
        bf16x8 l1 = *(const bf16x8*)&ql[kb + 8];
        bf16x8 l2 = *(const bf16x8*)&ql[kb + 16];
        bf16x8 l3 = *(const bf16x8*)&ql[kb + 24];

        __syncthreads();
        const int sb = kr * LK_ + kd;
        *(bf16x8*)&KsH[sb]      = h0;  *(bf16x8*)&KsH[sb + 8]  = h1;
        *(bf16x8*)&KsH[sb + 16] = h2;  *(bf16x8*)&KsH[sb + 24] = h3;
        *(bf16x8*)&KsL[sb]      = l0;  *(bf16x8*)&KsL[sb + 8]  = l1;
        *(bf16x8*)&KsL[sb + 16] = l2;  *(bf16x8*)&KsL[sb + 24] = l3;
        __syncthreads();

        f32x4 acc[8];
        #pragma unroll
        for (int fn = 0; fn < 8; ++fn) acc[fn] = (f32x4){0.f, 0.f, 0.f, 0.f};

        #pragma unroll
        for (int kk = 0; kk < 2; ++kk) {
            #pragma unroll
            for (int fn = 0; fn < 8; ++fn) {
                const int bidx = (fn * 16 + fr) * LK_ + kk * 32 + kg8 * 8;
                bf16x8 bH = *(const bf16x8*)&KsH[bidx];
                bf16x8 bL = *(const bf16x8*)&KsL[bidx];
                acc[fn] = __builtin_amdgcn_mfma_f32_16x16x32_bf16(
                    aH[kk], bH, acc[fn], 0, 0, 0);
                acc[fn] = __builtin_amdgcn_mfma_f32_16x16x32_bf16(
                    aH[kk], bL, acc[fn], 0, 0, 0);
                acc[fn] = __builtin_amdgcn_mfma_f32_16x16x32_bf16(
                    aL[kk], bH, acc[fn], 0, 0, 0);
            }
        }

        #pragma unroll
        for (int reg = 0; reg < 4; ++reg) {
            float tmax = acc[0][reg];
            #pragma unroll
            for (int fn = 1; fn < 8; ++fn) tmax = fmaxf(tmax, acc[fn][reg]);
            tmax *= 0.125f;
            tmax = fmaxf(tmax, __shfl_xor(tmax, 1));
            tmax = fmaxf(tmax, __shfl_xor(tmax, 2));
            tmax = fmaxf(tmax, __shfl_xor(tmax, 4));
            tmax = fmaxf(tmax, __shfl_xor(tmax, 8));
            float mnew  = fmaxf(mrun[reg], tmax);
            float alpha = expf(mrun[reg] - mnew);
            float tsum = 0.f;
            #pragma unroll
            for (int fn = 0; fn < 8; ++fn)
                tsum += expf(acc[fn][reg] * 0.125f - mnew);
            tsum += __shfl_xor(tsum, 1);
            tsum += __shfl_xor(tsum, 2);
            tsum += __shfl_xor(tsum, 4);
            tsum += __shfl_xor(tsum, 8);
            lsum[reg] = lsum[reg] * alpha + tsum;
            mrun[reg] = mnew;
        }
    }

    if (fr == 0) {
        #pragma unroll
        for (int reg = 0; reg < 4; ++reg)
            ml[((size_t)(b * H_ + hd)) * N_ + n0 + w * 16 + kg8 * 4 + reg] =
                make_float2(mrun[reg], lsum[reg]);
    }
}

// ---------------------------------------------------------------------------
// Pass B: sparse gather numerator. Lane = (c,dq). V read as f32.
// ---------------------------------------------------------------------------
__global__ __launch_bounds__(256) void sparse_pv_kernel(
    const u16* __restrict__ qh, const u16* __restrict__ ql,
    const float* __restrict__ Vf,
    const TopkRec* __restrict__ recs, const float2* __restrict__ ml,
    const float* __restrict__ head_scores,
    u16* __restrict__ out1h, u16* __restrict__ out1l)
{
    __shared__ int cols_s[62];
    __shared__ int cnt_s;

    const int t    = threadIdx.x;
    const int lane = t & 63, wv = t >> 6;
    const int c4   = lane >> 2;
    const int dq   = lane & 3;
    const int row  = blockIdx.x;
    const int b    = row >> 10, n = row & 1023;

    const TopkRec* rec = recs + row;
    if (t == 0) cnt_s = (int)min(rec->cnt, 62u);
    if (t < 62) cols_s[t] = rec->c[t];

    float hsum = 0.f;
    #pragma unroll
    for (int i = 0; i < H_; ++i) hsum += head_scores[i];
    const float hs_mean = hsum * (1.0f / 12.0f);
    __syncthreads();
    const int cnt = cnt_s;
    const int nbatch = (cnt + 15) >> 4;

    for (int hd = wv; hd < H_; hd += 4) {
        float qv[16];
        {
            const size_t qb = (size_t)row * QKS_ + hd * 64 + dq * 16;
            bf16x8 qh0 = *(const bf16x8*)&qh[qb], qh1 = *(const bf16x8*)&qh[qb + 8];
            bf16x8 ql0 = *(const bf16x8*)&ql[qb], ql1 = *(const bf16x8*)&ql[qb + 8];
            #pragma unroll
            for (int i = 0; i < 8; ++i) {
                qv[i]     = bf2f((u16)qh0[i]) + bf2f((u16)ql0[i]);
                qv[i + 8] = bf2f((u16)qh1[i]) + bf2f((u16)ql1[i]);
            }
        }
        const float2 mlv = ml[((size_t)(b * H_ + hd)) * N_ + n];

        float acc[16];
        #pragma unroll
        for (int i = 0; i < 16; ++i) acc[i] = 0.f;

        for (int batch = 0; batch < nbatch; ++batch) {
            const int cidx  = batch * 16 + c4;
            const bool valid = (cidx < cnt);
            const int col   = cols_s[valid ? cidx : cnt - 1];

            const size_t kb = (size_t)(b * N_ + col) * QKS_ + 768 + hd * 64 + dq * 16;
            bf16x8 kh0 = *(const bf16x8*)&qh[kb], kh1 = *(const bf16x8*)&qh[kb + 8];
            bf16x8 kl0 = *(const bf16x8*)&ql[kb], kl1 = *(const bf16x8*)&ql[kb + 8];
            float dot = 0.f;
            #pragma unroll
            for (int i = 0; i < 8; ++i) {
                dot += qv[i]     * (bf2f((u16)kh0[i]) + bf2f((u16)kl0[i]));
                dot += qv[i + 8] * (bf2f((u16)kh1[i]) + bf2f((u16)kl1[i]));
            }
            dot += __shfl_xor(dot, 1);
            dot += __shfl_xor(dot, 2);
            float p = valid ? expf(dot * 0.125f - mlv.x) : 0.f;

            const float* vb = &Vf[(size_t)(b * N_ + col) * C_ + hd * 64 + dq * 16];
            #pragma unroll
            for (int q = 0; q < 4; ++q) {
                float4 v4 = *(const float4*)&vb[q * 4];
                acc[q * 4 + 0] += p * v4.x;
                acc[q * 4 + 1] += p * v4.y;
                acc[q * 4 + 2] += p * v4.z;
                acc[q * 4 + 3] += p * v4.w;
            }
        }

        #pragma unroll
        for (int d = 4; d < 64; d <<= 1)
            #pragma unroll
            for (int i = 0; i < 16; ++i)
                acc[i] += __shfl_xor(acc[i], d);

        if (c4 == 0) {
            const float s = hs_mean / mlv.y;
            u16 hb[16], lb[16];
            #pragma unroll
            for (int i = 0; i < 16; ++i) {
                float val = acc[i] * s;
                u16 hi = f2bf(val);
                hb[i] = hi;
                lb[i] = f2bf(val - bf2f(hi));
            }
            const size_t ob = (size_t)row * C_ + hd * 64 + dq * 16;
            *(bf16x8*)&out1h[ob]     = *(const bf16x8*)&hb[0];
            *(bf16x8*)&out1h[ob + 8] = *(const bf16x8*)&hb[8];
            *(bf16x8*)&out1l[ob]     = *(const bf16x8*)&lb[0];
            *(bf16x8*)&out1l[ob + 8] = *(const bf16x8*)&lb[8];
        }
    }
}

// ---------------------------------------------------------------------------
// proj GEMM: pure-plane NT, global_load_lds staging, linear LDS; f32 out.
// ---------------------------------------------------------------------------
__global__ __launch_bounds__(256) void gemm_proj(
    const u16* __restrict__ Ath, const u16* __restrict__ Atl,
    const u16* __restrict__ Bth, const u16* __restrict__ Btl,
    const float* __restrict__ bias, float* __restrict__ Cm)
{
    __shared__ u16 Ah[128 * LDN_], Al[128 * LDN_];
    __shared__ u16 Bh[128 * LDN_], Bl[128 * LDN_];
    const int t    = threadIdx.x;
    const int m0   = blockIdx.y * 128, n0 = blockIdx.x * 128;
    const int lane = t & 63, w = t >> 6;
    const int wm   = (w >> 1) * 64, wn = (w & 1) * 64;
    const int fr   = lane & 15, kg8 = lane >> 4;
    const int w16  = w * 16;
    const int r4s  = lane >> 2, q4s = (lane & 3) * 8;

    f32x4 acc[4][4];
    #pragma unroll
    for (int i = 0; i < 4; ++i)
        #pragma unroll
        for (int j = 0; j < 4; ++j)
            acc[i][j] = (f32x4){0.f, 0.f, 0.f, 0.f};

    for (int k0 = 0; k0 < C_; k0 += 32) {
        __syncthreads();
        {
            const size_t ga0 = (size_t)(m0 + w16 + r4s) * C_ + k0 + q4s;
            const size_t ga1 = ga0 + (size_t)64 * C_;
            const size_t gb0 = (size_t)(n0 + w16 + r4s) * C_ + k0 + q4s;
            const size_t gb1 = gb0 + (size_t)64 * C_;
            gll16(&Ath[ga0], &Ah[w16 * LDN_]);
            gll16(&Ath[ga1], &Ah[(64 + w16) * LDN_]);
            gll16(&Atl[ga0], &Al[w16 * LDN_]);
            gll16(&Atl[ga1], &Al[(64 + w16) * LDN_]);
            gll16(&Bth[gb0], &Bh[w16 * LDN_]);
            gll16(&Bth[gb1], &Bh[(64 + w16) * LDN_]);
            gll16(&Btl[gb0], &Bl[w16 * LDN_]);
            gll16(&Btl[gb1], &Bl[(64 + w16) * LDN_]);
        }
        __syncthreads();

        bf16x8 aF[4], bF[4], a2F[4], b2F[4];
        #pragma unroll
        for (int fm = 0; fm < 4; ++fm)
            aF[fm] = *(const bf16x8*)&Ah[(wm + fm * 16 + fr) * LDN_ + kg8 * 8];
        #pragma unroll
        for (int fn = 0; fn < 4; ++fn)
            bF[fn] = *(const bf16x8*)&Bh[(wn + fn * 16 + fr) * LDN_ + kg8 * 8];
        #pragma unroll
        for (int fm = 0; fm < 4; ++fm)
            #pragma unroll
            for (int fn = 0; fn < 4; ++fn)
                acc[fm][fn] = __builtin_amdgcn_mfma_f32_16x16x32_bf16(
                    aF[fm], bF[fn], acc[fm][fn], 0, 0, 0);
        #pragma unroll
        for (int fn = 0; fn < 4; ++fn)
            b2F[fn] = *(const bf16x8*)&Bl[(wn + fn * 16 + fr) * LDN_ + kg8 * 8];
        #pragma unroll
        for (int fm = 0; fm < 4; ++fm)
            #pragma unroll
            for (int fn = 0; fn < 4; ++fn)
                acc[fm][fn] = __builtin_amdgcn_mfma_f32_16x16x32_bf16(
                    aF[fm], b2F[fn], acc[fm][fn], 0, 0, 0);
        #pragma unroll
        for (int fm = 0; fm < 4; ++fm)
            a2F[fm] = *(const bf16x8*)&Al[(wm + fm * 16 + fr) * LDN_ + kg8 * 8];
        #pragma unroll
        for (int fm = 0; fm < 4; ++fm)
            #pragma unroll
            for (int fn = 0; fn < 4; ++fn)
                acc[fm][fn] = __builtin_amdgcn_mfma_f32_16x16x32_bf16(
                    a2F[fm], bF[fn], acc[fm][fn], 0, 0, 0);
    }

    const int r4 = (lane >> 4) * 4;
    #pragma unroll
    for (int fn = 0; fn < 4; ++fn) {
        const int col = n0 + wn + fn * 16 + fr;
        const float bv = bias[col];
        #pragma unroll
        for (int fm = 0; fm < 4; ++fm)
            #pragma unroll
            for (int i = 0; i < 4; ++i)
                Cm[(size_t)(m0 + wm + fm * 16 + r4 + i) * C_ + col] =
                    acc[fm][fn][i] + bv;
    }
}

// ---------------------------------------------------------------------------
extern "C" void kernel_launch(void* const* d_in, const int* in_sizes, int n_in,
                              void* d_out, int out_size, void* d_ws, size_t ws_size,
                              hipStream_t stream)
{
    (void)in_sizes; (void)n_in; (void)out_size; (void)ws_size;
    const float* x           = (const float*)d_in[0];
    const float* u           = (const float*)d_in[1];
    const float* qkv_w       = (const float*)d_in[2];
    const float* qkv_b       = (const float*)d_in[3];
    const float* proj_w      = (const float*)d_in[4];
    const float* proj_b      = (const float*)d_in[5];
    const float* head_scores = (const float*)d_in[6];
    float* out = (float*)d_out;

    // Workspace (proven 55,050,240-byte footprint):
    //   [0, 12582912)            qkv_h  bf16 [4096][1536]  (Q,K planes)
    //   [12582912, 25165824)     qkv_l
    //   [25165824, 37748736)     V f32 [4096][768]
    //   R = [37748736, 55050240), time-shared:
    //     phase1: wq_t_h | wq_t_l
    //     phase2: z f32 (wq planes dead) + recs
    //     phase3 (z dead): wp_t_h | wp_t_l | ml | out1_h | out1_l
    // d_out time-shared: x_h | x_l planes (dead before gemm_proj writes out).
    char* ws = (char*)d_ws;
    u16*     qkv_h  = (u16*)ws;
    u16*     qkv_l  = (u16*)(ws + 12582912);
    float*   Vf     = (float*)(ws + 25165824);
    char*    R      = ws + 37748736;
    u16*     wq_t_h = (u16*)R;
    u16*     wq_t_l = (u16*)(R + 3538944);
    float*   z      = (float*)R;
    TopkRec* recs   = (TopkRec*)(R + 16777216);
    u16*     wp_t_h = (u16*)R;
    u16*     wp_t_l = (u16*)(R + 1179648);
    float2*  ml     = (float2*)(R + 2359296);
    u16*     out1h  = (u16*)(R + 2752512);
    u16*     out1l  = (u16*)(R + 9043968);
    u16*     x_h    = (u16*)d_out;
    u16*     x_l    = (u16*)((char*)d_out + 6291456);

    // 0) pre-split x -> hi/lo planes (stored in d_out, dead before proj)
    conv_x<<<dim3(4096 * 768 / 8 / 256), dim3(256), 0, stream>>>(x, x_h, x_l);

    // 1) convert qkv_w -> transposed split planes [2304][768]
    conv_w_nt<<<dim3(2304 / 64, 768 / 64), dim3(256), 0, stream>>>(
        qkv_w, wq_t_h, wq_t_l, 768, 2304);

    // 2) qkv = x @ qkv_w + b  -> Q,K planes + V f32
    gemm_qkv<<<dim3(2304 / 128, 4096 / 128), dim3(256), 0, stream>>>(
        x_h, x_l, wq_t_h, wq_t_l, qkv_b, qkv_h, qkv_l, Vf);

    // 3) z = (scale/H) Qc.Kc^T + gumbel(u)
    zscore_mfma<<<dim3(8, 8, B_), dim3(256), 0, stream>>>(qkv_h, qkv_l, u, z);

    // 4) exact top-32 -> column records
    topk_cols_kernel<<<dim3(B_ * N_), dim3(64), 0, stream>>>(z, recs);

    // 5) convert proj_w -> transposed split planes [768][768]
    conv_w_nt<<<dim3(768 / 64, 768 / 64), dim3(256), 0, stream>>>(
        proj_w, wp_t_h, wp_t_l, 768, 768);

    // 6) per-head softmax max + denominator (MFMA)
    attn_ml_mfma<<<dim3(16, H_, B_), dim3(256), 0, stream>>>(qkv_h, qkv_l, ml);

    // 7) sparse gather numerator -> out1 planes
    sparse_pv_kernel<<<dim3(B_ * N_), dim3(256), 0, stream>>>(
        qkv_h, qkv_l, Vf, recs, ml, head_scores, out1h, out1l);

    // 8) out = out1 @ proj_w + b
    gemm_proj<<<dim3(768 / 128, 4096 / 128), dim3(256), 0, stream>>>(
        out1h, out1l, wp_t_h, wp_t_l, proj_b, out);
}

// Round 10
// 290.806 us; speedup vs baseline: 2.1797x; 1.0764x over previous
//
#include <hip/hip_runtime.h>
#include <hip/hip_bf16.h>
#include <math.h>

#define B_ 4
#define N_ 1024
#define C_ 768
#define H_ 12
#define D_ 64
#define TOPK_ 32
#define EPS_ 1e-9f

#define LDN_ 32   // linear LDS row stride (u16) for global_load_lds staging
#define LK_  72   // attn LDS row stride: 64 used + 8 pad = 144 B
#define QKS_ 1536 // Q,K plane row stride (elems)

typedef __attribute__((ext_vector_type(8))) short bf16x8;
typedef __attribute__((ext_vector_type(4))) float f32x4;
typedef unsigned short u16;

struct TopkRec { unsigned int cnt; unsigned short c[62]; };  // 128 B

__device__ __forceinline__ u16 f2bf(float f) {
    unsigned int u = __float_as_uint(f);
    u += 0x7fffu + ((u >> 16) & 1u);
    return (u16)(u >> 16);
}
__device__ __forceinline__ float bf2f(u16 h) {
    return __uint_as_float(((unsigned int)h) << 16);
}

// async global->LDS, 16B per lane; LDS dest is wave-uniform base + lane*16.
__device__ __forceinline__ void gll16(const void* g, void* l) {
    __builtin_amdgcn_global_load_lds(
        (const __attribute__((address_space(1))) void*)g,
        (__attribute__((address_space(3))) void*)l, 16, 0, 0);
}

// ---------------------------------------------------------------------------
// x convert (elementwise): x f32 [M][K] -> hi/lo bf16 planes.
// ---------------------------------------------------------------------------
__global__ __launch_bounds__(256) void conv_x(
    const float* __restrict__ X, u16* __restrict__ Xh, u16* __restrict__ Xl)
{
    const size_t off = ((size_t)blockIdx.x * 256 + threadIdx.x) * 8;
    float4 a = *(const float4*)&X[off];
    float4 b = *(const float4*)&X[off + 4];
    float v[8] = {a.x, a.y, a.z, a.w, b.x, b.y, b.z, b.w};
    u16 hb[8], lb[8];
    #pragma unroll
    for (int i = 0; i < 8; ++i) {
        u16 hi = f2bf(v[i]);
        hb[i] = hi;
        lb[i] = f2bf(v[i] - bf2f(hi));
    }
    *(bf16x8*)&Xh[off] = *(const bf16x8*)&hb[0];
    *(bf16x8*)&Xl[off] = *(const bf16x8*)&lb[0];
}

// ---------------------------------------------------------------------------
// Weight convert: W f32 [K][Ncols] -> Wt_h, Wt_l bf16 [Ncols][K] transposed.
// ---------------------------------------------------------------------------
__global__ __launch_bounds__(256) void conv_w_nt(
    const float* __restrict__ W, u16* __restrict__ Wt_h, u16* __restrict__ Wt_l,
    int Kdim, int Ncols)
{
    __shared__ float Ts[64][65];
    const int t  = threadIdx.x;
    const int r  = t >> 2;
    const int cq = (t & 3) * 16;
    const int n0 = blockIdx.x * 64, k0 = blockIdx.y * 64;

    #pragma unroll
    for (int q = 0; q < 4; ++q) {
        float4 v = *(const float4*)&W[(size_t)(k0 + r) * Ncols + n0 + cq + q * 4];
        Ts[r][cq + q * 4 + 0] = v.x;
        Ts[r][cq + q * 4 + 1] = v.y;
        Ts[r][cq + q * 4 + 2] = v.z;
        Ts[r][cq + q * 4 + 3] = v.w;
    }
    __syncthreads();
    u16 hb[16], lb[16];
    #pragma unroll
    for (int i = 0; i < 16; ++i) {
        float val = Ts[cq + i][r];
        u16 hi = f2bf(val);
        hb[i] = hi;
        lb[i] = f2bf(val - bf2f(hi));
    }
    const size_t obase = (size_t)(n0 + r) * Kdim + k0 + cq;
    *(bf16x8*)&Wt_h[obase]     = *(const bf16x8*)&hb[0];
    *(bf16x8*)&Wt_h[obase + 8] = *(const bf16x8*)&hb[8];
    *(bf16x8*)&Wt_l[obase]     = *(const bf16x8*)&lb[0];
    *(bf16x8*)&Wt_l[obase + 8] = *(const bf16x8*)&lb[8];
}

// ---------------------------------------------------------------------------
// qkv GEMM: pure-plane NT, global_load_lds staging, linear LDS.
// ---------------------------------------------------------------------------
__global__ __launch_bounds__(256) void gemm_qkv(
    const u16* __restrict__ Ath, const u16* __restrict__ Atl,
    const u16* __restrict__ Bth, const u16* __restrict__ Btl,
    const float* __restrict__ bias,
    u16* __restrict__ Ch, u16* __restrict__ Cl, float* __restrict__ Vf)
{
    __shared__ u16 Ah[128 * LDN_], Al[128 * LDN_];
    __shared__ u16 Bh[128 * LDN_], Bl[128 * LDN_];
    const int t    = threadIdx.x;
    const int m0   = blockIdx.y * 128, n0 = blockIdx.x * 128;
    const int lane = t & 63, w = t >> 6;
    const int wm   = (w >> 1) * 64, wn = (w & 1) * 64;
    const int fr   = lane & 15, kg8 = lane >> 4;
    const int w16  = w * 16;
    const int r4s  = lane >> 2, q4s = (lane & 3) * 8;

    f32x4 acc[4][4];
    #pragma unroll
    for (int i = 0; i < 4; ++i)
        #pragma unroll
        for (int j = 0; j < 4; ++j)
            acc[i][j] = (f32x4){0.f, 0.f, 0.f, 0.f};

    for (int k0 = 0; k0 < C_; k0 += 32) {
        __syncthreads();
        {
            const size_t ga0 = (size_t)(m0 + w16 + r4s) * C_ + k0 + q4s;
            const size_t ga1 = ga0 + (size_t)64 * C_;
            const size_t gb0 = (size_t)(n0 + w16 + r4s) * C_ + k0 + q4s;
            const size_t gb1 = gb0 + (size_t)64 * C_;
            gll16(&Ath[ga0], &Ah[w16 * LDN_]);
            gll16(&Ath[ga1], &Ah[(64 + w16) * LDN_]);
            gll16(&Atl[ga0], &Al[w16 * LDN_]);
            gll16(&Atl[ga1], &Al[(64 + w16) * LDN_]);
            gll16(&Bth[gb0], &Bh[w16 * LDN_]);
            gll16(&Bth[gb1], &Bh[(64 + w16) * LDN_]);
            gll16(&Btl[gb0], &Bl[w16 * LDN_]);
            gll16(&Btl[gb1], &Bl[(64 + w16) * LDN_]);
        }
        __syncthreads();

        bf16x8 aF[4], bF[4], a2F[4], b2F[4];
        #pragma unroll
        for (int fm = 0; fm < 4; ++fm)
            aF[fm] = *(const bf16x8*)&Ah[(wm + fm * 16 + fr) * LDN_ + kg8 * 8];
        #pragma unroll
        for (int fn = 0; fn < 4; ++fn)
            bF[fn] = *(const bf16x8*)&Bh[(wn + fn * 16 + fr) * LDN_ + kg8 * 8];
        #pragma unroll
        for (int fm = 0; fm < 4; ++fm)
            #pragma unroll
            for (int fn = 0; fn < 4; ++fn)
                acc[fm][fn] = __builtin_amdgcn_mfma_f32_16x16x32_bf16(
                    aF[fm], bF[fn], acc[fm][fn], 0, 0, 0);
        #pragma unroll
        for (int fn = 0; fn < 4; ++fn)
            b2F[fn] = *(const bf16x8*)&Bl[(wn + fn * 16 + fr) * LDN_ + kg8 * 8];
        #pragma unroll
        for (int fm = 0; fm < 4; ++fm)
            #pragma unroll
            for (int fn = 0; fn < 4; ++fn)
                acc[fm][fn] = __builtin_amdgcn_mfma_f32_16x16x32_bf16(
                    aF[fm], b2F[fn], acc[fm][fn], 0, 0, 0);
        #pragma unroll
        for (int fm = 0; fm < 4; ++fm)
            a2F[fm] = *(const bf16x8*)&Al[(wm + fm * 16 + fr) * LDN_ + kg8 * 8];
        #pragma unroll
        for (int fm = 0; fm < 4; ++fm)
            #pragma unroll
            for (int fn = 0; fn < 4; ++fn)
                acc[fm][fn] = __builtin_amdgcn_mfma_f32_16x16x32_bf16(
                    a2F[fm], bF[fn], acc[fm][fn], 0, 0, 0);
    }

    const int r4 = (lane >> 4) * 4;
    const bool isV = (n0 >= 1536);
    #pragma unroll
    for (int fn = 0; fn < 4; ++fn) {
        const int col = n0 + wn + fn * 16 + fr;
        const float bv = bias[col];
        #pragma unroll
        for (int fm = 0; fm < 4; ++fm)
            #pragma unroll
            for (int i = 0; i < 4; ++i) {
                const int rown = m0 + wm + fm * 16 + r4 + i;
                float val = acc[fm][fn][i] + bv;
                if (isV) {
                    Vf[(size_t)rown * C_ + col - 1536] = val;
                } else {
                    const size_t o = (size_t)rown * QKS_ + col;
                    u16 hi = f2bf(val);
                    Ch[o] = hi;
                    Cl[o] = f2bf(val - bf2f(hi));
                }
            }
    }
}

// ---------------------------------------------------------------------------
// Fused z + per-head partial softmax. Block = (b, 64-row q-tile, 128-col
// m-chunk). For each head h: per-head scores S_h via split-MFMA; zacc += S_h
// (z = (scale/H)*sum_h S_h + gumbel comes free); per-chunk (tmax,tsum)
// partials written per head. K_h staged hi/lo in LDS; Q frags global->VGPR.
// ---------------------------------------------------------------------------
__global__ __launch_bounds__(256) void attn_fused(
    const u16* __restrict__ qh, const u16* __restrict__ ql,
    const float* __restrict__ u, float* __restrict__ z,
    float2* __restrict__ mlp)
{
    __shared__ u16 KsH[128 * LK_], KsL[128 * LK_];

    const int t    = threadIdx.x;
    const int lane = t & 63, w = t >> 6;
    const int fr   = lane & 15, kg8 = lane >> 4;
    const int n0   = blockIdx.x * 64;
    const int m0   = blockIdx.y * 128;
    const int mc   = blockIdx.y;          // chunk index 0..7
    const int b    = blockIdx.z;

    f32x4 zacc[8];
    #pragma unroll
    for (int fn = 0; fn < 8; ++fn) zacc[fn] = (f32x4){0.f, 0.f, 0.f, 0.f};

    const int kr = t >> 1, kd = (t & 1) * 32;   // K staging: row, 32-d half

    for (int hd = 0; hd < H_; ++hd) {
        // Q fragments for this head (global->VGPR, L2-hot)
        const size_t qb = (size_t)(b * N_ + n0 + w * 16 + fr) * QKS_ + hd * 64 + kg8 * 8;
        bf16x8 aH0 = *(const bf16x8*)&qh[qb];
        bf16x8 aH1 = *(const bf16x8*)&qh[qb + 32];
        bf16x8 aL0 = *(const bf16x8*)&ql[qb];
        bf16x8 aL1 = *(const bf16x8*)&ql[qb + 32];

        // K tile for this head
        const size_t kb = (size_t)(b * N_ + m0 + kr) * QKS_ + 768 + hd * 64 + kd;
        bf16x8 h0 = *(const bf16x8*)&qh[kb];
        bf16x8 h1 = *(const bf16x8*)&qh[kb + 8];
        bf16x8 h2 = *(const bf16x8*)&qh[kb + 16];
        bf16x8 h3 = *(const bf16x8*)&qh[kb + 24];
        bf16x8 l0 = *(const bf16x8*)&ql[kb];
        bf16x8 l1 = *(const bf16x8*)&ql[kb + 8];
        bf16x8 l2 = *(const bf16x8*)&ql[kb + 16];
        bf16x8 l3 = *(const bf16x8*)&ql[kb + 24];

        __syncthreads();                 // prev head's fragment reads done
        const int sb = kr * LK_ + kd;
        *(bf16x8*)&KsH[sb]      = h0;  *(bf16x8*)&KsH[sb + 8]  = h1;
        *(bf16x8*)&KsH[sb + 16] = h2;  *(bf16x8*)&KsH[sb + 24] = h3;
        *(bf16x8*)&KsL[sb]      = l0;  *(bf16x8*)&KsL[sb + 8]  = l1;
        *(bf16x8*)&KsL[sb + 16] = l2;  *(bf16x8*)&KsL[sb + 24] = l3;
        __syncthreads();

        f32x4 acc[8];
        #pragma unroll
        for (int fn = 0; fn < 8; ++fn) acc[fn] = (f32x4){0.f, 0.f, 0.f, 0.f};

        #pragma unroll
        for (int fn = 0; fn < 8; ++fn) {
            const int bidx = (fn * 16 + fr) * LK_ + kg8 * 8;
            bf16x8 bH = *(const bf16x8*)&KsH[bidx];
            bf16x8 bL = *(const bf16x8*)&KsL[bidx];
            acc[fn] = __builtin_amdgcn_mfma_f32_16x16x32_bf16(aH0, bH, acc[fn], 0, 0, 0);
            acc[fn] = __builtin_amdgcn_mfma_f32_16x16x32_bf16(aH0, bL, acc[fn], 0, 0, 0);
            acc[fn] = __builtin_amdgcn_mfma_f32_16x16x32_bf16(aL0, bH, acc[fn], 0, 0, 0);
        }
        #pragma unroll
        for (int fn = 0; fn < 8; ++fn) {
            const int bidx = (fn * 16 + fr) * LK_ + 32 + kg8 * 8;
            bf16x8 bH = *(const bf16x8*)&KsH[bidx];
            bf16x8 bL = *(const bf16x8*)&KsL[bidx];
            acc[fn] = __builtin_amdgcn_mfma_f32_16x16x32_bf16(aH1, bH, acc[fn], 0, 0, 0);
            acc[fn] = __builtin_amdgcn_mfma_f32_16x16x32_bf16(aH1, bL, acc[fn], 0, 0, 0);
            acc[fn] = __builtin_amdgcn_mfma_f32_16x16x32_bf16(aL1, bH, acc[fn], 0, 0, 0);
        }

        // z accumulation across heads
        #pragma unroll
        for (int fn = 0; fn < 8; ++fn) {
            zacc[fn][0] += acc[fn][0];
            zacc[fn][1] += acc[fn][1];
            zacc[fn][2] += acc[fn][2];
            zacc[fn][3] += acc[fn][3];
        }

        // per-head partial softmax over this 128-col chunk
        #pragma unroll
        for (int reg = 0; reg < 4; ++reg) {
            float tmax = acc[0][reg];
            #pragma unroll
            for (int fn = 1; fn < 8; ++fn) tmax = fmaxf(tmax, acc[fn][reg]);
            tmax *= 0.125f;
            tmax = fmaxf(tmax, __shfl_xor(tmax, 1));
            tmax = fmaxf(tmax, __shfl_xor(tmax, 2));
            tmax = fmaxf(tmax, __shfl_xor(tmax, 4));
            tmax = fmaxf(tmax, __shfl_xor(tmax, 8));
            float tsum = 0.f;
            #pragma unroll
            for (int fn = 0; fn < 8; ++fn)
                tsum += expf(acc[fn][reg] * 0.125f - tmax);
            tsum += __shfl_xor(tsum, 1);
            tsum += __shfl_xor(tsum, 2);
            tsum += __shfl_xor(tsum, 4);
            tsum += __shfl_xor(tsum, 8);
            if (fr == 0) {
                const int n = n0 + w * 16 + kg8 * 4 + reg;
                mlp[(((size_t)(b * H_ + hd)) * N_ + n) * 8 + mc] =
                    make_float2(tmax, tsum);
            }
        }
    }

    // z epilogue: z = zacc * (scale/H) + gumbel(u)
    const float sc = 0.125f / 12.0f;
    #pragma unroll
    for (int fn = 0; fn < 8; ++fn) {
        const int m = m0 + fn * 16 + fr;
        #pragma unroll
        for (int reg = 0; reg < 4; ++reg) {
            const int n = n0 + w * 16 + kg8 * 4 + reg;
            const float uv = u[((size_t)(b * N_ + n)) * N_ + m];
            const float g  = -logf(-logf(uv + EPS_) + EPS_);
            z[((size_t)(b * N_ + n)) * N_ + m] = zacc[fn][reg] * sc + g;
        }
    }
}

// ---------------------------------------------------------------------------
// Merge 8 per-chunk (tmax,tsum) partials into final (m, l) per (b,h,n).
// ---------------------------------------------------------------------------
__global__ __launch_bounds__(256) void ml_merge(
    const float2* __restrict__ mlp, float2* __restrict__ ml)
{
    const size_t idx = (size_t)blockIdx.x * 256 + threadIdx.x;  // < B*H*N
    float2 p[8];
    #pragma unroll
    for (int i = 0; i < 8; ++i) p[i] = mlp[idx * 8 + i];
    float m = p[0].x;
    #pragma unroll
    for (int i = 1; i < 8; ++i) m = fmaxf(m, p[i].x);
    float l = 0.f;
    #pragma unroll
    for (int i = 0; i < 8; ++i) l += p[i].y * expf(p[i].x - m);
    ml[idx] = make_float2(m, l);
}

// ---------------------------------------------------------------------------
// Per row: exact 32nd-largest of z; emit all cols >= thresh (cap 62).
// ---------------------------------------------------------------------------
__global__ __launch_bounds__(64) void topk_cols_kernel(
    const float* __restrict__ z, TopkRec* __restrict__ recs)
{
    const int row  = blockIdx.x;
    const int lane = threadIdx.x;
    const float* zr = z + (size_t)row * N_;
    float zv[16], wk[16];
    #pragma unroll
    for (int j = 0; j < 16; ++j) { zv[j] = zr[lane + 64 * j]; wk[j] = zv[j]; }

    float thresh = -INFINITY;
    for (int it = 0; it < TOPK_; ++it) {
        float lm = wk[0]; int li = 0;
        #pragma unroll
        for (int j = 1; j < 16; ++j)
            if (wk[j] > lm) { lm = wk[j]; li = j; }
        float gm = lm;
        gm = fmaxf(gm, __shfl_xor(gm, 1));
        gm = fmaxf(gm, __shfl_xor(gm, 2));
        gm = fmaxf(gm, __shfl_xor(gm, 4));
        gm = fmaxf(gm, __shfl_xor(gm, 8));
        gm = fmaxf(gm, __shfl_xor(gm, 16));
        gm = fmaxf(gm, __shfl_xor(gm, 32));
        unsigned long long has = __ballot(lm == gm);
        int first = __ffsll((unsigned long long)has) - 1;
        if (lane == first) wk[li] = -INFINITY;
        thresh = gm;
    }

    const unsigned long long below = ((unsigned long long)1 << lane) - 1;
    unsigned int basec = 0;
    TopkRec* rec = recs + row;
    #pragma unroll
    for (int j = 0; j < 16; ++j) {
        unsigned long long wmask = __ballot(zv[j] >= thresh);
        if (zv[j] >= thresh) {
            unsigned int pos = basec + (unsigned int)__popcll(wmask & below);
            if (pos < 62u) rec->c[pos] = (unsigned short)(lane + 64 * j);
        }
        basec += (unsigned int)__popcll(wmask);
    }
    if (lane == 0) rec->cnt = basec > 62u ? 62u : basec;
}

// ---------------------------------------------------------------------------
// Pass B: sparse gather numerator. Lane = (c,dq). V read as f32.
// ---------------------------------------------------------------------------
__global__ __launch_bounds__(256) void sparse_pv_kernel(
    const u16* __restrict__ qh, const u16* __restrict__ ql,
    const float* __restrict__ Vf,
    const TopkRec* __restrict__ recs, const float2* __restrict__ ml,
    const float* __restrict__ head_scores,
    u16* __restrict__ out1h, u16* __restrict__ out1l)
{
    __shared__ int cols_s[62];
    __shared__ int cnt_s;

    const int t    = threadIdx.x;
    const int lane = t & 63, wv = t >> 6;
    const int c4   = lane >> 2;
    const int dq   = lane & 3;
    const int row  = blockIdx.x;
    const int b    = row >> 10, n = row & 1023;

    const TopkRec* rec = recs + row;
    if (t == 0) cnt_s = (int)min(rec->cnt, 62u);
    if (t < 62) cols_s[t] = rec->c[t];

    float hsum = 0.f;
    #pragma unroll
    for (int i = 0; i < H_; ++i) hsum += head_scores[i];
    const float hs_mean = hsum * (1.0f / 12.0f);
    __syncthreads();
    const int cnt = cnt_s;
    const int nbatch = (cnt + 15) >> 4;

    for (int hd = wv; hd < H_; hd += 4) {
        float qv[16];
        {
            const size_t qb = (size_t)row * QKS_ + hd * 64 + dq * 16;
            bf16x8 qh0 = *(const bf16x8*)&qh[qb], qh1 = *(const bf16x8*)&qh[qb + 8];
            bf16x8 ql0 = *(const bf16x8*)&ql[qb], ql1 = *(const bf16x8*)&ql[qb + 8];
            #pragma unroll
            for (int i = 0; i < 8; ++i) {
                qv[i]     = bf2f((u16)qh0[i]) + bf2f((u16)ql0[i]);
                qv[i + 8] = bf2f((u16)qh1[i]) + bf2f((u16)ql1[i]);
            }
        }
        const float2 mlv = ml[((size_t)(b * H_ + hd)) * N_ + n];

        float acc[16];
        #pragma unroll
        for (int i = 0; i < 16; ++i) acc[i] = 0.f;

        for (int batch = 0; batch < nbatch; ++batch) {
            const int cidx  = batch * 16 + c4;
            const bool valid = (cidx < cnt);
            const int col   = cols_s[valid ? cidx : cnt - 1];

            const size_t kb = (size_t)(b * N_ + col) * QKS_ + 768 + hd * 64 + dq * 16;
            bf16x8 kh0 = *(const bf16x8*)&qh[kb], kh1 = *(const bf16x8*)&qh[kb + 8];
            bf16x8 kl0 = *(const bf16x8*)&ql[kb], kl1 = *(const bf16x8*)&ql[kb + 8];
            float dot = 0.f;
            #pragma unroll
            for (int i = 0; i < 8; ++i) {
                dot += qv[i]     * (bf2f((u16)kh0[i]) + bf2f((u16)kl0[i]));
                dot += qv[i + 8] * (bf2f((u16)kh1[i]) + bf2f((u16)kl1[i]));
            }
            dot += __shfl_xor(dot, 1);
            dot += __shfl_xor(dot, 2);
            float p = valid ? expf(dot * 0.125f - mlv.x) : 0.f;

            const float* vb = &Vf[(size_t)(b * N_ + col) * C_ + hd * 64 + dq * 16];
            #pragma unroll
            for (int q = 0; q < 4; ++q) {
                float4 v4 = *(const float4*)&vb[q * 4];
                acc[q * 4 + 0] += p * v4.x;
                acc[q * 4 + 1] += p * v4.y;
                acc[q * 4 + 2] += p * v4.z;
                acc[q * 4 + 3] += p * v4.w;
            }
        }

        #pragma unroll
        for (int d = 4; d < 64; d <<= 1)
            #pragma unroll
            for (int i = 0; i < 16; ++i)
                acc[i] += __shfl_xor(acc[i], d);

        if (c4 == 0) {
            const float s = hs_mean / mlv.y;
            u16 hb[16], lb[16];
            #pragma unroll
            for (int i = 0; i < 16; ++i) {
                float val = acc[i] * s;
                u16 hi = f2bf(val);
                hb[i] = hi;
                lb[i] = f2bf(val - bf2f(hi));
            }
            const size_t ob = (size_t)row * C_ + hd * 64 + dq * 16;
            *(bf16x8*)&out1h[ob]     = *(const bf16x8*)&hb[0];
            *(bf16x8*)&out1h[ob + 8] = *(const bf16x8*)&hb[8];
            *(bf16x8*)&out1l[ob]     = *(const bf16x8*)&lb[0];
            *(bf16x8*)&out1l[ob + 8] = *(const bf16x8*)&lb[8];
        }
    }
}

// ---------------------------------------------------------------------------
// proj GEMM: pure-plane NT, global_load_lds staging, linear LDS; f32 out.
// ---------------------------------------------------------------------------
__global__ __launch_bounds__(256) void gemm_proj(
    const u16* __restrict__ Ath, const u16* __restrict__ Atl,
    const u16* __restrict__ Bth, const u16* __restrict__ Btl,
    const float* __restrict__ bias, float* __restrict__ Cm)
{
    __shared__ u16 Ah[128 * LDN_], Al[128 * LDN_];
    __shared__ u16 Bh[128 * LDN_], Bl[128 * LDN_];
    const int t    = threadIdx.x;
    const int m0   = blockIdx.y * 128, n0 = blockIdx.x * 128;
    const int lane = t & 63, w = t >> 6;
    const int wm   = (w >> 1) * 64, wn = (w & 1) * 64;
    const int fr   = lane & 15, kg8 = lane >> 4;
    const int w16  = w * 16;
    const int r4s  = lane >> 2, q4s = (lane & 3) * 8;

    f32x4 acc[4][4];
    #pragma unroll
    for (int i = 0; i < 4; ++i)
        #pragma unroll
        for (int j = 0; j < 4; ++j)
            acc[i][j] = (f32x4){0.f, 0.f, 0.f, 0.f};

    for (int k0 = 0; k0 < C_; k0 += 32) {
        __syncthreads();
        {
            const size_t ga0 = (size_t)(m0 + w16 + r4s) * C_ + k0 + q4s;
            const size_t ga1 = ga0 + (size_t)64 * C_;
            const size_t gb0 = (size_t)(n0 + w16 + r4s) * C_ + k0 + q4s;
            const size_t gb1 = gb0 + (size_t)64 * C_;
            gll16(&Ath[ga0], &Ah[w16 * LDN_]);
            gll16(&Ath[ga1], &Ah[(64 + w16) * LDN_]);
            gll16(&Atl[ga0], &Al[w16 * LDN_]);
            gll16(&Atl[ga1], &Al[(64 + w16) * LDN_]);
            gll16(&Bth[gb0], &Bh[w16 * LDN_]);
            gll16(&Bth[gb1], &Bh[(64 + w16) * LDN_]);
            gll16(&Btl[gb0], &Bl[w16 * LDN_]);
            gll16(&Btl[gb1], &Bl[(64 + w16) * LDN_]);
        }
        __syncthreads();

        bf16x8 aF[4], bF[4], a2F[4], b2F[4];
        #pragma unroll
        for (int fm = 0; fm < 4; ++fm)
            aF[fm] = *(const bf16x8*)&Ah[(wm + fm * 16 + fr) * LDN_ + kg8 * 8];
        #pragma unroll
        for (int fn = 0; fn < 4; ++fn)
            bF[fn] = *(const bf16x8*)&Bh[(wn + fn * 16 + fr) * LDN_ + kg8 * 8];
        #pragma unroll
        for (int fm = 0; fm < 4; ++fm)
            #pragma unroll
            for (int fn = 0; fn < 4; ++fn)
                acc[fm][fn] = __builtin_amdgcn_mfma_f32_16x16x32_bf16(
                    aF[fm], bF[fn], acc[fm][fn], 0, 0, 0);
        #pragma unroll
        for (int fn = 0; fn < 4; ++fn)
            b2F[fn] = *(const bf16x8*)&Bl[(wn + fn * 16 + fr) * LDN_ + kg8 * 8];
        #pragma unroll
        for (int fm = 0; fm < 4; ++fm)
            #pragma unroll
            for (int fn = 0; fn < 4; ++fn)
                acc[fm][fn] = __builtin_amdgcn_mfma_f32_16x16x32_bf16(
                    aF[fm], b2F[fn], acc[fm][fn], 0, 0, 0);
        #pragma unroll
        for (int fm = 0; fm < 4; ++fm)
            a2F[fm] = *(const bf16x8*)&Al[(wm + fm * 16 + fr) * LDN_ + kg8 * 8];
        #pragma unroll
        for (int fm = 0; fm < 4; ++fm)
            #pragma unroll
            for (int fn = 0; fn < 4; ++fn)
                acc[fm][fn] = __builtin_amdgcn_mfma_f32_16x16x32_bf16(
                    a2F[fm], bF[fn], acc[fm][fn], 0, 0, 0);
    }

    const int r4 = (lane >> 4) * 4;
    #pragma unroll
    for (int fn = 0; fn < 4; ++fn) {
        const int col = n0 + wn + fn * 16 + fr;
        const float bv = bias[col];
        #pragma unroll
        for (int fm = 0; fm < 4; ++fm)
            #pragma unroll
            for (int i = 0; i < 4; ++i)
                Cm[(size_t)(m0 + wm + fm * 16 + r4 + i) * C_ + col] =
                    acc[fm][fn][i] + bv;
    }
}

// ---------------------------------------------------------------------------
extern "C" void kernel_launch(void* const* d_in, const int* in_sizes, int n_in,
                              void* d_out, int out_size, void* d_ws, size_t ws_size,
                              hipStream_t stream)
{
    (void)in_sizes; (void)n_in; (void)out_size; (void)ws_size;
    const float* x           = (const float*)d_in[0];
    const float* u           = (const float*)d_in[1];
    const float* qkv_w       = (const float*)d_in[2];
    const float* qkv_b       = (const float*)d_in[3];
    const float* proj_w      = (const float*)d_in[4];
    const float* proj_b      = (const float*)d_in[5];
    const float* head_scores = (const float*)d_in[6];
    float* out = (float*)d_out;

    // Workspace (proven 55,050,240-byte footprint):
    //   [0, 12582912)            qkv_h  bf16 [4096][1536]  (Q,K planes)
    //   [12582912, 25165824)     qkv_l
    //   [25165824, 37748736)     V f32 [4096][768]
    //   R = [37748736, 55050240), time-shared:
    //     phase1: wq_t_h | wq_t_l (dead after gemm_qkv)
    //     phase2: z f32 [0,16777216) + recs [16777216,17301504)
    //     phase3 (z dead): wp_t_h | wp_t_l | ml | out1_h | out1_l
    // d_out (12,582,912 B) time-shared:
    //     x_h | x_l planes (dead after gemm_qkv)
    //     mlp partials [0, 3145728) (written by attn_fused, dead after
    //       ml_merge); gemm_proj overwrites d_out last.
    char* ws = (char*)d_ws;
    u16*     qkv_h  = (u16*)ws;
    u16*     qkv_l  = (u16*)(ws + 12582912);
    float*   Vf     = (float*)(ws + 25165824);
    char*    R      = ws + 37748736;
    u16*     wq_t_h = (u16*)R;
    u16*     wq_t_l = (u16*)(R + 3538944);
    float*   z      = (float*)R;
    TopkRec* recs   = (TopkRec*)(R + 16777216);
    u16*     wp_t_h = (u16*)R;
    u16*     wp_t_l = (u16*)(R + 1179648);
    float2*  ml     = (float2*)(R + 2359296);
    u16*     out1h  = (u16*)(R + 2752512);
    u16*     out1l  = (u16*)(R + 9043968);
    u16*     x_h    = (u16*)d_out;
    u16*     x_l    = (u16*)((char*)d_out + 6291456);
    float2*  mlp    = (float2*)d_out;   // 3,145,728 B (after x planes dead)

    // 0) pre-split x -> hi/lo planes (stored in d_out)
    conv_x<<<dim3(4096 * 768 / 8 / 256), dim3(256), 0, stream>>>(x, x_h, x_l);

    // 1) convert qkv_w -> transposed split planes [2304][768]
    conv_w_nt<<<dim3(2304 / 64, 768 / 64), dim3(256), 0, stream>>>(
        qkv_w, wq_t_h, wq_t_l, 768, 2304);

    // 2) qkv = x @ qkv_w + b  -> Q,K planes + V f32
    gemm_qkv<<<dim3(2304 / 128, 4096 / 128), dim3(256), 0, stream>>>(
        x_h, x_l, wq_t_h, wq_t_l, qkv_b, qkv_h, qkv_l, Vf);

    // 3) fused: z (+gumbel) AND per-head per-chunk softmax partials
    //    (x planes in d_out are dead now; mlp reuses that space)
    attn_fused<<<dim3(16, 8, B_), dim3(256), 0, stream>>>(
        qkv_h, qkv_l, u, z, mlp);

    // 4) exact top-32 -> column records
    topk_cols_kernel<<<dim3(B_ * N_), dim3(64), 0, stream>>>(z, recs);

    // 5) convert proj_w -> transposed split planes [768][768]  (z dead)
    conv_w_nt<<<dim3(768 / 64, 768 / 64), dim3(256), 0, stream>>>(
        proj_w, wp_t_h, wp_t_l, 768, 768);

    // 6) merge partials -> final (m, l)
    ml_merge<<<dim3(B_ * H_ * N_ / 256), dim3(256), 0, stream>>>(mlp, ml);

    // 7) sparse gather numerator -> out1 planes
    sparse_pv_kernel<<<dim3(B_ * N_), dim3(256), 0, stream>>>(
        qkv_h, qkv_l, Vf, recs, ml, head_scores, out1h, out1l);

    // 8) out = out1 @ proj_w + b
    gemm_proj<<<dim3(768 / 128, 4096 / 128), dim3(256), 0, stream>>>(
        out1h, out1l, wp_t_h, wp_t_l, proj_b, out);
}